// Round 18
// baseline (558.265 us; speedup 1.0000x reference)
//
#include <hip/hip_runtime.h>

#define NN 65536
#define EE 262144
#define ND ((size_t)NN * 128)
#define TBW 132
#define WLP 136   // LDS weight pitch (u16)
#define NTOT (EE + NN)          // edges + selfs per type
#define CSRN (3*EE + 3*NN)      // total CSR slots

typedef unsigned short u16;
typedef unsigned char u8;
typedef short bf8_t __attribute__((ext_vector_type(8)));
typedef float f32x4 __attribute__((ext_vector_type(4)));
typedef float f32x2 __attribute__((ext_vector_type(2)));

__device__ __forceinline__ float lrelu(float x){ return x > 0.f ? x : 0.2f*x; }
__device__ __forceinline__ float gelu_exact(float x){ return 0.5f*x*(1.f+erff(x*0.70710678118654752f)); }
__device__ __forceinline__ float fexp(float x){ return __expf(x); }
__device__ __forceinline__ u16 f2bf(float f){
    union { float f; unsigned u; } v; v.f = f;
    unsigned u = v.u;
    return (u16)((u + 0x7FFFu + ((u >> 16) & 1u)) >> 16);
}
__device__ __forceinline__ float bf2f(u16 b){
    union { unsigned u; float f; } v; v.u = ((unsigned)b) << 16; return v.f;
}
__device__ __forceinline__ float2 bf2x(unsigned p){
    union { unsigned u; float f; } a, b;
    a.u = (p & 0xFFFFu) << 16; b.u = p & 0xFFFF0000u;
    return make_float2(a.f, b.f);
}
__device__ __forceinline__ unsigned cvt2(float a, float b){
    unsigned r; asm("v_cvt_pk_bf16_f32 %0, %1, %2" : "=v"(r) : "v"(a), "v"(b)); return r;
}
// ---- fp8 e4m3 (OCP) HW conversions ----
__device__ __forceinline__ unsigned enc_fp8x4(float a, float b, float c, float d){
    int r = __builtin_amdgcn_cvt_pk_fp8_f32(a, b, 0, false);
    r = __builtin_amdgcn_cvt_pk_fp8_f32(c, d, r, true);
    return (unsigned)r;
}

// ============ A-fragment loads ============
__device__ __forceinline__ void load_af32(const float* __restrict__ X, int row, int lk, bf8_t* af){
    #pragma unroll
    for (int kk = 0; kk < 4; ++kk){
        const float* p = X + (size_t)row*128 + kk*32 + lk*8;
        float4 a = *(const float4*)p;
        float4 b = *(const float4*)(p+4);
        union { bf8_t v; unsigned u[4]; } r;
        r.u[0] = cvt2(a.x, a.y); r.u[1] = cvt2(a.z, a.w);
        r.u[2] = cvt2(b.x, b.y); r.u[3] = cvt2(b.z, b.w);
        af[kk] = r.v;
    }
}
__device__ __forceinline__ void load_af16(const u16* __restrict__ X, int row, int lk, bf8_t* af){
    #pragma unroll
    for (int kk = 0; kk < 4; ++kk)
        af[kk] = *(const bf8_t*)(X + (size_t)row*128 + kk*32 + lk*8);
}

// ============ LDS weight staging ============
__device__ __forceinline__ void stage_w(const u16* __restrict__ src, u16* __restrict__ wl, int tid){
    #pragma unroll
    for (int j = 0; j < 8; ++j){
        int o = (j*256 + tid)*8;
        bf8_t v = *(const bf8_t*)(src + o);
        *(bf8_t*)(wl + ((o>>7)*WLP + (o&127))) = v;
    }
}

// ============ MFMA from LDS-staged weights ============
__device__ __forceinline__ void mfma_l2(const bf8_t* af0, const bf8_t* af1,
                                        const u16* __restrict__ wl,
                                        int lr, int lk, f32x4* acc0, f32x4* acc1){
    #pragma unroll
    for (int i = 0; i < 8; ++i){ acc0[i] = (f32x4){0.f,0.f,0.f,0.f}; acc1[i] = (f32x4){0.f,0.f,0.f,0.f}; }
    #pragma unroll
    for (int kk = 0; kk < 4; ++kk){
        bf8_t B[8];
        #pragma unroll
        for (int nt = 0; nt < 8; ++nt)
            B[nt] = *(const bf8_t*)&wl[(nt*16+lr)*WLP + kk*32 + lk*8];
        #pragma unroll
        for (int nt = 0; nt < 8; ++nt){
            acc0[nt] = __builtin_amdgcn_mfma_f32_16x16x32_bf16(af0[kk], B[nt], acc0[nt], 0, 0, 0);
            acc1[nt] = __builtin_amdgcn_mfma_f32_16x16x32_bf16(af1[kk], B[nt], acc1[nt], 0, 0, 0);
        }
    }
}
// ============ dense MFMA direct from GLOBAL (batched B loads) ============
__device__ __forceinline__ void mfma_g1(const bf8_t* af, const u16* __restrict__ Wp,
                                        int lr, int lk, f32x4* acc){
    #pragma unroll
    for (int i = 0; i < 8; ++i) acc[i] = (f32x4){0.f,0.f,0.f,0.f};
    #pragma unroll
    for (int kk = 0; kk < 4; ++kk){
        bf8_t B[8];
        #pragma unroll
        for (int nt = 0; nt < 8; ++nt)
            B[nt] = *(const bf8_t*)&Wp[(nt*16+lr)*128 + kk*32 + lk*8];
        #pragma unroll
        for (int nt = 0; nt < 8; ++nt)
            acc[nt] = __builtin_amdgcn_mfma_f32_16x16x32_bf16(af[kk], B[nt], acc[nt], 0, 0, 0);
    }
}
// ============ block-diagonal MFMA: packed B [8 nt][16 lr][32 k] from GLOBAL ============
__device__ __forceinline__ void mfma_bd1_acc(const bf8_t* af, const u16* __restrict__ Bp,
                                             int lr, int lk, f32x4* acc){
    bf8_t B[8];
    #pragma unroll
    for (int nt = 0; nt < 8; ++nt)
        B[nt] = *(const bf8_t*)&Bp[nt*512 + lr*32 + lk*8];
    #pragma unroll
    for (int nt = 0; nt < 8; ++nt)
        acc[nt] = __builtin_amdgcn_mfma_f32_16x16x32_bf16(af[nt>>1], B[nt], acc[nt], 0, 0, 0);
}
__device__ __forceinline__ void mfma_bd2(const bf8_t* af0, const bf8_t* af1,
                                         const u16* __restrict__ Bp,
                                         int lr, int lk, f32x4* acc0, f32x4* acc1){
    bf8_t B[8];
    #pragma unroll
    for (int nt = 0; nt < 8; ++nt)
        B[nt] = *(const bf8_t*)&Bp[nt*512 + lr*32 + lk*8];
    #pragma unroll
    for (int nt = 0; nt < 8; ++nt){
        acc0[nt] = __builtin_amdgcn_mfma_f32_16x16x32_bf16(af0[nt>>1], B[nt], (f32x4){0.f,0.f,0.f,0.f}, 0, 0, 0);
        acc1[nt] = __builtin_amdgcn_mfma_f32_16x16x32_bf16(af1[nt>>1], B[nt], (f32x4){0.f,0.f,0.f,0.f}, 0, 0, 0);
    }
}

// ============ per-wave LDS transpose buffer ============
__device__ __forceinline__ void acc_to_tb(u16 (*tbw)[TBW], const f32x4* acc, int lr, int lk, const float* bias){
    asm volatile("s_waitcnt lgkmcnt(0)" ::: "memory");
    #pragma unroll
    for (int nt = 0; nt < 8; ++nt){
        int col = nt*16 + lr;
        float badd = bias ? bias[col] : 0.f;
        #pragma unroll
        for (int i = 0; i < 4; ++i) tbw[lk*4+i][col] = f2bf(acc[nt][i] + badd);
    }
    asm volatile("s_waitcnt lgkmcnt(0)" ::: "memory");
}
__device__ __forceinline__ void acc_to_tb_gelu(u16 (*tbw)[TBW], const f32x4* acc, int lr, int lk){
    asm volatile("s_waitcnt lgkmcnt(0)" ::: "memory");
    #pragma unroll
    for (int nt = 0; nt < 8; ++nt){
        int col = nt*16 + lr;
        #pragma unroll
        for (int i = 0; i < 4; ++i) tbw[lk*4+i][col] = f2bf(gelu_exact(acc[nt][i]));
    }
    asm volatile("s_waitcnt lgkmcnt(0)" ::: "memory");
}
__device__ __forceinline__ void tb_store(const u16 (*tbw)[TBW], u16* __restrict__ O, size_t rowstride, int rowbase, int lr, int lk){
    #pragma unroll
    for (int c = 0; c < 4; ++c){
        bf8_t v = *(const bf8_t*)&tbw[c*4+lk][lr*8];
        *(bf8_t*)(O + (size_t)(rowbase + c*4 + lk)*rowstride + lr*8) = v;
    }
}
// fp8 store: rowstride in BYTES
__device__ __forceinline__ void tb_store_fp8(const u16 (*tbw)[TBW], u8* __restrict__ O, size_t rowstride, int rowbase, int lr, int lk){
    #pragma unroll
    for (int c = 0; c < 4; ++c){
        bf8_t v = *(const bf8_t*)&tbw[c*4+lk][lr*8];
        float f[8];
        #pragma unroll
        for (int j = 0; j < 8; ++j) f[j] = bf2f((u16)v[j]);
        uint2 o2;
        o2.x = enc_fp8x4(f[0], f[1], f[2], f[3]);
        o2.y = enc_fp8x4(f[4], f[5], f[6], f[7]);
        *(uint2*)(O + (size_t)(rowbase + c*4 + lk)*rowstride + lr*8) = o2;
    }
}
__device__ __forceinline__ void tb_frags(const u16 (*tbw)[TBW], int lr, int lk, bf8_t* ha){
    #pragma unroll
    for (int kk = 0; kk < 4; ++kk) ha[kk] = *(const bf8_t*)&tbw[lr][kk*32 + lk*8];
}
__device__ __forceinline__ void tb_rows(const u16 (*tbw)[TBW], int lr, int lk, bf8_t* rw){
    #pragma unroll
    for (int c = 0; c < 4; ++c) rw[c] = *(const bf8_t*)&tbw[c*4+lk][lr*8];
}

// ============ x_cell f32 -> bf16 one-time cast ============
__global__ __launch_bounds__(256) void xcast_k(const float* __restrict__ X, u16* __restrict__ O){
    size_t gid = (size_t)blockIdx.x*256 + threadIdx.x;
    const float* p = X + gid*8;
    float4 a = *(const float4*)p;
    float4 b = *(const float4*)(p+4);
    union { bf8_t v; unsigned u[4]; } r;
    r.u[0] = cvt2(a.x, a.y); r.u[1] = cvt2(a.z, a.w);
    r.u[2] = cvt2(b.x, b.y); r.u[3] = cvt2(b.z, b.w);
    *(bf8_t*)(O + gid*8) = r.v;
}

// ============ weight pre-pack ============
__global__ __launch_bounds__(256) void wpack_k(
    const float* __restrict__ g1W, const float* __restrict__ g2W,
    const float* __restrict__ Wk, const float* __restrict__ Wq, const float* __restrict__ Wv,
    const float* __restrict__ Wo, const float* __restrict__ injW,
    const float* __restrict__ arel, const float* __restrict__ mrel,
    const float* __restrict__ g1as, const float* __restrict__ g1ad,
    const float* __restrict__ g2as, const float* __restrict__ g2ad,
    u16* __restrict__ wp, u16* __restrict__ wpa)
{
    int b = blockIdx.x, tid = threadIdx.x;
    if (b < 11) {
        const float* src;
        if (b < 3) src = g1W + b*16384;
        else if (b < 6) src = g2W + (b-3)*16384;
        else if (b == 6) src = Wk;
        else if (b == 7) src = Wq;
        else if (b == 8) src = Wv;
        else if (b == 9) src = Wo;
        else src = injW;
        u16* dst = wp + (size_t)b*16384;
        for (int idx = tid; idx < 16384; idx += 256) {
            int n = idx >> 7, k = idx & 127;
            dst[idx] = f2bf(src[k*128 + n]);
        }
    } else if (b < 17) {
        int rel2 = (b < 14);
        const float* src = rel2 ? (arel + (b-11)*4096) : (mrel + (b-14)*4096);
        u16* dst = wp + (size_t)11*16384 + (size_t)(b-11)*4096;
        for (int idx = tid; idx < 4096; idx += 256) {
            int nt = idx >> 9, rest = idx & 511;
            int lr = rest >> 5, kp = rest & 31;
            int h = nt >> 1, c = (nt & 1)*16 + lr;
            float v = rel2 ? src[h*1024 + c*32 + kp] : src[h*1024 + kp*32 + c];
            dst[idx] = f2bf(v);
        }
    } else {
        for (int idx = tid; idx < 6*2048; idx += 256) {
            int m = idx >> 11;
            int j = idx & 2047;
            int cg = j >> 7, k = j & 127;
            const float* as = (m < 3) ? g1as : g2as;
            const float* ad = (m < 3) ? g1ad : g2ad;
            int t = (m < 3) ? m : m - 3;
            float v = 0.f;
            if (cg < 4)      { if ((k>>5)==cg)   v = as[t*128 + cg*32 + (k&31)]; }
            else if (cg < 8) { int g = cg-4; if ((k>>5)==g) v = ad[t*128 + g*32 + (k&31)]; }
            wpa[idx] = f2bf(v);
        }
    }
}

// ============ GAT projection: grid (512 rowblocks x 3 types), bf16 input ============
__global__ __launch_bounds__(256, 3) void gat_gemm3_k(const u16* __restrict__ Xb,
    const u16* __restrict__ wpg, const u16* __restrict__ wpa,
    u16* __restrict__ hb, float* __restrict__ alsb, float* __restrict__ aldb)
{
    __shared__ __align__(16) u16 wl[128*WLP];
    __shared__ __align__(16) u16 tb[4][16][TBW];
    const int tid = threadIdx.x, wave = tid>>6, lane = tid&63, lr = lane&15, lk = lane>>4;
    const int t = blockIdx.y;
    const int rw0 = blockIdx.x*128 + wave*32;
    bf8_t af0[4], af1[4];
    load_af16(Xb, rw0 + lr, lk, af0);
    load_af16(Xb, rw0 + 16 + lr, lk, af1);
    stage_w(wpg + t*16384, wl, tid);
    bf8_t Ba[4];
    #pragma unroll
    for (int kk = 0; kk < 4; ++kk)
        Ba[kk] = *(const bf8_t*)&wpa[t*2048 + lr*128 + kk*32 + lk*8];
    __syncthreads();
    f32x4 acc0[8], acc1[8];
    mfma_l2(af0, af1, wl, lr, lk, acc0, acc1);
    u16* h = hb + (size_t)t*ND;
    float* alst = alsb + (size_t)t*NN*4;
    float* aldt = aldb + (size_t)t*NN*4;
    {
        acc_to_tb(tb[wave], acc0, lr, lk, nullptr);
        tb_store(tb[wave], h, 128, rw0, lr, lk);
        bf8_t ha[4]; tb_frags(tb[wave], lr, lk, ha);
        f32x4 a2 = (f32x4){0.f,0.f,0.f,0.f};
        #pragma unroll
        for (int kk = 0; kk < 4; ++kk)
            a2 = __builtin_amdgcn_mfma_f32_16x16x32_bf16(ha[kk], Ba[kk], a2, 0, 0, 0);
        if (lr < 8){
            float* dp = (lr < 4) ? alst : aldt;
            int g = lr & 3;
            #pragma unroll
            for (int i = 0; i < 4; ++i) dp[(size_t)(rw0 + lk*4 + i)*4 + g] = a2[i];
        }
    }
    {
        acc_to_tb(tb[wave], acc1, lr, lk, nullptr);
        tb_store(tb[wave], h, 128, rw0 + 16, lr, lk);
        bf8_t ha[4]; tb_frags(tb[wave], lr, lk, ha);
        f32x4 a2 = (f32x4){0.f,0.f,0.f,0.f};
        #pragma unroll
        for (int kk = 0; kk < 4; ++kk)
            a2 = __builtin_amdgcn_mfma_f32_16x16x32_bf16(ha[kk], Ba[kk], a2, 0, 0, 0);
        if (lr < 8){
            float* dp = (lr < 4) ? alst : aldt;
            int g = lr & 3;
            #pragma unroll
            for (int i = 0; i < 4; ++i) dp[(size_t)(rw0 + 16 + lk*4 + i)*4 + g] = a2[i];
        }
    }
}

// ============ HGT projections: grid (512 rowblocks x 5 tasks); kv fp8 ============
__global__ __launch_bounds__(256, 3) void hgt_proj_k(const u16* __restrict__ X,
    const u16* __restrict__ wpk, const u16* __restrict__ wpq, const u16* __restrict__ wpv,
    const u16* __restrict__ wpad,
    const float* __restrict__ bk, const float* __restrict__ bq, const float* __restrict__ bv,
    u8* __restrict__ kvb, u16* __restrict__ qtb)
{
    __shared__ __align__(16) u16 wl[128*WLP];
    __shared__ __align__(16) u16 tb[4][16][TBW];
    const int tid = threadIdx.x, wave = tid>>6, lane = tid&63, lr = lane&15, lk = lane>>4;
    const int task = blockIdx.y;
    const int rw0 = blockIdx.x*128 + wave*32;
    bf8_t af0[4], af1[4];
    load_af16(X, rw0 + lr, lk, af0);
    load_af16(X, rw0 + 16 + lr, lk, af1);
    f32x4 acc0[8], acc1[8];
    if (task == 0) {
        stage_w(wpk, wl, tid);
        __syncthreads();
        mfma_l2(af0, af1, wl, lr, lk, acc0, acc1);
        acc_to_tb(tb[wave], acc0, lr, lk, bk); tb_store_fp8(tb[wave], kvb, 256, rw0, lr, lk);
        acc_to_tb(tb[wave], acc1, lr, lk, bk); tb_store_fp8(tb[wave], kvb, 256, rw0 + 16, lr, lk);
    } else if (task == 1) {
        stage_w(wpv, wl, tid);
        __syncthreads();
        mfma_l2(af0, af1, wl, lr, lk, acc0, acc1);
        acc_to_tb(tb[wave], acc0, lr, lk, bv); tb_store_fp8(tb[wave], kvb + 128, 256, rw0, lr, lk);
        acc_to_tb(tb[wave], acc1, lr, lk, bv); tb_store_fp8(tb[wave], kvb + 128, 256, rw0 + 16, lr, lk);
    } else {
        const int t = task - 2;
        stage_w(wpq, wl, tid);
        __syncthreads();
        mfma_l2(af0, af1, wl, lr, lk, acc0, acc1);
        bf8_t ha0[4], ha1[4];
        acc_to_tb(tb[wave], acc0, lr, lk, bq); tb_frags(tb[wave], lr, lk, ha0);
        acc_to_tb(tb[wave], acc1, lr, lk, bq); tb_frags(tb[wave], lr, lk, ha1);
        mfma_bd2(ha0, ha1, wpad + t*4096, lr, lk, acc0, acc1);
        u16* o = qtb + (size_t)t*ND;
        acc_to_tb(tb[wave], acc0, lr, lk, nullptr); tb_store(tb[wave], o, 128, rw0, lr, lk);
        acc_to_tb(tb[wave], acc1, lr, lk, nullptr); tb_store(tb[wave], o, 128, rw0 + 16, lr, lk);
    }
}

// ================= type-sorted merged CSR with self-loop slots =================
__global__ __launch_bounds__(256) void hist_k(const int* __restrict__ ei, int* __restrict__ cnt){
    int gid = blockIdx.x*256 + threadIdx.x;
    int t = gid / EE, e = gid - t*EE;
    int d = ei[t*2*EE + EE + e];
    atomicAdd(&cnt[t*NN + d], 1);
}
__global__ __launch_bounds__(256) void scanA_k(const int* __restrict__ cnt, int* __restrict__ s0off, int* __restrict__ parts){
    __shared__ int sums[256];
    int b = blockIdx.x; int base = b * 1024;
    int tid = threadIdx.x;
    int v[4]; int tsum = 0;
    #pragma unroll
    for (int i = 0; i < 4; ++i){
        int n = base + tid*4 + i;
        v[i] = cnt[n] + cnt[NN+n] + cnt[2*NN+n] + 3;
        tsum += v[i];
    }
    sums[tid] = tsum; __syncthreads();
    for (int ofs = 1; ofs < 256; ofs <<= 1) {
        int a = (tid >= ofs) ? sums[tid-ofs] : 0;
        __syncthreads();
        sums[tid] += a;
        __syncthreads();
    }
    int run = sums[tid] - tsum;
    #pragma unroll
    for (int i = 0; i < 4; ++i){ s0off[base + tid*4 + i] = run; run += v[i]; }
    if (tid == 255) parts[b] = sums[255];
}
__global__ void scan2_k(int* parts){
    if (threadIdx.x == 0 && blockIdx.x == 0) {
        int run = 0;
        for (int i = 0; i < 64; ++i) { int v = parts[i]; parts[i] = run; run += v; }
    }
}
__global__ __launch_bounds__(256) void scanB_k(const int* __restrict__ cnt, int* __restrict__ s0off,
                                               int* __restrict__ s1off, int* __restrict__ s2off,
                                               const int* __restrict__ parts){
    int b = blockIdx.x; int base = b * 1024;
    int add = parts[b];
    #pragma unroll
    for (int i = 0; i < 4; ++i){
        int n = base + threadIdx.x*4 + i;
        int m = s0off[n] + add;
        int c0 = cnt[n], c1 = cnt[NN+n];
        s0off[n] = m;
        s1off[n] = m + c0 + 1;
        s2off[n] = m + c0 + c1 + 2;
    }
    if (b == 0 && threadIdx.x == 0) s0off[NN] = CSRN;
}
__global__ __launch_bounds__(256) void selffill_k(const int* __restrict__ s0off, const int* __restrict__ s1off,
                                                  const int* __restrict__ s2off, int* __restrict__ csrc){
    int gid = blockIdx.x*256 + threadIdx.x;
    int t = gid / NN, n = gid - t*NN;
    int pos = (t==0) ? s0off[n] : (t==1 ? s1off[n] : s2off[n]);
    csrc[pos] = n;
}
__global__ __launch_bounds__(256) void scatter_k(const int* __restrict__ ei,
    const int* __restrict__ s0off, const int* __restrict__ s1off, const int* __restrict__ s2off,
    int* __restrict__ cur, int* __restrict__ csrc, int* __restrict__ posmap){
    int gid = blockIdx.x*256 + threadIdx.x;
    int t = gid / EE, e = gid - t*EE;
    int s = ei[t*2*EE + e];
    int d = ei[t*2*EE + EE + e];
    int p = atomicAdd(&cur[t*NN + d], 1);
    int basep = (t==0) ? s0off[d] : (t==1 ? s1off[d] : s2off[d]);
    int pos = basep + 1 + p;
    csrc[pos] = s;
    posmap[t*EE + e] = pos;
}

// ============ per-edge alpha precompute (GAT layer) ============
__global__ __launch_bounds__(256) void alpha_k(const float* __restrict__ alsb, const float* __restrict__ aldb,
    const int* __restrict__ ei, const int* __restrict__ posmap,
    const int* __restrict__ s0off, const int* __restrict__ s1off, const int* __restrict__ s2off,
    float4* __restrict__ ab)
{
    int gid = blockIdx.x*256 + threadIdx.x;
    int t = gid / NTOT, r = gid - t*NTOT;
    int s, d, pos;
    if (r < EE) {
        s = ei[t*2*EE + r];
        d = ei[t*2*EE + EE + r];
        pos = posmap[t*EE + r];
    } else {
        int n = r - EE;
        s = n; d = n;
        pos = (t==0) ? s0off[n] : (t==1 ? s1off[n] : s2off[n]);
    }
    const float* As = alsb + ((size_t)t*NN + s)*4;
    const float* Ad = aldb + ((size_t)t*NN + d)*4;
    float4 o;
    o.x = fexp(lrelu(As[0] + Ad[0]));
    o.y = fexp(lrelu(As[1] + Ad[1]));
    o.z = fexp(lrelu(As[2] + Ad[2]));
    o.w = fexp(lrelu(As[3] + Ad[3]));
    ab[pos] = o;
}

// ============ GAT aggregate: 4ch/lane, 2 edges/wave ============
__global__ __launch_bounds__(256) void gat_aggres_k(const u16* __restrict__ hb,
    const float* __restrict__ abf,
    const int* __restrict__ s0off, const int* __restrict__ s1off, const int* __restrict__ s2off,
    const int* __restrict__ csrc,
    const float* __restrict__ bias3, const u16* __restrict__ xoldb,
    const float* __restrict__ scale, u16* __restrict__ outb)
{
    int gid = blockIdx.x*256 + threadIdx.x;
    int node = gid >> 6, lane = gid & 63;
    int eh = lane >> 5, hh = (lane >> 3) & 3, cp = lane & 7;
    int ch = hh*32 + cp*4;
    int segb[4] = { s0off[node], s1off[node], s2off[node], s0off[node+1] };
    float a[4] = {0.f, 0.f, 0.f, 0.f};
    #pragma unroll
    for (int t = 0; t < 3; ++t) {
        const u16* h = hb + (size_t)t*ND;
        int beg = segb[t], end = segb[t+1];
        float ds = 0.f, s0 = 0.f, s1 = 0.f, s2 = 0.f, s3 = 0.f;
        for (int pos = beg; pos < end; pos += 4) {
            int p0 = pos + eh, p1 = pos + 2 + eh;
            int v0 = (p0 < end), v1 = (p1 < end);
            int q0 = v0 ? p0 : beg, q1 = v1 ? p1 : beg;
            int sA = csrc[q0], sB = csrc[q1];
            float alA = abf[(size_t)q0*4 + hh];
            float alB = abf[(size_t)q1*4 + hh];
            uint2 hA = *(const uint2*)&h[(size_t)sA*128 + ch];
            uint2 hB = *(const uint2*)&h[(size_t)sB*128 + ch];
            alA = v0 ? alA : 0.f;
            alB = v1 ? alB : 0.f;
            float2 wA0 = bf2x(hA.x), wA1 = bf2x(hA.y);
            float2 wB0 = bf2x(hB.x), wB1 = bf2x(hB.y);
            ds += alA + alB;
            s0 += alA*wA0.x + alB*wB0.x;
            s1 += alA*wA0.y + alB*wB0.y;
            s2 += alA*wA1.x + alB*wB1.x;
            s3 += alA*wA1.y + alB*wB1.y;
        }
        ds += __shfl_xor(ds, 32);
        s0 += __shfl_xor(s0, 32);
        s1 += __shfl_xor(s1, 32);
        s2 += __shfl_xor(s2, 32);
        s3 += __shfl_xor(s3, 32);
        float inv = 1.f/(ds + 1e-16f);
        a[0] += s0*inv; a[1] += s1*inv; a[2] += s2*inv; a[3] += s3*inv;
    }
    float4 b0 = *(const float4*)&bias3[ch];
    float4 b1 = *(const float4*)&bias3[128 + ch];
    float4 b2 = *(const float4*)&bias3[256 + ch];
    a[0] += b0.x + b1.x + b2.x;
    a[1] += b0.y + b1.y + b2.y;
    a[2] += b0.z + b1.z + b2.z;
    a[3] += b0.w + b1.w + b2.w;
    float ssum = a[0]*a[0] + a[1]*a[1] + a[2]*a[2] + a[3]*a[3];
    ssum += __shfl_xor(ssum, 1); ssum += __shfl_xor(ssum, 2);
    ssum += __shfl_xor(ssum, 4); ssum += __shfl_xor(ssum, 8);
    ssum += __shfl_xor(ssum, 16);
    float r = rsqrtf(ssum*(1.f/128.f) + 1e-6f);
    float4 sc = *(const float4*)&scale[ch];
    size_t off = (size_t)node*128 + ch;
    uint2 xo = *(const uint2*)&xoldb[off];
    float2 p0 = bf2x(xo.x), p1 = bf2x(xo.y);
    float y0 = lrelu(p0.x + sc.x*a[0]*r);
    float y1 = lrelu(p0.y + sc.y*a[1]*r);
    float y2 = lrelu(p1.x + sc.z*a[2]*r);
    float y3 = lrelu(p1.y + sc.w*a[3]*r);
    uint2 o2; o2.x = cvt2(y0, y1); o2.y = cvt2(y2, y3);
    *(uint2*)&outb[off] = o2;
}

// ============ HGT aggregate: fp8 kv, 4ch/lane, 2 edges/wave, 8-lane dot reduce ============
__global__ __launch_bounds__(256) void hgt_agg_k(const u8* __restrict__ kvb,
    const u16* __restrict__ qtb, const float* __restrict__ prel,
    const int* __restrict__ s0off, const int* __restrict__ s1off, const int* __restrict__ s2off,
    const int* __restrict__ csrc, u16* __restrict__ pb)
{
    int gid = blockIdx.x*256 + threadIdx.x;
    int node = gid >> 6, lane = gid & 63;
    int eh = lane >> 5, hh = (lane >> 3) & 3, cp = lane & 7;
    int ch = hh*32 + cp*4;
    const float S = 0.17677669529663689f; // 1/sqrt(32)
    int segb[4] = { s0off[node], s1off[node], s2off[node], s0off[node+1] };
    float dsum = 0.f;
    float ac[3][4];
    #pragma unroll
    for (int t = 0; t < 3; ++t){ ac[t][0]=0.f; ac[t][1]=0.f; ac[t][2]=0.f; ac[t][3]=0.f; }
    #pragma unroll
    for (int t = 0; t < 3; ++t) {
        float ph = prel[t*4 + hh] * S;
        uint2 qw = *(const uint2*)&qtb[(size_t)t*ND + (size_t)node*128 + ch];
        float2 q0 = bf2x(qw.x), q1 = bf2x(qw.y);
        int self = segb[t];
        int beg = self + 1, end = segb[t+1];
        for (int pos = beg; pos < end; pos += 4) {
            int p0 = pos + eh, p1 = pos + 2 + eh;
            int v0 = (p0 < end), v1 = (p1 < end);
            int qp0 = v0 ? p0 : self, qp1 = v1 ? p1 : self;
            int sA = csrc[qp0], sB = csrc[qp1];
            size_t rA = (size_t)sA*256 + ch, rB = (size_t)sB*256 + ch;
            unsigned kA = *(const unsigned*)&kvb[rA], kB = *(const unsigned*)&kvb[rB];
            unsigned vA = *(const unsigned*)&kvb[rA + 128], vB = *(const unsigned*)&kvb[rB + 128];
            f32x2 kA0 = __builtin_amdgcn_cvt_pk_f32_fp8((int)kA, false);
            f32x2 kA1 = __builtin_amdgcn_cvt_pk_f32_fp8((int)kA, true);
            f32x2 kB0 = __builtin_amdgcn_cvt_pk_f32_fp8((int)kB, false);
            f32x2 kB1 = __builtin_amdgcn_cvt_pk_f32_fp8((int)kB, true);
            float scA = kA0[0]*q0.x + kA0[1]*q0.y + kA1[0]*q1.x + kA1[1]*q1.y;
            float scB = kB0[0]*q0.x + kB0[1]*q0.y + kB1[0]*q1.x + kB1[1]*q1.y;
            scA += __shfl_xor(scA, 1); scB += __shfl_xor(scB, 1);
            scA += __shfl_xor(scA, 2); scB += __shfl_xor(scB, 2);
            scA += __shfl_xor(scA, 4); scB += __shfl_xor(scB, 4);
            float eA = v0 ? fexp(scA*ph) : 0.f;
            float eB = v1 ? fexp(scB*ph) : 0.f;
            f32x2 vA0 = __builtin_amdgcn_cvt_pk_f32_fp8((int)vA, false);
            f32x2 vA1 = __builtin_amdgcn_cvt_pk_f32_fp8((int)vA, true);
            f32x2 vB0 = __builtin_amdgcn_cvt_pk_f32_fp8((int)vB, false);
            f32x2 vB1 = __builtin_amdgcn_cvt_pk_f32_fp8((int)vB, true);
            dsum += eA + eB;
            ac[t][0] += eA*vA0[0] + eB*vB0[0];
            ac[t][1] += eA*vA0[1] + eB*vB0[1];
            ac[t][2] += eA*vA1[0] + eB*vB1[0];
            ac[t][3] += eA*vA1[1] + eB*vB1[1];
        }
    }
    dsum += __shfl_xor(dsum, 32);
    #pragma unroll
    for (int t = 0; t < 3; ++t){
        ac[t][0] += __shfl_xor(ac[t][0], 32);
        ac[t][1] += __shfl_xor(ac[t][1], 32);
        ac[t][2] += __shfl_xor(ac[t][2], 32);
        ac[t][3] += __shfl_xor(ac[t][3], 32);
    }
    float inv = 1.f/(dsum + 1e-16f);
    size_t o = (size_t)node*128 + ch;
    #pragma unroll
    for (int t = 0; t < 3; ++t){
        uint2 o2;
        o2.x = cvt2(ac[t][0]*inv, ac[t][1]*inv);
        o2.y = cvt2(ac[t][2]*inv, ac[t][3]*inv);
        *(uint2*)&pb[(size_t)t*ND + o] = o2;
    }
}

// ============ final: all B direct from global; ZERO barriers; tb-only LDS ============
__global__ __launch_bounds__(256, 4) void final_k(const u16* __restrict__ pb,
    const u16* __restrict__ wpmd, const u16* __restrict__ wpo, const float* __restrict__ bo,
    const u16* __restrict__ x2b, const float* __restrict__ skipp, const float* __restrict__ scale,
    const float* __restrict__ xemb, const u16* __restrict__ wpinj, const float* __restrict__ injb,
    const float* __restrict__ gbuf, const int* __restrict__ bszp,
    float* __restrict__ out)
{
    __shared__ __align__(16) u16 tb[4][16][TBW];
    const int tid = threadIdx.x, wave = tid>>6, lane = tid&63, lr = lane&15, lk = lane>>4;
    const int rw = blockIdx.x*64 + wave*16;
    bf8_t e0[4];
    load_af32(xemb, rw + lr, lk, e0);
    // ---- agg_pre = Σ_t partial_t @ M_t (block-diag packed, direct global B) ----
    f32x4 acc[8];
    #pragma unroll
    for (int i = 0; i < 8; ++i) acc[i] = (f32x4){0.f,0.f,0.f,0.f};
    #pragma unroll
    for (int t = 0; t < 3; ++t){
        bf8_t a0[4]; load_af16(pb + (size_t)t*ND, rw + lr, lk, a0);
        mfma_bd1_acc(a0, wpmd + t*4096, lr, lk, acc);
    }
    // ---- gelu -> tb -> A-frags ----
    bf8_t ga[4];
    acc_to_tb_gelu(tb[wave], acc, lr, lk);
    tb_frags(tb[wave], lr, lk, ga);
    // ---- Wo GEMM (direct global B) ----
    mfma_g1(ga, wpo, lr, lk, acc);
    bf8_t hw[4];
    acc_to_tb(tb[wave], acc, lr, lk, bo);
    tb_rows(tb[wave], lr, lk, hw);
    // ---- inject GEMM (direct global B) ----
    mfma_g1(e0, wpinj, lr, lk, acc);
    bf8_t in[4];
    acc_to_tb(tb[wave], acc, lr, lk, injb);
    tb_rows(tb[wave], lr, lk, in);
    // ---- vectorized row-major epilogue ----
    const float sig = 1.f/(1.f + expf(-skipp[0]));
    const int cpb = NN / *bszp;
    float4 sca = *(const float4*)&scale[lr*8];
    float4 scb = *(const float4*)&scale[lr*8 + 4];
    #pragma unroll
    for (int c = 0; c < 4; ++c){
        int row = rw + c*4 + lk;
        bf8_t x8 = *(const bf8_t*)(x2b + (size_t)row*128 + lr*8);
        float x[8], v[8];
        float ssl = 0.f;
        #pragma unroll
        for (int j = 0; j < 8; ++j){
            x[j] = bf2f((u16)x8[j]);
            float h = bf2f((u16)hw[c][j]);
            v[j] = sig*h + (1.f - sig)*x[j];
            ssl += v[j]*v[j];
        }
        ssl += __shfl_xor(ssl, 1); ssl += __shfl_xor(ssl, 2);
        ssl += __shfl_xor(ssl, 4); ssl += __shfl_xor(ssl, 8);
        float rq = rsqrtf(ssl*(1.f/128.f) + 1e-6f);
        const float* gr = gbuf + (row / cpb)*256;
        float4 g0 = *(const float4*)&gr[lr*8];
        float4 g1 = *(const float4*)&gr[lr*8 + 4];
        float4 b0 = *(const float4*)&gr[128 + lr*8];
        float4 b1 = *(const float4*)&gr[128 + lr*8 + 4];
        float4 oA, oB;
        #pragma unroll
        for (int j = 0; j < 8; ++j){
            float scj = (j < 4) ? ((const float*)&sca)[j] : ((const float*)&scb)[j-4];
            float y = lrelu(x[j] + scj*v[j]*rq);
            float hf = y + bf2f((u16)in[c][j]);
            float gj = (j < 4) ? ((const float*)&g0)[j] : ((const float*)&g1)[j-4];
            float bj = (j < 4) ? ((const float*)&b0)[j] : ((const float*)&b1)[j-4];
            float ov = (1.f + gj)*hf + bj;
            if (j < 4) ((float*)&oA)[j] = ov; else ((float*)&oB)[j-4] = ov;
        }
        *(float4*)(out + (size_t)row*128 + lr*8)     = oA;
        *(float4*)(out + (size_t)row*128 + lr*8 + 4) = oB;
    }
}

// ============ FiLM small MLP ============
__global__ __launch_bounds__(256) void film_k(const float* __restrict__ z,
    const float* __restrict__ W1, const float* __restrict__ b1,
    const float* __restrict__ W2, const float* __restrict__ b2,
    float* __restrict__ gb)
{
    __shared__ float zr[128];
    __shared__ float g1[256];
    int r = blockIdx.x, tid = threadIdx.x;
    if (tid < 128) zr[tid] = z[r*128 + tid];
    __syncthreads();
    float s = b1[tid];
    for (int k = 0; k < 128; ++k) s += zr[k]*W1[k*256 + tid];
    g1[tid] = gelu_exact(s);
    __syncthreads();
    float s2 = b2[tid];
    for (int k = 0; k < 256; ++k) s2 += g1[k]*W2[k*256 + tid];
    gb[r*256 + tid] = 0.1f*tanhf(s2);
}

// ================= launch =================
extern "C" void kernel_launch(void* const* d_in, const int* in_sizes, int n_in,
                              void* d_out, int out_size, void* d_ws, size_t ws_size,
                              hipStream_t stream)
{
    const float* x_cell = (const float*)d_in[0];
    const float* z_h    = (const float*)d_in[1];
    const float* x_emb  = (const float*)d_in[2];
    const int*   eidx   = (const int*)d_in[3];
    const int*   bszp   = (const int*)d_in[4];
    const float* g1W  = (const float*)d_in[5];
    const float* g1as = (const float*)d_in[6];
    const float* g1ad = (const float*)d_in[7];
    const float* g1b  = (const float*)d_in[8];
    const float* g2W  = (const float*)d_in[9];
    const float* g2as = (const float*)d_in[10];
    const float* g2ad = (const float*)d_in[11];
    const float* g2b  = (const float*)d_in[12];
    const float* n1s  = (const float*)d_in[13];
    const float* n2s  = (const float*)d_in[14];
    const float* n3s  = (const float*)d_in[15];
    const float* Wk   = (const float*)d_in[16];
    const float* bk   = (const float*)d_in[17];
    const float* Wq   = (const float*)d_in[18];
    const float* bq   = (const float*)d_in[19];
    const float* Wv   = (const float*)d_in[20];
    const float* bv   = (const float*)d_in[21];
    const float* arel = (const float*)d_in[22];
    const float* mrel = (const float*)d_in[23];
    const float* prel = (const float*)d_in[24];
    const float* Wo   = (const float*)d_in[25];
    const float* bo   = (const float*)d_in[26];
    const float* skipp= (const float*)d_in[27];
    const float* injW = (const float*)d_in[28];
    const float* injb = (const float*)d_in[29];
    const float* fW1  = (const float*)d_in[30];
    const float* fb1  = (const float*)d_in[31];
    const float* fW2  = (const float*)d_in[32];
    const float* fb2  = (const float*)d_in[33];

    // ---- workspace layout ----
    u16* wp   = (u16*)d_ws;                   // 17*16384 u16
    u16* wpa  = wp + (size_t)17*16384;        // 6*2048 u16
    float4* ab = (float4*)(wpa + 6*2048);     // CSRN float4
    u16* x0b  = (u16*)(ab + CSRN);            // ND u16 (x_cell bf16)
    u16* x1b  = x0b + ND;                     // ND u16
    u16* x2b  = x1b + ND;                     // ND u16
    u8*  kvb  = (u8*)(x2b + ND);              // NN*256 bytes (k|v fp8)
    u16* pb   = (u16*)(kvb + (size_t)NN*256); // 3*ND u16
    u16* hb   = pb + 3*ND;                    // 3*ND u16 (reused as qtb)
    float* alsb = (float*)(hb + 3*ND);        // 3*NN*4 f32
    float* aldb = alsb + (size_t)3*NN*4;      // 3*NN*4 f32
    float* gbuf = aldb + (size_t)3*NN*4;      // 32*256 f32
    int* s0off  = (int*)(gbuf + 32*256);      // NN+1
    int* s1off  = s0off + (NN+1);             // NN
    int* s2off  = s1off + NN;                 // NN
    int* csrc   = s2off + NN;                 // CSRN
    int* posmap = csrc + CSRN;                // 3*EE
    int* tmpc   = posmap + 3*EE;              // 3*NN (cnt)
    int* cur    = tmpc + 3*NN;                // 3*NN
    int* parts  = cur + 3*NN;                 // 256

    u16* qtb = hb;
    float* outp = (float*)d_out;

    const u16* wpg1 = wp;
    const u16* wpg2 = wp + (size_t)3*16384;
    const u16* wpk  = wp + (size_t)6*16384;
    const u16* wpq  = wp + (size_t)7*16384;
    const u16* wpv  = wp + (size_t)8*16384;
    const u16* wpo  = wp + (size_t)9*16384;
    const u16* wpinj= wp + (size_t)10*16384;
    const u16* wpad = wp + (size_t)11*16384;            // packed arel [3][4096]
    const u16* wpmd = wpad + (size_t)3*4096;            // packed mrel [3][4096]

    // ---- weight pre-pack + x_cell cast ----
    wpack_k<<<18, 256, 0, stream>>>(g1W, g2W, Wk, Wq, Wv, Wo, injW, arel, mrel,
                                    g1as, g1ad, g2as, g2ad, wp, wpa);
    xcast_k<<<(int)(ND/2048), 256, 0, stream>>>(x_cell, x0b);

    // ---- type-sorted merged CSR with self slots ----
    hipMemsetAsync(tmpc, 0, 3*NN*sizeof(int), stream);
    hist_k<<<3*EE/256, 256, 0, stream>>>(eidx, tmpc);
    scanA_k<<<64, 256, 0, stream>>>(tmpc, s0off, parts);
    scan2_k<<<1, 64, 0, stream>>>(parts);
    scanB_k<<<64, 256, 0, stream>>>(tmpc, s0off, s1off, s2off, parts);
    selffill_k<<<3*NN/256, 256, 0, stream>>>(s0off, s1off, s2off, csrc);
    hipMemsetAsync(cur, 0, 3*NN*sizeof(int), stream);
    scatter_k<<<3*EE/256, 256, 0, stream>>>(eidx, s0off, s1off, s2off, cur, csrc, posmap);

    // ---- FiLM small MLP ----
    int B = in_sizes[1] / 128;
    film_k<<<B, 256, 0, stream>>>(z_h, fW1, fb1, fW2, fb2, gbuf);

    // ---- GAT layer 1 ----
    gat_gemm3_k<<<dim3(512,3), 256, 0, stream>>>(x0b, wpg1, wpa, hb, alsb, aldb);
    alpha_k<<<3*NTOT/256, 256, 0, stream>>>(alsb, aldb, eidx, posmap, s0off, s1off, s2off, ab);
    gat_aggres_k<<<16384, 256, 0, stream>>>(hb, (const float*)ab, s0off, s1off, s2off, csrc,
                                            g1b, x0b, n1s, x1b);

    // ---- GAT layer 2 ----
    gat_gemm3_k<<<dim3(512,3), 256, 0, stream>>>(x1b, wpg2, wpa + 3*2048, hb, alsb, aldb);
    alpha_k<<<3*NTOT/256, 256, 0, stream>>>(alsb, aldb, eidx, posmap, s0off, s1off, s2off, ab);
    gat_aggres_k<<<16384, 256, 0, stream>>>(hb, (const float*)ab, s0off, s1off, s2off, csrc,
                                            g2b, x1b, n2s, x2b);

    // ---- HGT ----
    hgt_proj_k<<<dim3(512,5), 256, 0, stream>>>(x2b, wpk, wpq, wpv, wpad,
                                                bk, bq, bv, kvb, qtb);
    hgt_agg_k<<<16384, 256, 0, stream>>>(kvb, qtb, prel, s0off, s1off, s2off, csrc, pb);

    // ---- final ----
    final_k<<<1024, 256, 0, stream>>>(pb, wpmd, wpo, bo, x2b, skipp, n3s,
                                      x_emb, wpinj, injb, gbuf, bszp, outp);
}

// Round 19
// 544.155 us; speedup vs baseline: 1.0259x; 1.0259x over previous
//
#include <hip/hip_runtime.h>

#define NN 65536
#define EE 262144
#define ND ((size_t)NN * 128)
#define TBW 132
#define WLP 136   // LDS weight pitch (u16)
#define NTOT (EE + NN)          // edges + selfs per type
#define CSRN (3*EE + 3*NN)      // total CSR slots

typedef unsigned short u16;
typedef unsigned char u8;
typedef short bf8_t __attribute__((ext_vector_type(8)));
typedef float f32x4 __attribute__((ext_vector_type(4)));
typedef float f32x2 __attribute__((ext_vector_type(2)));

__device__ __forceinline__ float lrelu(float x){ return x > 0.f ? x : 0.2f*x; }
__device__ __forceinline__ float gelu_exact(float x){ return 0.5f*x*(1.f+erff(x*0.70710678118654752f)); }
__device__ __forceinline__ float fexp(float x){ return __expf(x); }
__device__ __forceinline__ u16 f2bf(float f){
    union { float f; unsigned u; } v; v.f = f;
    unsigned u = v.u;
    return (u16)((u + 0x7FFFu + ((u >> 16) & 1u)) >> 16);
}
__device__ __forceinline__ float bf2f(u16 b){
    union { unsigned u; float f; } v; v.u = ((unsigned)b) << 16; return v.f;
}
__device__ __forceinline__ float2 bf2x(unsigned p){
    union { unsigned u; float f; } a, b;
    a.u = (p & 0xFFFFu) << 16; b.u = p & 0xFFFF0000u;
    return make_float2(a.f, b.f);
}
__device__ __forceinline__ unsigned cvt2(float a, float b){
    unsigned r; asm("v_cvt_pk_bf16_f32 %0, %1, %2" : "=v"(r) : "v"(a), "v"(b)); return r;
}
// ---- fp8 e4m3 (OCP) HW conversions ----
__device__ __forceinline__ unsigned enc_fp8x4(float a, float b, float c, float d){
    int r = __builtin_amdgcn_cvt_pk_fp8_f32(a, b, 0, false);
    r = __builtin_amdgcn_cvt_pk_fp8_f32(c, d, r, true);
    return (unsigned)r;
}

// ============ A-fragment loads ============
__device__ __forceinline__ void load_af32(const float* __restrict__ X, int row, int lk, bf8_t* af){
    #pragma unroll
    for (int kk = 0; kk < 4; ++kk){
        const float* p = X + (size_t)row*128 + kk*32 + lk*8;
        float4 a = *(const float4*)p;
        float4 b = *(const float4*)(p+4);
        union { bf8_t v; unsigned u[4]; } r;
        r.u[0] = cvt2(a.x, a.y); r.u[1] = cvt2(a.z, a.w);
        r.u[2] = cvt2(b.x, b.y); r.u[3] = cvt2(b.z, b.w);
        af[kk] = r.v;
    }
}
__device__ __forceinline__ void load_af16(const u16* __restrict__ X, int row, int lk, bf8_t* af){
    #pragma unroll
    for (int kk = 0; kk < 4; ++kk)
        af[kk] = *(const bf8_t*)(X + (size_t)row*128 + kk*32 + lk*8);
}

// ============ LDS weight staging ============
__device__ __forceinline__ void stage_w(const u16* __restrict__ src, u16* __restrict__ wl, int tid){
    #pragma unroll
    for (int j = 0; j < 8; ++j){
        int o = (j*256 + tid)*8;
        bf8_t v = *(const bf8_t*)(src + o);
        *(bf8_t*)(wl + ((o>>7)*WLP + (o&127))) = v;
    }
}

// ============ MFMA from LDS-staged weights ============
__device__ __forceinline__ void mfma_l1(const bf8_t* af, const u16* __restrict__ wl,
                                        int lr, int lk, f32x4* acc){
    #pragma unroll
    for (int i = 0; i < 8; ++i) acc[i] = (f32x4){0.f,0.f,0.f,0.f};
    #pragma unroll
    for (int kk = 0; kk < 4; ++kk){
        bf8_t B[8];
        #pragma unroll
        for (int nt = 0; nt < 8; ++nt)
            B[nt] = *(const bf8_t*)&wl[(nt*16+lr)*WLP + kk*32 + lk*8];
        #pragma unroll
        for (int nt = 0; nt < 8; ++nt)
            acc[nt] = __builtin_amdgcn_mfma_f32_16x16x32_bf16(af[kk], B[nt], acc[nt], 0, 0, 0);
    }
}
__device__ __forceinline__ void mfma_l2(const bf8_t* af0, const bf8_t* af1,
                                        const u16* __restrict__ wl,
                                        int lr, int lk, f32x4* acc0, f32x4* acc1){
    #pragma unroll
    for (int i = 0; i < 8; ++i){ acc0[i] = (f32x4){0.f,0.f,0.f,0.f}; acc1[i] = (f32x4){0.f,0.f,0.f,0.f}; }
    #pragma unroll
    for (int kk = 0; kk < 4; ++kk){
        bf8_t B[8];
        #pragma unroll
        for (int nt = 0; nt < 8; ++nt)
            B[nt] = *(const bf8_t*)&wl[(nt*16+lr)*WLP + kk*32 + lk*8];
        #pragma unroll
        for (int nt = 0; nt < 8; ++nt){
            acc0[nt] = __builtin_amdgcn_mfma_f32_16x16x32_bf16(af0[kk], B[nt], acc0[nt], 0, 0, 0);
            acc1[nt] = __builtin_amdgcn_mfma_f32_16x16x32_bf16(af1[kk], B[nt], acc1[nt], 0, 0, 0);
        }
    }
}
// ============ block-diagonal MFMA: packed B [8 nt][16 lr][32 k] from GLOBAL ============
__device__ __forceinline__ void mfma_bd1_acc(const bf8_t* af, const u16* __restrict__ Bp,
                                             int lr, int lk, f32x4* acc){
    bf8_t B[8];
    #pragma unroll
    for (int nt = 0; nt < 8; ++nt)
        B[nt] = *(const bf8_t*)&Bp[nt*512 + lr*32 + lk*8];
    #pragma unroll
    for (int nt = 0; nt < 8; ++nt)
        acc[nt] = __builtin_amdgcn_mfma_f32_16x16x32_bf16(af[nt>>1], B[nt], acc[nt], 0, 0, 0);
}
__device__ __forceinline__ void mfma_bd2(const bf8_t* af0, const bf8_t* af1,
                                         const u16* __restrict__ Bp,
                                         int lr, int lk, f32x4* acc0, f32x4* acc1){
    bf8_t B[8];
    #pragma unroll
    for (int nt = 0; nt < 8; ++nt)
        B[nt] = *(const bf8_t*)&Bp[nt*512 + lr*32 + lk*8];
    #pragma unroll
    for (int nt = 0; nt < 8; ++nt){
        acc0[nt] = __builtin_amdgcn_mfma_f32_16x16x32_bf16(af0[nt>>1], B[nt], (f32x4){0.f,0.f,0.f,0.f}, 0, 0, 0);
        acc1[nt] = __builtin_amdgcn_mfma_f32_16x16x32_bf16(af1[nt>>1], B[nt], (f32x4){0.f,0.f,0.f,0.f}, 0, 0, 0);
    }
}

// ============ per-wave LDS transpose buffer ============
__device__ __forceinline__ void acc_to_tb(u16 (*tbw)[TBW], const f32x4* acc, int lr, int lk, const float* bias){
    asm volatile("s_waitcnt lgkmcnt(0)" ::: "memory");
    #pragma unroll
    for (int nt = 0; nt < 8; ++nt){
        int col = nt*16 + lr;
        float badd = bias ? bias[col] : 0.f;
        #pragma unroll
        for (int i = 0; i < 4; ++i) tbw[lk*4+i][col] = f2bf(acc[nt][i] + badd);
    }
    asm volatile("s_waitcnt lgkmcnt(0)" ::: "memory");
}
__device__ __forceinline__ void acc_to_tb_gelu(u16 (*tbw)[TBW], const f32x4* acc, int lr, int lk){
    asm volatile("s_waitcnt lgkmcnt(0)" ::: "memory");
    #pragma unroll
    for (int nt = 0; nt < 8; ++nt){
        int col = nt*16 + lr;
        #pragma unroll
        for (int i = 0; i < 4; ++i) tbw[lk*4+i][col] = f2bf(gelu_exact(acc[nt][i]));
    }
    asm volatile("s_waitcnt lgkmcnt(0)" ::: "memory");
}
__device__ __forceinline__ void tb_store(const u16 (*tbw)[TBW], u16* __restrict__ O, size_t rowstride, int rowbase, int lr, int lk){
    #pragma unroll
    for (int c = 0; c < 4; ++c){
        bf8_t v = *(const bf8_t*)&tbw[c*4+lk][lr*8];
        *(bf8_t*)(O + (size_t)(rowbase + c*4 + lk)*rowstride + lr*8) = v;
    }
}
// fp8 store: rowstride in BYTES
__device__ __forceinline__ void tb_store_fp8(const u16 (*tbw)[TBW], u8* __restrict__ O, size_t rowstride, int rowbase, int lr, int lk){
    #pragma unroll
    for (int c = 0; c < 4; ++c){
        bf8_t v = *(const bf8_t*)&tbw[c*4+lk][lr*8];
        float f[8];
        #pragma unroll
        for (int j = 0; j < 8; ++j) f[j] = bf2f((u16)v[j]);
        uint2 o2;
        o2.x = enc_fp8x4(f[0], f[1], f[2], f[3]);
        o2.y = enc_fp8x4(f[4], f[5], f[6], f[7]);
        *(uint2*)(O + (size_t)(rowbase + c*4 + lk)*rowstride + lr*8) = o2;
    }
}
__device__ __forceinline__ void tb_frags(const u16 (*tbw)[TBW], int lr, int lk, bf8_t* ha){
    #pragma unroll
    for (int kk = 0; kk < 4; ++kk) ha[kk] = *(const bf8_t*)&tbw[lr][kk*32 + lk*8];
}
__device__ __forceinline__ void tb_rows(const u16 (*tbw)[TBW], int lr, int lk, bf8_t* rw){
    #pragma unroll
    for (int c = 0; c < 4; ++c) rw[c] = *(const bf8_t*)&tbw[c*4+lk][lr*8];
}

// ============ x_cell f32 -> bf16 one-time cast ============
__global__ __launch_bounds__(256) void xcast_k(const float* __restrict__ X, u16* __restrict__ O){
    size_t gid = (size_t)blockIdx.x*256 + threadIdx.x;
    const float* p = X + gid*8;
    float4 a = *(const float4*)p;
    float4 b = *(const float4*)(p+4);
    union { bf8_t v; unsigned u[4]; } r;
    r.u[0] = cvt2(a.x, a.y); r.u[1] = cvt2(a.z, a.w);
    r.u[2] = cvt2(b.x, b.y); r.u[3] = cvt2(b.z, b.w);
    *(bf8_t*)(O + gid*8) = r.v;
}

// ============ weight pre-pack ============
__global__ __launch_bounds__(256) void wpack_k(
    const float* __restrict__ g1W, const float* __restrict__ g2W,
    const float* __restrict__ Wk, const float* __restrict__ Wq, const float* __restrict__ Wv,
    const float* __restrict__ Wo, const float* __restrict__ injW,
    const float* __restrict__ arel, const float* __restrict__ mrel,
    const float* __restrict__ g1as, const float* __restrict__ g1ad,
    const float* __restrict__ g2as, const float* __restrict__ g2ad,
    u16* __restrict__ wp, u16* __restrict__ wpa)
{
    int b = blockIdx.x, tid = threadIdx.x;
    if (b < 11) {
        const float* src;
        if (b < 3) src = g1W + b*16384;
        else if (b < 6) src = g2W + (b-3)*16384;
        else if (b == 6) src = Wk;
        else if (b == 7) src = Wq;
        else if (b == 8) src = Wv;
        else if (b == 9) src = Wo;
        else src = injW;
        u16* dst = wp + (size_t)b*16384;
        for (int idx = tid; idx < 16384; idx += 256) {
            int n = idx >> 7, k = idx & 127;
            dst[idx] = f2bf(src[k*128 + n]);
        }
    } else if (b < 17) {
        int rel2 = (b < 14);
        const float* src = rel2 ? (arel + (b-11)*4096) : (mrel + (b-14)*4096);
        u16* dst = wp + (size_t)11*16384 + (size_t)(b-11)*4096;
        for (int idx = tid; idx < 4096; idx += 256) {
            int nt = idx >> 9, rest = idx & 511;
            int lr = rest >> 5, kp = rest & 31;
            int h = nt >> 1, c = (nt & 1)*16 + lr;
            float v = rel2 ? src[h*1024 + c*32 + kp] : src[h*1024 + kp*32 + c];
            dst[idx] = f2bf(v);
        }
    } else {
        for (int idx = tid; idx < 6*2048; idx += 256) {
            int m = idx >> 11;
            int j = idx & 2047;
            int cg = j >> 7, k = j & 127;
            const float* as = (m < 3) ? g1as : g2as;
            const float* ad = (m < 3) ? g1ad : g2ad;
            int t = (m < 3) ? m : m - 3;
            float v = 0.f;
            if (cg < 4)      { if ((k>>5)==cg)   v = as[t*128 + cg*32 + (k&31)]; }
            else if (cg < 8) { int g = cg-4; if ((k>>5)==g) v = ad[t*128 + g*32 + (k&31)]; }
            wpa[idx] = f2bf(v);
        }
    }
}

// ============ GAT projection: grid (512 rowblocks x 3 types), bf16 input ============
__global__ __launch_bounds__(256, 3) void gat_gemm3_k(const u16* __restrict__ Xb,
    const u16* __restrict__ wpg, const u16* __restrict__ wpa,
    u16* __restrict__ hb, float* __restrict__ alsb, float* __restrict__ aldb)
{
    __shared__ __align__(16) u16 wl[128*WLP];
    __shared__ __align__(16) u16 tb[4][16][TBW];
    const int tid = threadIdx.x, wave = tid>>6, lane = tid&63, lr = lane&15, lk = lane>>4;
    const int t = blockIdx.y;
    const int rw0 = blockIdx.x*128 + wave*32;
    bf8_t af0[4], af1[4];
    load_af16(Xb, rw0 + lr, lk, af0);
    load_af16(Xb, rw0 + 16 + lr, lk, af1);
    stage_w(wpg + t*16384, wl, tid);
    bf8_t Ba[4];
    #pragma unroll
    for (int kk = 0; kk < 4; ++kk)
        Ba[kk] = *(const bf8_t*)&wpa[t*2048 + lr*128 + kk*32 + lk*8];
    __syncthreads();
    f32x4 acc0[8], acc1[8];
    mfma_l2(af0, af1, wl, lr, lk, acc0, acc1);
    u16* h = hb + (size_t)t*ND;
    float* alst = alsb + (size_t)t*NN*4;
    float* aldt = aldb + (size_t)t*NN*4;
    {
        acc_to_tb(tb[wave], acc0, lr, lk, nullptr);
        tb_store(tb[wave], h, 128, rw0, lr, lk);
        bf8_t ha[4]; tb_frags(tb[wave], lr, lk, ha);
        f32x4 a2 = (f32x4){0.f,0.f,0.f,0.f};
        #pragma unroll
        for (int kk = 0; kk < 4; ++kk)
            a2 = __builtin_amdgcn_mfma_f32_16x16x32_bf16(ha[kk], Ba[kk], a2, 0, 0, 0);
        if (lr < 8){
            float* dp = (lr < 4) ? alst : aldt;
            int g = lr & 3;
            #pragma unroll
            for (int i = 0; i < 4; ++i) dp[(size_t)(rw0 + lk*4 + i)*4 + g] = a2[i];
        }
    }
    {
        acc_to_tb(tb[wave], acc1, lr, lk, nullptr);
        tb_store(tb[wave], h, 128, rw0 + 16, lr, lk);
        bf8_t ha[4]; tb_frags(tb[wave], lr, lk, ha);
        f32x4 a2 = (f32x4){0.f,0.f,0.f,0.f};
        #pragma unroll
        for (int kk = 0; kk < 4; ++kk)
            a2 = __builtin_amdgcn_mfma_f32_16x16x32_bf16(ha[kk], Ba[kk], a2, 0, 0, 0);
        if (lr < 8){
            float* dp = (lr < 4) ? alst : aldt;
            int g = lr & 3;
            #pragma unroll
            for (int i = 0; i < 4; ++i) dp[(size_t)(rw0 + 16 + lk*4 + i)*4 + g] = a2[i];
        }
    }
}

// ============ HGT projections + inject: grid (512 rowblocks x 6 tasks) ============
// task 0: k -> kv[:,0:128] fp8 | 1: v -> kv[:,128:256] fp8 | 2: inj = xemb@injW + injb -> injv bf16
// task 3..5: qt_t = (x@Wq + bq) @ A_t^T -> qtb
__global__ __launch_bounds__(256, 3) void hgt_proj_k(const u16* __restrict__ X,
    const u16* __restrict__ wpk, const u16* __restrict__ wpq, const u16* __restrict__ wpv,
    const u16* __restrict__ wpad, const u16* __restrict__ wpinj, const float* __restrict__ xembf,
    const float* __restrict__ bk, const float* __restrict__ bq, const float* __restrict__ bv,
    const float* __restrict__ injb,
    u8* __restrict__ kvb, u16* __restrict__ qtb, u16* __restrict__ injv)
{
    __shared__ __align__(16) u16 wl[128*WLP];
    __shared__ __align__(16) u16 tb[4][16][TBW];
    const int tid = threadIdx.x, wave = tid>>6, lane = tid&63, lr = lane&15, lk = lane>>4;
    const int task = blockIdx.y;
    const int rw0 = blockIdx.x*128 + wave*32;
    f32x4 acc0[8], acc1[8];
    if (task == 2) {
        bf8_t e0[4], e1[4];
        load_af32(xembf, rw0 + lr, lk, e0);
        load_af32(xembf, rw0 + 16 + lr, lk, e1);
        stage_w(wpinj, wl, tid);
        __syncthreads();
        mfma_l2(e0, e1, wl, lr, lk, acc0, acc1);
        acc_to_tb(tb[wave], acc0, lr, lk, injb); tb_store(tb[wave], injv, 128, rw0, lr, lk);
        acc_to_tb(tb[wave], acc1, lr, lk, injb); tb_store(tb[wave], injv, 128, rw0 + 16, lr, lk);
        return;
    }
    bf8_t af0[4], af1[4];
    load_af16(X, rw0 + lr, lk, af0);
    load_af16(X, rw0 + 16 + lr, lk, af1);
    if (task == 0) {
        stage_w(wpk, wl, tid);
        __syncthreads();
        mfma_l2(af0, af1, wl, lr, lk, acc0, acc1);
        acc_to_tb(tb[wave], acc0, lr, lk, bk); tb_store_fp8(tb[wave], kvb, 256, rw0, lr, lk);
        acc_to_tb(tb[wave], acc1, lr, lk, bk); tb_store_fp8(tb[wave], kvb, 256, rw0 + 16, lr, lk);
    } else if (task == 1) {
        stage_w(wpv, wl, tid);
        __syncthreads();
        mfma_l2(af0, af1, wl, lr, lk, acc0, acc1);
        acc_to_tb(tb[wave], acc0, lr, lk, bv); tb_store_fp8(tb[wave], kvb + 128, 256, rw0, lr, lk);
        acc_to_tb(tb[wave], acc1, lr, lk, bv); tb_store_fp8(tb[wave], kvb + 128, 256, rw0 + 16, lr, lk);
    } else {
        const int t = task - 3;
        stage_w(wpq, wl, tid);
        __syncthreads();
        mfma_l2(af0, af1, wl, lr, lk, acc0, acc1);
        bf8_t ha0[4], ha1[4];
        acc_to_tb(tb[wave], acc0, lr, lk, bq); tb_frags(tb[wave], lr, lk, ha0);
        acc_to_tb(tb[wave], acc1, lr, lk, bq); tb_frags(tb[wave], lr, lk, ha1);
        mfma_bd2(ha0, ha1, wpad + t*4096, lr, lk, acc0, acc1);
        u16* o = qtb + (size_t)t*ND;
        acc_to_tb(tb[wave], acc0, lr, lk, nullptr); tb_store(tb[wave], o, 128, rw0, lr, lk);
        acc_to_tb(tb[wave], acc1, lr, lk, nullptr); tb_store(tb[wave], o, 128, rw0 + 16, lr, lk);
    }
}

// ================= type-sorted merged CSR with self-loop slots =================
__global__ __launch_bounds__(256) void hist_k(const int* __restrict__ ei, int* __restrict__ cnt){
    int gid = blockIdx.x*256 + threadIdx.x;
    int t = gid / EE, e = gid - t*EE;
    int d = ei[t*2*EE + EE + e];
    atomicAdd(&cnt[t*NN + d], 1);
}
__global__ __launch_bounds__(256) void scanA_k(const int* __restrict__ cnt, int* __restrict__ s0off, int* __restrict__ parts){
    __shared__ int sums[256];
    int b = blockIdx.x; int base = b * 1024;
    int tid = threadIdx.x;
    int v[4]; int tsum = 0;
    #pragma unroll
    for (int i = 0; i < 4; ++i){
        int n = base + tid*4 + i;
        v[i] = cnt[n] + cnt[NN+n] + cnt[2*NN+n] + 3;
        tsum += v[i];
    }
    sums[tid] = tsum; __syncthreads();
    for (int ofs = 1; ofs < 256; ofs <<= 1) {
        int a = (tid >= ofs) ? sums[tid-ofs] : 0;
        __syncthreads();
        sums[tid] += a;
        __syncthreads();
    }
    int run = sums[tid] - tsum;
    #pragma unroll
    for (int i = 0; i < 4; ++i){ s0off[base + tid*4 + i] = run; run += v[i]; }
    if (tid == 255) parts[b] = sums[255];
}
__global__ void scan2_k(int* parts){
    if (threadIdx.x == 0 && blockIdx.x == 0) {
        int run = 0;
        for (int i = 0; i < 64; ++i) { int v = parts[i]; parts[i] = run; run += v; }
    }
}
__global__ __launch_bounds__(256) void scanB_k(const int* __restrict__ cnt, int* __restrict__ s0off,
                                               int* __restrict__ s1off, int* __restrict__ s2off,
                                               const int* __restrict__ parts){
    int b = blockIdx.x; int base = b * 1024;
    int add = parts[b];
    #pragma unroll
    for (int i = 0; i < 4; ++i){
        int n = base + threadIdx.x*4 + i;
        int m = s0off[n] + add;
        int c0 = cnt[n], c1 = cnt[NN+n];
        s0off[n] = m;
        s1off[n] = m + c0 + 1;
        s2off[n] = m + c0 + c1 + 2;
    }
    if (b == 0 && threadIdx.x == 0) s0off[NN] = CSRN;
}
__global__ __launch_bounds__(256) void selffill_k(const int* __restrict__ s0off, const int* __restrict__ s1off,
                                                  const int* __restrict__ s2off, int* __restrict__ csrc){
    int gid = blockIdx.x*256 + threadIdx.x;
    int t = gid / NN, n = gid - t*NN;
    int pos = (t==0) ? s0off[n] : (t==1 ? s1off[n] : s2off[n]);
    csrc[pos] = n;
}
__global__ __launch_bounds__(256) void scatter_k(const int* __restrict__ ei,
    const int* __restrict__ s0off, const int* __restrict__ s1off, const int* __restrict__ s2off,
    int* __restrict__ cur, int* __restrict__ csrc, int* __restrict__ posmap){
    int gid = blockIdx.x*256 + threadIdx.x;
    int t = gid / EE, e = gid - t*EE;
    int s = ei[t*2*EE + e];
    int d = ei[t*2*EE + EE + e];
    int p = atomicAdd(&cur[t*NN + d], 1);
    int basep = (t==0) ? s0off[d] : (t==1 ? s1off[d] : s2off[d]);
    int pos = basep + 1 + p;
    csrc[pos] = s;
    posmap[t*EE + e] = pos;
}

// ============ per-edge alpha precompute (GAT layer) ============
__global__ __launch_bounds__(256) void alpha_k(const float* __restrict__ alsb, const float* __restrict__ aldb,
    const int* __restrict__ ei, const int* __restrict__ posmap,
    const int* __restrict__ s0off, const int* __restrict__ s1off, const int* __restrict__ s2off,
    float4* __restrict__ ab)
{
    int gid = blockIdx.x*256 + threadIdx.x;
    int t = gid / NTOT, r = gid - t*NTOT;
    int s, d, pos;
    if (r < EE) {
        s = ei[t*2*EE + r];
        d = ei[t*2*EE + EE + r];
        pos = posmap[t*EE + r];
    } else {
        int n = r - EE;
        s = n; d = n;
        pos = (t==0) ? s0off[n] : (t==1 ? s1off[n] : s2off[n]);
    }
    const float* As = alsb + ((size_t)t*NN + s)*4;
    const float* Ad = aldb + ((size_t)t*NN + d)*4;
    float4 o;
    o.x = fexp(lrelu(As[0] + Ad[0]));
    o.y = fexp(lrelu(As[1] + Ad[1]));
    o.z = fexp(lrelu(As[2] + Ad[2]));
    o.w = fexp(lrelu(As[3] + Ad[3]));
    ab[pos] = o;
}

// ============ GAT aggregate: 4ch/lane, 2 edges/wave ============
__global__ __launch_bounds__(256) void gat_aggres_k(const u16* __restrict__ hb,
    const float* __restrict__ abf,
    const int* __restrict__ s0off, const int* __restrict__ s1off, const int* __restrict__ s2off,
    const int* __restrict__ csrc,
    const float* __restrict__ bias3, const u16* __restrict__ xoldb,
    const float* __restrict__ scale, u16* __restrict__ outb)
{
    int gid = blockIdx.x*256 + threadIdx.x;
    int node = gid >> 6, lane = gid & 63;
    int eh = lane >> 5, hh = (lane >> 3) & 3, cp = lane & 7;
    int ch = hh*32 + cp*4;
    int segb[4] = { s0off[node], s1off[node], s2off[node], s0off[node+1] };
    float a[4] = {0.f, 0.f, 0.f, 0.f};
    #pragma unroll
    for (int t = 0; t < 3; ++t) {
        const u16* h = hb + (size_t)t*ND;
        int beg = segb[t], end = segb[t+1];
        float ds = 0.f, s0 = 0.f, s1 = 0.f, s2 = 0.f, s3 = 0.f;
        for (int pos = beg; pos < end; pos += 4) {
            int p0 = pos + eh, p1 = pos + 2 + eh;
            int v0 = (p0 < end), v1 = (p1 < end);
            int q0 = v0 ? p0 : beg, q1 = v1 ? p1 : beg;
            int sA = csrc[q0], sB = csrc[q1];
            float alA = abf[(size_t)q0*4 + hh];
            float alB = abf[(size_t)q1*4 + hh];
            uint2 hA = *(const uint2*)&h[(size_t)sA*128 + ch];
            uint2 hB = *(const uint2*)&h[(size_t)sB*128 + ch];
            alA = v0 ? alA : 0.f;
            alB = v1 ? alB : 0.f;
            float2 wA0 = bf2x(hA.x), wA1 = bf2x(hA.y);
            float2 wB0 = bf2x(hB.x), wB1 = bf2x(hB.y);
            ds += alA + alB;
            s0 += alA*wA0.x + alB*wB0.x;
            s1 += alA*wA0.y + alB*wB0.y;
            s2 += alA*wA1.x + alB*wB1.x;
            s3 += alA*wA1.y + alB*wB1.y;
        }
        ds += __shfl_xor(ds, 32);
        s0 += __shfl_xor(s0, 32);
        s1 += __shfl_xor(s1, 32);
        s2 += __shfl_xor(s2, 32);
        s3 += __shfl_xor(s3, 32);
        float inv = 1.f/(ds + 1e-16f);
        a[0] += s0*inv; a[1] += s1*inv; a[2] += s2*inv; a[3] += s3*inv;
    }
    float4 b0 = *(const float4*)&bias3[ch];
    float4 b1 = *(const float4*)&bias3[128 + ch];
    float4 b2 = *(const float4*)&bias3[256 + ch];
    a[0] += b0.x + b1.x + b2.x;
    a[1] += b0.y + b1.y + b2.y;
    a[2] += b0.z + b1.z + b2.z;
    a[3] += b0.w + b1.w + b2.w;
    float ssum = a[0]*a[0] + a[1]*a[1] + a[2]*a[2] + a[3]*a[3];
    ssum += __shfl_xor(ssum, 1); ssum += __shfl_xor(ssum, 2);
    ssum += __shfl_xor(ssum, 4); ssum += __shfl_xor(ssum, 8);
    ssum += __shfl_xor(ssum, 16);
    float r = rsqrtf(ssum*(1.f/128.f) + 1e-6f);
    float4 sc = *(const float4*)&scale[ch];
    size_t off = (size_t)node*128 + ch;
    uint2 xo = *(const uint2*)&xoldb[off];
    float2 p0 = bf2x(xo.x), p1 = bf2x(xo.y);
    float y0 = lrelu(p0.x + sc.x*a[0]*r);
    float y1 = lrelu(p0.y + sc.y*a[1]*r);
    float y2 = lrelu(p1.x + sc.z*a[2]*r);
    float y3 = lrelu(p1.y + sc.w*a[3]*r);
    uint2 o2; o2.x = cvt2(y0, y1); o2.y = cvt2(y2, y3);
    *(uint2*)&outb[off] = o2;
}

// ============ HGT aggregate: fp8 kv, 4ch/lane, 2 edges/wave; pb interleaved [node][3][128] ============
__global__ __launch_bounds__(256) void hgt_agg_k(const u8* __restrict__ kvb,
    const u16* __restrict__ qtb, const float* __restrict__ prel,
    const int* __restrict__ s0off, const int* __restrict__ s1off, const int* __restrict__ s2off,
    const int* __restrict__ csrc, u16* __restrict__ pb)
{
    int gid = blockIdx.x*256 + threadIdx.x;
    int node = gid >> 6, lane = gid & 63;
    int eh = lane >> 5, hh = (lane >> 3) & 3, cp = lane & 7;
    int ch = hh*32 + cp*4;
    const float S = 0.17677669529663689f; // 1/sqrt(32)
    int segb[4] = { s0off[node], s1off[node], s2off[node], s0off[node+1] };
    float dsum = 0.f;
    float ac[3][4];
    #pragma unroll
    for (int t = 0; t < 3; ++t){ ac[t][0]=0.f; ac[t][1]=0.f; ac[t][2]=0.f; ac[t][3]=0.f; }
    #pragma unroll
    for (int t = 0; t < 3; ++t) {
        float ph = prel[t*4 + hh] * S;
        uint2 qw = *(const uint2*)&qtb[(size_t)t*ND + (size_t)node*128 + ch];
        float2 q0 = bf2x(qw.x), q1 = bf2x(qw.y);
        int self = segb[t];
        int beg = self + 1, end = segb[t+1];
        for (int pos = beg; pos < end; pos += 4) {
            int p0 = pos + eh, p1 = pos + 2 + eh;
            int v0 = (p0 < end), v1 = (p1 < end);
            int qp0 = v0 ? p0 : self, qp1 = v1 ? p1 : self;
            int sA = csrc[qp0], sB = csrc[qp1];
            size_t rA = (size_t)sA*256 + ch, rB = (size_t)sB*256 + ch;
            unsigned kA = *(const unsigned*)&kvb[rA], kB = *(const unsigned*)&kvb[rB];
            unsigned vA = *(const unsigned*)&kvb[rA + 128], vB = *(const unsigned*)&kvb[rB + 128];
            f32x2 kA0 = __builtin_amdgcn_cvt_pk_f32_fp8((int)kA, false);
            f32x2 kA1 = __builtin_amdgcn_cvt_pk_f32_fp8((int)kA, true);
            f32x2 kB0 = __builtin_amdgcn_cvt_pk_f32_fp8((int)kB, false);
            f32x2 kB1 = __builtin_amdgcn_cvt_pk_f32_fp8((int)kB, true);
            float scA = kA0[0]*q0.x + kA0[1]*q0.y + kA1[0]*q1.x + kA1[1]*q1.y;
            float scB = kB0[0]*q0.x + kB0[1]*q0.y + kB1[0]*q1.x + kB1[1]*q1.y;
            scA += __shfl_xor(scA, 1); scB += __shfl_xor(scB, 1);
            scA += __shfl_xor(scA, 2); scB += __shfl_xor(scB, 2);
            scA += __shfl_xor(scA, 4); scB += __shfl_xor(scB, 4);
            float eA = v0 ? fexp(scA*ph) : 0.f;
            float eB = v1 ? fexp(scB*ph) : 0.f;
            f32x2 vA0 = __builtin_amdgcn_cvt_pk_f32_fp8((int)vA, false);
            f32x2 vA1 = __builtin_amdgcn_cvt_pk_f32_fp8((int)vA, true);
            f32x2 vB0 = __builtin_amdgcn_cvt_pk_f32_fp8((int)vB, false);
            f32x2 vB1 = __builtin_amdgcn_cvt_pk_f32_fp8((int)vB, true);
            dsum += eA + eB;
            ac[t][0] += eA*vA0[0] + eB*vB0[0];
            ac[t][1] += eA*vA0[1] + eB*vB0[1];
            ac[t][2] += eA*vA1[0] + eB*vB1[0];
            ac[t][3] += eA*vA1[1] + eB*vB1[1];
        }
    }
    dsum += __shfl_xor(dsum, 32);
    #pragma unroll
    for (int t = 0; t < 3; ++t){
        ac[t][0] += __shfl_xor(ac[t][0], 32);
        ac[t][1] += __shfl_xor(ac[t][1], 32);
        ac[t][2] += __shfl_xor(ac[t][2], 32);
        ac[t][3] += __shfl_xor(ac[t][3], 32);
    }
    float inv = 1.f/(dsum + 1e-16f);
    size_t o = (size_t)node*384 + ch;
    #pragma unroll
    for (int t = 0; t < 3; ++t){
        uint2 o2;
        o2.x = cvt2(ac[t][0]*inv, ac[t][1]*inv);
        o2.y = cvt2(ac[t][2]*inv, ac[t][3]*inv);
        *(uint2*)&pb[o + (size_t)t*128] = o2;
    }
}

// ============ final: M-stage (block-diag) + Wo (LDS) + epilogue w/ precomputed injv ============
__global__ __launch_bounds__(256, 3) void final_k(const u16* __restrict__ pb,
    const u16* __restrict__ wpmd, const u16* __restrict__ wpo, const float* __restrict__ bo,
    const u16* __restrict__ x2b, const float* __restrict__ skipp, const float* __restrict__ scale,
    const u16* __restrict__ injv,
    const float* __restrict__ gbuf, const int* __restrict__ bszp,
    float* __restrict__ out)
{
    __shared__ __align__(16) u16 wl[128*WLP];
    __shared__ __align__(16) u16 tb[4][16][TBW];
    const int tid = threadIdx.x, wave = tid>>6, lane = tid&63, lr = lane&15, lk = lane>>4;
    const int rw = blockIdx.x*64 + wave*16;
    stage_w(wpo, wl, tid);
    // ---- agg_pre = Σ_t partial_t @ M_t (interleaved pb, block-diag packed B) ----
    f32x4 acc[8];
    #pragma unroll
    for (int i = 0; i < 8; ++i) acc[i] = (f32x4){0.f,0.f,0.f,0.f};
    {
        const u16* pr = pb + (size_t)(rw + lr)*384;
        #pragma unroll
        for (int t = 0; t < 3; ++t){
            bf8_t a0[4];
            #pragma unroll
            for (int kk = 0; kk < 4; ++kk)
                a0[kk] = *(const bf8_t*)(pr + t*128 + kk*32 + lk*8);
            mfma_bd1_acc(a0, wpmd + t*4096, lr, lk, acc);
        }
    }
    // ---- gelu -> tb -> A-frags ----
    bf8_t ga[4];
    acc_to_tb_gelu(tb[wave], acc, lr, lk);
    tb_frags(tb[wave], lr, lk, ga);
    // ---- Wo GEMM (LDS-staged) ----
    __syncthreads();
    mfma_l1(ga, wl, lr, lk, acc);
    bf8_t hw[4];
    acc_to_tb(tb[wave], acc, lr, lk, bo);
    tb_rows(tb[wave], lr, lk, hw);
    // ---- vectorized row-major epilogue (+ precomputed injv) ----
    const float sig = 1.f/(1.f + expf(-skipp[0]));
    const int cpb = NN / *bszp;
    float4 sca = *(const float4*)&scale[lr*8];
    float4 scb = *(const float4*)&scale[lr*8 + 4];
    #pragma unroll
    for (int c = 0; c < 4; ++c){
        int row = rw + c*4 + lk;
        bf8_t x8 = *(const bf8_t*)(x2b + (size_t)row*128 + lr*8);
        bf8_t i8 = *(const bf8_t*)(injv + (size_t)row*128 + lr*8);
        float x[8], v[8];
        float ssl = 0.f;
        #pragma unroll
        for (int j = 0; j < 8; ++j){
            x[j] = bf2f((u16)x8[j]);
            float h = bf2f((u16)hw[c][j]);
            v[j] = sig*h + (1.f - sig)*x[j];
            ssl += v[j]*v[j];
        }
        ssl += __shfl_xor(ssl, 1); ssl += __shfl_xor(ssl, 2);
        ssl += __shfl_xor(ssl, 4); ssl += __shfl_xor(ssl, 8);
        float rq = rsqrtf(ssl*(1.f/128.f) + 1e-6f);
        const float* gr = gbuf + (row / cpb)*256;
        float4 g0 = *(const float4*)&gr[lr*8];
        float4 g1 = *(const float4*)&gr[lr*8 + 4];
        float4 b0 = *(const float4*)&gr[128 + lr*8];
        float4 b1 = *(const float4*)&gr[128 + lr*8 + 4];
        float4 oA, oB;
        #pragma unroll
        for (int j = 0; j < 8; ++j){
            float scj = (j < 4) ? ((const float*)&sca)[j] : ((const float*)&scb)[j-4];
            float y = lrelu(x[j] + scj*v[j]*rq);
            float hf = y + bf2f((u16)i8[j]);
            float gj = (j < 4) ? ((const float*)&g0)[j] : ((const float*)&g1)[j-4];
            float bj = (j < 4) ? ((const float*)&b0)[j] : ((const float*)&b1)[j-4];
            float ov = (1.f + gj)*hf + bj;
            if (j < 4) ((float*)&oA)[j] = ov; else ((float*)&oB)[j-4] = ov;
        }
        *(float4*)(out + (size_t)row*128 + lr*8)     = oA;
        *(float4*)(out + (size_t)row*128 + lr*8 + 4) = oB;
    }
}

// ============ FiLM small MLP ============
__global__ __launch_bounds__(256) void film_k(const float* __restrict__ z,
    const float* __restrict__ W1, const float* __restrict__ b1,
    const float* __restrict__ W2, const float* __restrict__ b2,
    float* __restrict__ gb)
{
    __shared__ float zr[128];
    __shared__ float g1[256];
    int r = blockIdx.x, tid = threadIdx.x;
    if (tid < 128) zr[tid] = z[r*128 + tid];
    __syncthreads();
    float s = b1[tid];
    for (int k = 0; k < 128; ++k) s += zr[k]*W1[k*256 + tid];
    g1[tid] = gelu_exact(s);
    __syncthreads();
    float s2 = b2[tid];
    for (int k = 0; k < 256; ++k) s2 += g1[k]*W2[k*256 + tid];
    gb[r*256 + tid] = 0.1f*tanhf(s2);
}

// ================= launch =================
extern "C" void kernel_launch(void* const* d_in, const int* in_sizes, int n_in,
                              void* d_out, int out_size, void* d_ws, size_t ws_size,
                              hipStream_t stream)
{
    const float* x_cell = (const float*)d_in[0];
    const float* z_h    = (const float*)d_in[1];
    const float* x_emb  = (const float*)d_in[2];
    const int*   eidx   = (const int*)d_in[3];
    const int*   bszp   = (const int*)d_in[4];
    const float* g1W  = (const float*)d_in[5];
    const float* g1as = (const float*)d_in[6];
    const float* g1ad = (const float*)d_in[7];
    const float* g1b  = (const float*)d_in[8];
    const float* g2W  = (const float*)d_in[9];
    const float* g2as = (const float*)d_in[10];
    const float* g2ad = (const float*)d_in[11];
    const float* g2b  = (const float*)d_in[12];
    const float* n1s  = (const float*)d_in[13];
    const float* n2s  = (const float*)d_in[14];
    const float* n3s  = (const float*)d_in[15];
    const float* Wk   = (const float*)d_in[16];
    const float* bk   = (const float*)d_in[17];
    const float* Wq   = (const float*)d_in[18];
    const float* bq   = (const float*)d_in[19];
    const float* Wv   = (const float*)d_in[20];
    const float* bv   = (const float*)d_in[21];
    const float* arel = (const float*)d_in[22];
    const float* mrel = (const float*)d_in[23];
    const float* prel = (const float*)d_in[24];
    const float* Wo   = (const float*)d_in[25];
    const float* bo   = (const float*)d_in[26];
    const float* skipp= (const float*)d_in[27];
    const float* injW = (const float*)d_in[28];
    const float* injb = (const float*)d_in[29];
    const float* fW1  = (const float*)d_in[30];
    const float* fb1  = (const float*)d_in[31];
    const float* fW2  = (const float*)d_in[32];
    const float* fb2  = (const float*)d_in[33];

    // ---- workspace layout ----
    u16* wp   = (u16*)d_ws;                   // 17*16384 u16
    u16* wpa  = wp + (size_t)17*16384;        // 6*2048 u16
    float4* ab = (float4*)(wpa + 6*2048);     // CSRN float4
    u16* x0b  = (u16*)(ab + CSRN);            // ND u16 (x_cell bf16)
    u16* x1b  = x0b + ND;                     // ND u16
    u16* x2b  = x1b + ND;                     // ND u16
    u8*  kvb  = (u8*)(x2b + ND);              // NN*256 bytes (k|v fp8)
    u16* pb   = (u16*)(kvb + (size_t)NN*256); // 3*ND u16 (interleaved [node][3][128])
    u16* hb   = pb + 3*ND;                    // 3*ND u16 (reused as qtb)
    u16* injv = hb + 3*ND;                    // ND u16 (inject result, bias folded)
    float* alsb = (float*)(injv + ND);        // 3*NN*4 f32
    float* aldb = alsb + (size_t)3*NN*4;      // 3*NN*4 f32
    float* gbuf = aldb + (size_t)3*NN*4;      // 32*256 f32
    int* s0off  = (int*)(gbuf + 32*256);      // NN+1
    int* s1off  = s0off + (NN+1);             // NN
    int* s2off  = s1off + NN;                 // NN
    int* csrc   = s2off + NN;                 // CSRN
    int* posmap = csrc + CSRN;                // 3*EE
    int* tmpc   = posmap + 3*EE;              // 3*NN (cnt)
    int* cur    = tmpc + 3*NN;                // 3*NN
    int* parts  = cur + 3*NN;                 // 256

    u16* qtb = hb;
    float* outp = (float*)d_out;

    const u16* wpg1 = wp;
    const u16* wpg2 = wp + (size_t)3*16384;
    const u16* wpk  = wp + (size_t)6*16384;
    const u16* wpq  = wp + (size_t)7*16384;
    const u16* wpv  = wp + (size_t)8*16384;
    const u16* wpo  = wp + (size_t)9*16384;
    const u16* wpinj= wp + (size_t)10*16384;
    const u16* wpad = wp + (size_t)11*16384;            // packed arel [3][4096]
    const u16* wpmd = wpad + (size_t)3*4096;            // packed mrel [3][4096]

    // ---- weight pre-pack + x_cell cast ----
    wpack_k<<<18, 256, 0, stream>>>(g1W, g2W, Wk, Wq, Wv, Wo, injW, arel, mrel,
                                    g1as, g1ad, g2as, g2ad, wp, wpa);
    xcast_k<<<(int)(ND/2048), 256, 0, stream>>>(x_cell, x0b);

    // ---- type-sorted merged CSR with self slots ----
    hipMemsetAsync(tmpc, 0, 3*NN*sizeof(int), stream);
    hist_k<<<3*EE/256, 256, 0, stream>>>(eidx, tmpc);
    scanA_k<<<64, 256, 0, stream>>>(tmpc, s0off, parts);
    scan2_k<<<1, 64, 0, stream>>>(parts);
    scanB_k<<<64, 256, 0, stream>>>(tmpc, s0off, s1off, s2off, parts);
    selffill_k<<<3*NN/256, 256, 0, stream>>>(s0off, s1off, s2off, csrc);
    hipMemsetAsync(cur, 0, 3*NN*sizeof(int), stream);
    scatter_k<<<3*EE/256, 256, 0, stream>>>(eidx, s0off, s1off, s2off, cur, csrc, posmap);

    // ---- FiLM small MLP ----
    int B = in_sizes[1] / 128;
    film_k<<<B, 256, 0, stream>>>(z_h, fW1, fb1, fW2, fb2, gbuf);

    // ---- GAT layer 1 ----
    gat_gemm3_k<<<dim3(512,3), 256, 0, stream>>>(x0b, wpg1, wpa, hb, alsb, aldb);
    alpha_k<<<3*NTOT/256, 256, 0, stream>>>(alsb, aldb, eidx, posmap, s0off, s1off, s2off, ab);
    gat_aggres_k<<<16384, 256, 0, stream>>>(hb, (const float*)ab, s0off, s1off, s2off, csrc,
                                            g1b, x0b, n1s, x1b);

    // ---- GAT layer 2 ----
    gat_gemm3_k<<<dim3(512,3), 256, 0, stream>>>(x1b, wpg2, wpa + 3*2048, hb, alsb, aldb);
    alpha_k<<<3*NTOT/256, 256, 0, stream>>>(alsb, aldb, eidx, posmap, s0off, s1off, s2off, ab);
    gat_aggres_k<<<16384, 256, 0, stream>>>(hb, (const float*)ab, s0off, s1off, s2off, csrc,
                                            g2b, x1b, n2s, x2b);

    // ---- HGT projections + inject (6 tasks) ----
    hgt_proj_k<<<dim3(512,6), 256, 0, stream>>>(x2b, wpk, wpq, wpv, wpad, wpinj, x_emb,
                                                bk, bq, bv, injb, kvb, qtb, injv);
    hgt_agg_k<<<16384, 256, 0, stream>>>(kvb, qtb, prel, s0off, s1off, s2off, csrc, pb);

    // ---- final ----
    final_k<<<1024, 256, 0, stream>>>(pb, wpmd, wpo, bo, x2b, skipp, n3s,
                                      injv, gbuf, bszp, outp);
}

// Round 20
// 541.155 us; speedup vs baseline: 1.0316x; 1.0055x over previous
//
#include <hip/hip_runtime.h>

#define NN 65536
#define EE 262144
#define ND ((size_t)NN * 128)
#define TBW 132
#define WLP 136   // LDS weight pitch (u16)
#define NTOT (EE + NN)          // edges + selfs per type
#define CSRN (3*EE + 3*NN)      // total CSR slots

typedef unsigned short u16;
typedef unsigned char u8;
typedef short bf8_t __attribute__((ext_vector_type(8)));
typedef float f32x4 __attribute__((ext_vector_type(4)));
typedef float f32x2 __attribute__((ext_vector_type(2)));

__device__ __forceinline__ float lrelu(float x){ return x > 0.f ? x : 0.2f*x; }
__device__ __forceinline__ float gelu_exact(float x){ return 0.5f*x*(1.f+erff(x*0.70710678118654752f)); }
__device__ __forceinline__ float fexp(float x){ return __expf(x); }
__device__ __forceinline__ u16 f2bf(float f){
    union { float f; unsigned u; } v; v.f = f;
    unsigned u = v.u;
    return (u16)((u + 0x7FFFu + ((u >> 16) & 1u)) >> 16);
}
__device__ __forceinline__ float bf2f(u16 b){
    union { unsigned u; float f; } v; v.u = ((unsigned)b) << 16; return v.f;
}
__device__ __forceinline__ float2 bf2x(unsigned p){
    union { unsigned u; float f; } a, b;
    a.u = (p & 0xFFFFu) << 16; b.u = p & 0xFFFF0000u;
    return make_float2(a.f, b.f);
}
__device__ __forceinline__ unsigned cvt2(float a, float b){
    unsigned r; asm("v_cvt_pk_bf16_f32 %0, %1, %2" : "=v"(r) : "v"(a), "v"(b)); return r;
}
// ---- fp8 e4m3 (OCP) HW conversions ----
__device__ __forceinline__ unsigned enc_fp8x4(float a, float b, float c, float d){
    int r = __builtin_amdgcn_cvt_pk_fp8_f32(a, b, 0, false);
    r = __builtin_amdgcn_cvt_pk_fp8_f32(c, d, r, true);
    return (unsigned)r;
}

// ============ A-fragment loads ============
__device__ __forceinline__ void load_af32(const float* __restrict__ X, int row, int lk, bf8_t* af){
    #pragma unroll
    for (int kk = 0; kk < 4; ++kk){
        const float* p = X + (size_t)row*128 + kk*32 + lk*8;
        float4 a = *(const float4*)p;
        float4 b = *(const float4*)(p+4);
        union { bf8_t v; unsigned u[4]; } r;
        r.u[0] = cvt2(a.x, a.y); r.u[1] = cvt2(a.z, a.w);
        r.u[2] = cvt2(b.x, b.y); r.u[3] = cvt2(b.z, b.w);
        af[kk] = r.v;
    }
}
__device__ __forceinline__ void load_af16(const u16* __restrict__ X, int row, int lk, bf8_t* af){
    #pragma unroll
    for (int kk = 0; kk < 4; ++kk)
        af[kk] = *(const bf8_t*)(X + (size_t)row*128 + kk*32 + lk*8);
}

// ============ LDS weight staging ============
__device__ __forceinline__ void stage_w(const u16* __restrict__ src, u16* __restrict__ wl, int tid){
    #pragma unroll
    for (int j = 0; j < 8; ++j){
        int o = (j*256 + tid)*8;
        bf8_t v = *(const bf8_t*)(src + o);
        *(bf8_t*)(wl + ((o>>7)*WLP + (o&127))) = v;
    }
}

// ============ MFMA from LDS-staged weights ============
__device__ __forceinline__ void mfma_l1(const bf8_t* af, const u16* __restrict__ wl,
                                        int lr, int lk, f32x4* acc){
    #pragma unroll
    for (int i = 0; i < 8; ++i) acc[i] = (f32x4){0.f,0.f,0.f,0.f};
    #pragma unroll
    for (int kk = 0; kk < 4; ++kk){
        bf8_t B[8];
        #pragma unroll
        for (int nt = 0; nt < 8; ++nt)
            B[nt] = *(const bf8_t*)&wl[(nt*16+lr)*WLP + kk*32 + lk*8];
        #pragma unroll
        for (int nt = 0; nt < 8; ++nt)
            acc[nt] = __builtin_amdgcn_mfma_f32_16x16x32_bf16(af[kk], B[nt], acc[nt], 0, 0, 0);
    }
}
__device__ __forceinline__ void mfma_l2(const bf8_t* af0, const bf8_t* af1,
                                        const u16* __restrict__ wl,
                                        int lr, int lk, f32x4* acc0, f32x4* acc1){
    #pragma unroll
    for (int i = 0; i < 8; ++i){ acc0[i] = (f32x4){0.f,0.f,0.f,0.f}; acc1[i] = (f32x4){0.f,0.f,0.f,0.f}; }
    #pragma unroll
    for (int kk = 0; kk < 4; ++kk){
        bf8_t B[8];
        #pragma unroll
        for (int nt = 0; nt < 8; ++nt)
            B[nt] = *(const bf8_t*)&wl[(nt*16+lr)*WLP + kk*32 + lk*8];
        #pragma unroll
        for (int nt = 0; nt < 8; ++nt){
            acc0[nt] = __builtin_amdgcn_mfma_f32_16x16x32_bf16(af0[kk], B[nt], acc0[nt], 0, 0, 0);
            acc1[nt] = __builtin_amdgcn_mfma_f32_16x16x32_bf16(af1[kk], B[nt], acc1[nt], 0, 0, 0);
        }
    }
}
// ============ block-diagonal MFMA: packed B [8 nt][16 lr][32 k] from GLOBAL ============
__device__ __forceinline__ void mfma_bd1_acc(const bf8_t* af, const u16* __restrict__ Bp,
                                             int lr, int lk, f32x4* acc){
    bf8_t B[8];
    #pragma unroll
    for (int nt = 0; nt < 8; ++nt)
        B[nt] = *(const bf8_t*)&Bp[nt*512 + lr*32 + lk*8];
    #pragma unroll
    for (int nt = 0; nt < 8; ++nt)
        acc[nt] = __builtin_amdgcn_mfma_f32_16x16x32_bf16(af[nt>>1], B[nt], acc[nt], 0, 0, 0);
}
__device__ __forceinline__ void mfma_bd2(const bf8_t* af0, const bf8_t* af1,
                                         const u16* __restrict__ Bp,
                                         int lr, int lk, f32x4* acc0, f32x4* acc1){
    bf8_t B[8];
    #pragma unroll
    for (int nt = 0; nt < 8; ++nt)
        B[nt] = *(const bf8_t*)&Bp[nt*512 + lr*32 + lk*8];
    #pragma unroll
    for (int nt = 0; nt < 8; ++nt){
        acc0[nt] = __builtin_amdgcn_mfma_f32_16x16x32_bf16(af0[nt>>1], B[nt], (f32x4){0.f,0.f,0.f,0.f}, 0, 0, 0);
        acc1[nt] = __builtin_amdgcn_mfma_f32_16x16x32_bf16(af1[nt>>1], B[nt], (f32x4){0.f,0.f,0.f,0.f}, 0, 0, 0);
    }
}

// ============ per-wave LDS transpose buffer ============
__device__ __forceinline__ void acc_to_tb(u16 (*tbw)[TBW], const f32x4* acc, int lr, int lk, const float* bias){
    asm volatile("s_waitcnt lgkmcnt(0)" ::: "memory");
    #pragma unroll
    for (int nt = 0; nt < 8; ++nt){
        int col = nt*16 + lr;
        float badd = bias ? bias[col] : 0.f;
        #pragma unroll
        for (int i = 0; i < 4; ++i) tbw[lk*4+i][col] = f2bf(acc[nt][i] + badd);
    }
    asm volatile("s_waitcnt lgkmcnt(0)" ::: "memory");
}
__device__ __forceinline__ void acc_to_tb_gelu(u16 (*tbw)[TBW], const f32x4* acc, int lr, int lk){
    asm volatile("s_waitcnt lgkmcnt(0)" ::: "memory");
    #pragma unroll
    for (int nt = 0; nt < 8; ++nt){
        int col = nt*16 + lr;
        #pragma unroll
        for (int i = 0; i < 4; ++i) tbw[lk*4+i][col] = f2bf(gelu_exact(acc[nt][i]));
    }
    asm volatile("s_waitcnt lgkmcnt(0)" ::: "memory");
}
__device__ __forceinline__ void tb_store(const u16 (*tbw)[TBW], u16* __restrict__ O, size_t rowstride, int rowbase, int lr, int lk){
    #pragma unroll
    for (int c = 0; c < 4; ++c){
        bf8_t v = *(const bf8_t*)&tbw[c*4+lk][lr*8];
        *(bf8_t*)(O + (size_t)(rowbase + c*4 + lk)*rowstride + lr*8) = v;
    }
}
// fp8 store: rowstride in BYTES
__device__ __forceinline__ void tb_store_fp8(const u16 (*tbw)[TBW], u8* __restrict__ O, size_t rowstride, int rowbase, int lr, int lk){
    #pragma unroll
    for (int c = 0; c < 4; ++c){
        bf8_t v = *(const bf8_t*)&tbw[c*4+lk][lr*8];
        float f[8];
        #pragma unroll
        for (int j = 0; j < 8; ++j) f[j] = bf2f((u16)v[j]);
        uint2 o2;
        o2.x = enc_fp8x4(f[0], f[1], f[2], f[3]);
        o2.y = enc_fp8x4(f[4], f[5], f[6], f[7]);
        *(uint2*)(O + (size_t)(rowbase + c*4 + lk)*rowstride + lr*8) = o2;
    }
}
__device__ __forceinline__ void tb_frags(const u16 (*tbw)[TBW], int lr, int lk, bf8_t* ha){
    #pragma unroll
    for (int kk = 0; kk < 4; ++kk) ha[kk] = *(const bf8_t*)&tbw[lr][kk*32 + lk*8];
}
__device__ __forceinline__ void tb_rows(const u16 (*tbw)[TBW], int lr, int lk, bf8_t* rw){
    #pragma unroll
    for (int c = 0; c < 4; ++c) rw[c] = *(const bf8_t*)&tbw[c*4+lk][lr*8];
}

// ============ x_cell f32 -> bf16 one-time cast ============
__global__ __launch_bounds__(256) void xcast_k(const float* __restrict__ X, u16* __restrict__ O){
    size_t gid = (size_t)blockIdx.x*256 + threadIdx.x;
    const float* p = X + gid*8;
    float4 a = *(const float4*)p;
    float4 b = *(const float4*)(p+4);
    union { bf8_t v; unsigned u[4]; } r;
    r.u[0] = cvt2(a.x, a.y); r.u[1] = cvt2(a.z, a.w);
    r.u[2] = cvt2(b.x, b.y); r.u[3] = cvt2(b.z, b.w);
    *(bf8_t*)(O + gid*8) = r.v;
}

// ============ weight pre-pack ============
__global__ __launch_bounds__(256) void wpack_k(
    const float* __restrict__ g1W, const float* __restrict__ g2W,
    const float* __restrict__ Wk, const float* __restrict__ Wq, const float* __restrict__ Wv,
    const float* __restrict__ Wo, const float* __restrict__ injW,
    const float* __restrict__ arel, const float* __restrict__ mrel,
    const float* __restrict__ g1as, const float* __restrict__ g1ad,
    const float* __restrict__ g2as, const float* __restrict__ g2ad,
    u16* __restrict__ wp, u16* __restrict__ wpa)
{
    int b = blockIdx.x, tid = threadIdx.x;
    if (b < 11) {
        const float* src;
        if (b < 3) src = g1W + b*16384;
        else if (b < 6) src = g2W + (b-3)*16384;
        else if (b == 6) src = Wk;
        else if (b == 7) src = Wq;
        else if (b == 8) src = Wv;
        else if (b == 9) src = Wo;
        else src = injW;
        u16* dst = wp + (size_t)b*16384;
        for (int idx = tid; idx < 16384; idx += 256) {
            int n = idx >> 7, k = idx & 127;
            dst[idx] = f2bf(src[k*128 + n]);
        }
    } else if (b < 17) {
        int rel2 = (b < 14);
        const float* src = rel2 ? (arel + (b-11)*4096) : (mrel + (b-14)*4096);
        u16* dst = wp + (size_t)11*16384 + (size_t)(b-11)*4096;
        for (int idx = tid; idx < 4096; idx += 256) {
            int nt = idx >> 9, rest = idx & 511;
            int lr = rest >> 5, kp = rest & 31;
            int h = nt >> 1, c = (nt & 1)*16 + lr;
            float v = rel2 ? src[h*1024 + c*32 + kp] : src[h*1024 + kp*32 + c];
            dst[idx] = f2bf(v);
        }
    } else {
        for (int idx = tid; idx < 6*2048; idx += 256) {
            int m = idx >> 11;
            int j = idx & 2047;
            int cg = j >> 7, k = j & 127;
            const float* as = (m < 3) ? g1as : g2as;
            const float* ad = (m < 3) ? g1ad : g2ad;
            int t = (m < 3) ? m : m - 3;
            float v = 0.f;
            if (cg < 4)      { if ((k>>5)==cg)   v = as[t*128 + cg*32 + (k&31)]; }
            else if (cg < 8) { int g = cg-4; if ((k>>5)==g) v = ad[t*128 + g*32 + (k&31)]; }
            wpa[idx] = f2bf(v);
        }
    }
}

// ============ GAT projection: grid (512 rowblocks x 3 types), bf16 input ============
__global__ __launch_bounds__(256, 3) void gat_gemm3_k(const u16* __restrict__ Xb,
    const u16* __restrict__ wpg, const u16* __restrict__ wpa,
    u16* __restrict__ hb, float* __restrict__ alsb, float* __restrict__ aldb)
{
    __shared__ __align__(16) u16 wl[128*WLP];
    __shared__ __align__(16) u16 tb[4][16][TBW];
    const int tid = threadIdx.x, wave = tid>>6, lane = tid&63, lr = lane&15, lk = lane>>4;
    const int t = blockIdx.y;
    const int rw0 = blockIdx.x*128 + wave*32;
    bf8_t af0[4], af1[4];
    load_af16(Xb, rw0 + lr, lk, af0);
    load_af16(Xb, rw0 + 16 + lr, lk, af1);
    stage_w(wpg + t*16384, wl, tid);
    bf8_t Ba[4];
    #pragma unroll
    for (int kk = 0; kk < 4; ++kk)
        Ba[kk] = *(const bf8_t*)&wpa[t*2048 + lr*128 + kk*32 + lk*8];
    __syncthreads();
    f32x4 acc0[8], acc1[8];
    mfma_l2(af0, af1, wl, lr, lk, acc0, acc1);
    u16* h = hb + (size_t)t*ND;
    float* alst = alsb + (size_t)t*NN*4;
    float* aldt = aldb + (size_t)t*NN*4;
    {
        acc_to_tb(tb[wave], acc0, lr, lk, nullptr);
        tb_store(tb[wave], h, 128, rw0, lr, lk);
        bf8_t ha[4]; tb_frags(tb[wave], lr, lk, ha);
        f32x4 a2 = (f32x4){0.f,0.f,0.f,0.f};
        #pragma unroll
        for (int kk = 0; kk < 4; ++kk)
            a2 = __builtin_amdgcn_mfma_f32_16x16x32_bf16(ha[kk], Ba[kk], a2, 0, 0, 0);
        if (lr < 8){
            float* dp = (lr < 4) ? alst : aldt;
            int g = lr & 3;
            #pragma unroll
            for (int i = 0; i < 4; ++i) dp[(size_t)(rw0 + lk*4 + i)*4 + g] = a2[i];
        }
    }
    {
        acc_to_tb(tb[wave], acc1, lr, lk, nullptr);
        tb_store(tb[wave], h, 128, rw0 + 16, lr, lk);
        bf8_t ha[4]; tb_frags(tb[wave], lr, lk, ha);
        f32x4 a2 = (f32x4){0.f,0.f,0.f,0.f};
        #pragma unroll
        for (int kk = 0; kk < 4; ++kk)
            a2 = __builtin_amdgcn_mfma_f32_16x16x32_bf16(ha[kk], Ba[kk], a2, 0, 0, 0);
        if (lr < 8){
            float* dp = (lr < 4) ? alst : aldt;
            int g = lr & 3;
            #pragma unroll
            for (int i = 0; i < 4; ++i) dp[(size_t)(rw0 + 16 + lk*4 + i)*4 + g] = a2[i];
        }
    }
}

// ============ HGT projections + inject: grid (512 rowblocks x 4 tasks) ============
// task 0: k -> kv[:,0:128] fp8 | 1: v -> kv[:,128:256] fp8 | 2: inj -> injv bf16
// task 3: q = x@Wq + bq computed ONCE, then qt_t = q @ A_t^T for t=0..2
__global__ __launch_bounds__(256, 3) void hgt_proj_k(const u16* __restrict__ X,
    const u16* __restrict__ wpk, const u16* __restrict__ wpq, const u16* __restrict__ wpv,
    const u16* __restrict__ wpad, const u16* __restrict__ wpinj, const float* __restrict__ xembf,
    const float* __restrict__ bk, const float* __restrict__ bq, const float* __restrict__ bv,
    const float* __restrict__ injb,
    u8* __restrict__ kvb, u16* __restrict__ qtb, u16* __restrict__ injv)
{
    __shared__ __align__(16) u16 wl[128*WLP];
    __shared__ __align__(16) u16 tb[4][16][TBW];
    const int tid = threadIdx.x, wave = tid>>6, lane = tid&63, lr = lane&15, lk = lane>>4;
    const int task = blockIdx.y;
    const int rw0 = blockIdx.x*128 + wave*32;
    f32x4 acc0[8], acc1[8];
    if (task == 2) {
        bf8_t e0[4], e1[4];
        load_af32(xembf, rw0 + lr, lk, e0);
        load_af32(xembf, rw0 + 16 + lr, lk, e1);
        stage_w(wpinj, wl, tid);
        __syncthreads();
        mfma_l2(e0, e1, wl, lr, lk, acc0, acc1);
        acc_to_tb(tb[wave], acc0, lr, lk, injb); tb_store(tb[wave], injv, 128, rw0, lr, lk);
        acc_to_tb(tb[wave], acc1, lr, lk, injb); tb_store(tb[wave], injv, 128, rw0 + 16, lr, lk);
        return;
    }
    bf8_t af0[4], af1[4];
    load_af16(X, rw0 + lr, lk, af0);
    load_af16(X, rw0 + 16 + lr, lk, af1);
    if (task == 0) {
        stage_w(wpk, wl, tid);
        __syncthreads();
        mfma_l2(af0, af1, wl, lr, lk, acc0, acc1);
        acc_to_tb(tb[wave], acc0, lr, lk, bk); tb_store_fp8(tb[wave], kvb, 256, rw0, lr, lk);
        acc_to_tb(tb[wave], acc1, lr, lk, bk); tb_store_fp8(tb[wave], kvb, 256, rw0 + 16, lr, lk);
    } else if (task == 1) {
        stage_w(wpv, wl, tid);
        __syncthreads();
        mfma_l2(af0, af1, wl, lr, lk, acc0, acc1);
        acc_to_tb(tb[wave], acc0, lr, lk, bv); tb_store_fp8(tb[wave], kvb + 128, 256, rw0, lr, lk);
        acc_to_tb(tb[wave], acc1, lr, lk, bv); tb_store_fp8(tb[wave], kvb + 128, 256, rw0 + 16, lr, lk);
    } else {
        // task 3: q once, then 3 block-diag transforms
        stage_w(wpq, wl, tid);
        __syncthreads();
        mfma_l2(af0, af1, wl, lr, lk, acc0, acc1);
        bf8_t ha0[4], ha1[4];
        acc_to_tb(tb[wave], acc0, lr, lk, bq); tb_frags(tb[wave], lr, lk, ha0);
        acc_to_tb(tb[wave], acc1, lr, lk, bq); tb_frags(tb[wave], lr, lk, ha1);
        #pragma unroll
        for (int t = 0; t < 3; ++t){
            mfma_bd2(ha0, ha1, wpad + t*4096, lr, lk, acc0, acc1);
            u16* o = qtb + (size_t)t*ND;
            acc_to_tb(tb[wave], acc0, lr, lk, nullptr); tb_store(tb[wave], o, 128, rw0, lr, lk);
            acc_to_tb(tb[wave], acc1, lr, lk, nullptr); tb_store(tb[wave], o, 128, rw0 + 16, lr, lk);
        }
    }
}

// ================= type-sorted merged CSR with self-loop slots =================
__global__ __launch_bounds__(256) void hist_k(const int* __restrict__ ei, int* __restrict__ cnt){
    int gid = blockIdx.x*256 + threadIdx.x;
    int t = gid / EE, e = gid - t*EE;
    int d = ei[t*2*EE + EE + e];
    atomicAdd(&cnt[t*NN + d], 1);
}
__global__ __launch_bounds__(256) void scanA_k(const int* __restrict__ cnt, int* __restrict__ s0off, int* __restrict__ parts){
    __shared__ int sums[256];
    int b = blockIdx.x; int base = b * 1024;
    int tid = threadIdx.x;
    int v[4]; int tsum = 0;
    #pragma unroll
    for (int i = 0; i < 4; ++i){
        int n = base + tid*4 + i;
        v[i] = cnt[n] + cnt[NN+n] + cnt[2*NN+n] + 3;
        tsum += v[i];
    }
    sums[tid] = tsum; __syncthreads();
    for (int ofs = 1; ofs < 256; ofs <<= 1) {
        int a = (tid >= ofs) ? sums[tid-ofs] : 0;
        __syncthreads();
        sums[tid] += a;
        __syncthreads();
    }
    int run = sums[tid] - tsum;
    #pragma unroll
    for (int i = 0; i < 4; ++i){ s0off[base + tid*4 + i] = run; run += v[i]; }
    if (tid == 255) parts[b] = sums[255];
}
__global__ void scan2_k(int* parts){
    if (threadIdx.x == 0 && blockIdx.x == 0) {
        int run = 0;
        for (int i = 0; i < 64; ++i) { int v = parts[i]; parts[i] = run; run += v; }
    }
}
__global__ __launch_bounds__(256) void scanB_k(const int* __restrict__ cnt, int* __restrict__ s0off,
                                               int* __restrict__ s1off, int* __restrict__ s2off,
                                               const int* __restrict__ parts){
    int b = blockIdx.x; int base = b * 1024;
    int add = parts[b];
    #pragma unroll
    for (int i = 0; i < 4; ++i){
        int n = base + threadIdx.x*4 + i;
        int m = s0off[n] + add;
        int c0 = cnt[n], c1 = cnt[NN+n];
        s0off[n] = m;
        s1off[n] = m + c0 + 1;
        s2off[n] = m + c0 + c1 + 2;
    }
    if (b == 0 && threadIdx.x == 0) s0off[NN] = CSRN;
}
__global__ __launch_bounds__(256) void selffill_k(const int* __restrict__ s0off, const int* __restrict__ s1off,
                                                  const int* __restrict__ s2off, int* __restrict__ csrc){
    int gid = blockIdx.x*256 + threadIdx.x;
    int t = gid / NN, n = gid - t*NN;
    int pos = (t==0) ? s0off[n] : (t==1 ? s1off[n] : s2off[n]);
    csrc[pos] = n;
}
__global__ __launch_bounds__(256) void scatter_k(const int* __restrict__ ei,
    const int* __restrict__ s0off, const int* __restrict__ s1off, const int* __restrict__ s2off,
    int* __restrict__ cur, int* __restrict__ csrc, int* __restrict__ posmap){
    int gid = blockIdx.x*256 + threadIdx.x;
    int t = gid / EE, e = gid - t*EE;
    int s = ei[t*2*EE + e];
    int d = ei[t*2*EE + EE + e];
    int p = atomicAdd(&cur[t*NN + d], 1);
    int basep = (t==0) ? s0off[d] : (t==1 ? s1off[d] : s2off[d]);
    int pos = basep + 1 + p;
    csrc[pos] = s;
    posmap[t*EE + e] = pos;
}

// ============ per-edge alpha precompute (GAT layer) ============
__global__ __launch_bounds__(256) void alpha_k(const float* __restrict__ alsb, const float* __restrict__ aldb,
    const int* __restrict__ ei, const int* __restrict__ posmap,
    const int* __restrict__ s0off, const int* __restrict__ s1off, const int* __restrict__ s2off,
    float4* __restrict__ ab)
{
    int gid = blockIdx.x*256 + threadIdx.x;
    int t = gid / NTOT, r = gid - t*NTOT;
    int s, d, pos;
    if (r < EE) {
        s = ei[t*2*EE + r];
        d = ei[t*2*EE + EE + r];
        pos = posmap[t*EE + r];
    } else {
        int n = r - EE;
        s = n; d = n;
        pos = (t==0) ? s0off[n] : (t==1 ? s1off[n] : s2off[n]);
    }
    const float* As = alsb + ((size_t)t*NN + s)*4;
    const float* Ad = aldb + ((size_t)t*NN + d)*4;
    float4 o;
    o.x = fexp(lrelu(As[0] + Ad[0]));
    o.y = fexp(lrelu(As[1] + Ad[1]));
    o.z = fexp(lrelu(As[2] + Ad[2]));
    o.w = fexp(lrelu(As[3] + Ad[3]));
    ab[pos] = o;
}

// ============ GAT aggregate: 4ch/lane, 2 edges/wave ============
__global__ __launch_bounds__(256) void gat_aggres_k(const u16* __restrict__ hb,
    const float* __restrict__ abf,
    const int* __restrict__ s0off, const int* __restrict__ s1off, const int* __restrict__ s2off,
    const int* __restrict__ csrc,
    const float* __restrict__ bias3, const u16* __restrict__ xoldb,
    const float* __restrict__ scale, u16* __restrict__ outb)
{
    int gid = blockIdx.x*256 + threadIdx.x;
    int node = gid >> 6, lane = gid & 63;
    int eh = lane >> 5, hh = (lane >> 3) & 3, cp = lane & 7;
    int ch = hh*32 + cp*4;
    int segb[4] = { s0off[node], s1off[node], s2off[node], s0off[node+1] };
    float a[4] = {0.f, 0.f, 0.f, 0.f};
    #pragma unroll
    for (int t = 0; t < 3; ++t) {
        const u16* h = hb + (size_t)t*ND;
        int beg = segb[t], end = segb[t+1];
        float ds = 0.f, s0 = 0.f, s1 = 0.f, s2 = 0.f, s3 = 0.f;
        for (int pos = beg; pos < end; pos += 4) {
            int p0 = pos + eh, p1 = pos + 2 + eh;
            int v0 = (p0 < end), v1 = (p1 < end);
            int q0 = v0 ? p0 : beg, q1 = v1 ? p1 : beg;
            int sA = csrc[q0], sB = csrc[q1];
            float alA = abf[(size_t)q0*4 + hh];
            float alB = abf[(size_t)q1*4 + hh];
            uint2 hA = *(const uint2*)&h[(size_t)sA*128 + ch];
            uint2 hB = *(const uint2*)&h[(size_t)sB*128 + ch];
            alA = v0 ? alA : 0.f;
            alB = v1 ? alB : 0.f;
            float2 wA0 = bf2x(hA.x), wA1 = bf2x(hA.y);
            float2 wB0 = bf2x(hB.x), wB1 = bf2x(hB.y);
            ds += alA + alB;
            s0 += alA*wA0.x + alB*wB0.x;
            s1 += alA*wA0.y + alB*wB0.y;
            s2 += alA*wA1.x + alB*wB1.x;
            s3 += alA*wA1.y + alB*wB1.y;
        }
        ds += __shfl_xor(ds, 32);
        s0 += __shfl_xor(s0, 32);
        s1 += __shfl_xor(s1, 32);
        s2 += __shfl_xor(s2, 32);
        s3 += __shfl_xor(s3, 32);
        float inv = 1.f/(ds + 1e-16f);
        a[0] += s0*inv; a[1] += s1*inv; a[2] += s2*inv; a[3] += s3*inv;
    }
    float4 b0 = *(const float4*)&bias3[ch];
    float4 b1 = *(const float4*)&bias3[128 + ch];
    float4 b2 = *(const float4*)&bias3[256 + ch];
    a[0] += b0.x + b1.x + b2.x;
    a[1] += b0.y + b1.y + b2.y;
    a[2] += b0.z + b1.z + b2.z;
    a[3] += b0.w + b1.w + b2.w;
    float ssum = a[0]*a[0] + a[1]*a[1] + a[2]*a[2] + a[3]*a[3];
    ssum += __shfl_xor(ssum, 1); ssum += __shfl_xor(ssum, 2);
    ssum += __shfl_xor(ssum, 4); ssum += __shfl_xor(ssum, 8);
    ssum += __shfl_xor(ssum, 16);
    float r = rsqrtf(ssum*(1.f/128.f) + 1e-6f);
    float4 sc = *(const float4*)&scale[ch];
    size_t off = (size_t)node*128 + ch;
    uint2 xo = *(const uint2*)&xoldb[off];
    float2 p0 = bf2x(xo.x), p1 = bf2x(xo.y);
    float y0 = lrelu(p0.x + sc.x*a[0]*r);
    float y1 = lrelu(p0.y + sc.y*a[1]*r);
    float y2 = lrelu(p1.x + sc.z*a[2]*r);
    float y3 = lrelu(p1.y + sc.w*a[3]*r);
    uint2 o2; o2.x = cvt2(y0, y1); o2.y = cvt2(y2, y3);
    *(uint2*)&outb[off] = o2;
}

// ============ HGT aggregate: fp8 kv, 4ch/lane, 2 edges/wave; pb interleaved [node][3][128] ============
__global__ __launch_bounds__(256) void hgt_agg_k(const u8* __restrict__ kvb,
    const u16* __restrict__ qtb, const float* __restrict__ prel,
    const int* __restrict__ s0off, const int* __restrict__ s1off, const int* __restrict__ s2off,
    const int* __restrict__ csrc, u16* __restrict__ pb)
{
    int gid = blockIdx.x*256 + threadIdx.x;
    int node = gid >> 6, lane = gid & 63;
    int eh = lane >> 5, hh = (lane >> 3) & 3, cp = lane & 7;
    int ch = hh*32 + cp*4;
    const float S = 0.17677669529663689f; // 1/sqrt(32)
    int segb[4] = { s0off[node], s1off[node], s2off[node], s0off[node+1] };
    float dsum = 0.f;
    float ac[3][4];
    #pragma unroll
    for (int t = 0; t < 3; ++t){ ac[t][0]=0.f; ac[t][1]=0.f; ac[t][2]=0.f; ac[t][3]=0.f; }
    #pragma unroll
    for (int t = 0; t < 3; ++t) {
        float ph = prel[t*4 + hh] * S;
        uint2 qw = *(const uint2*)&qtb[(size_t)t*ND + (size_t)node*128 + ch];
        float2 q0 = bf2x(qw.x), q1 = bf2x(qw.y);
        int self = segb[t];
        int beg = self + 1, end = segb[t+1];
        for (int pos = beg; pos < end; pos += 4) {
            int p0 = pos + eh, p1 = pos + 2 + eh;
            int v0 = (p0 < end), v1 = (p1 < end);
            int qp0 = v0 ? p0 : self, qp1 = v1 ? p1 : self;
            int sA = csrc[qp0], sB = csrc[qp1];
            size_t rA = (size_t)sA*256 + ch, rB = (size_t)sB*256 + ch;
            unsigned kA = *(const unsigned*)&kvb[rA], kB = *(const unsigned*)&kvb[rB];
            unsigned vA = *(const unsigned*)&kvb[rA + 128], vB = *(const unsigned*)&kvb[rB + 128];
            f32x2 kA0 = __builtin_amdgcn_cvt_pk_f32_fp8((int)kA, false);
            f32x2 kA1 = __builtin_amdgcn_cvt_pk_f32_fp8((int)kA, true);
            f32x2 kB0 = __builtin_amdgcn_cvt_pk_f32_fp8((int)kB, false);
            f32x2 kB1 = __builtin_amdgcn_cvt_pk_f32_fp8((int)kB, true);
            float scA = kA0[0]*q0.x + kA0[1]*q0.y + kA1[0]*q1.x + kA1[1]*q1.y;
            float scB = kB0[0]*q0.x + kB0[1]*q0.y + kB1[0]*q1.x + kB1[1]*q1.y;
            scA += __shfl_xor(scA, 1); scB += __shfl_xor(scB, 1);
            scA += __shfl_xor(scA, 2); scB += __shfl_xor(scB, 2);
            scA += __shfl_xor(scA, 4); scB += __shfl_xor(scB, 4);
            float eA = v0 ? fexp(scA*ph) : 0.f;
            float eB = v1 ? fexp(scB*ph) : 0.f;
            f32x2 vA0 = __builtin_amdgcn_cvt_pk_f32_fp8((int)vA, false);
            f32x2 vA1 = __builtin_amdgcn_cvt_pk_f32_fp8((int)vA, true);
            f32x2 vB0 = __builtin_amdgcn_cvt_pk_f32_fp8((int)vB, false);
            f32x2 vB1 = __builtin_amdgcn_cvt_pk_f32_fp8((int)vB, true);
            dsum += eA + eB;
            ac[t][0] += eA*vA0[0] + eB*vB0[0];
            ac[t][1] += eA*vA0[1] + eB*vB0[1];
            ac[t][2] += eA*vA1[0] + eB*vB1[0];
            ac[t][3] += eA*vA1[1] + eB*vB1[1];
        }
    }
    dsum += __shfl_xor(dsum, 32);
    #pragma unroll
    for (int t = 0; t < 3; ++t){
        ac[t][0] += __shfl_xor(ac[t][0], 32);
        ac[t][1] += __shfl_xor(ac[t][1], 32);
        ac[t][2] += __shfl_xor(ac[t][2], 32);
        ac[t][3] += __shfl_xor(ac[t][3], 32);
    }
    float inv = 1.f/(dsum + 1e-16f);
    size_t o = (size_t)node*384 + ch;
    #pragma unroll
    for (int t = 0; t < 3; ++t){
        uint2 o2;
        o2.x = cvt2(ac[t][0]*inv, ac[t][1]*inv);
        o2.y = cvt2(ac[t][2]*inv, ac[t][3]*inv);
        *(uint2*)&pb[o + (size_t)t*128] = o2;
    }
}

// ============ final: M-stage (block-diag) + Wo (LDS) + epilogue w/ precomputed injv ============
__global__ __launch_bounds__(256, 3) void final_k(const u16* __restrict__ pb,
    const u16* __restrict__ wpmd, const u16* __restrict__ wpo, const float* __restrict__ bo,
    const u16* __restrict__ x2b, const float* __restrict__ skipp, const float* __restrict__ scale,
    const u16* __restrict__ injv,
    const float* __restrict__ gbuf, const int* __restrict__ bszp,
    float* __restrict__ out)
{
    __shared__ __align__(16) u16 wl[128*WLP];
    __shared__ __align__(16) u16 tb[4][16][TBW];
    const int tid = threadIdx.x, wave = tid>>6, lane = tid&63, lr = lane&15, lk = lane>>4;
    const int rw = blockIdx.x*64 + wave*16;
    stage_w(wpo, wl, tid);
    // ---- agg_pre = Σ_t partial_t @ M_t (interleaved pb, block-diag packed B) ----
    f32x4 acc[8];
    #pragma unroll
    for (int i = 0; i < 8; ++i) acc[i] = (f32x4){0.f,0.f,0.f,0.f};
    {
        const u16* pr = pb + (size_t)(rw + lr)*384;
        #pragma unroll
        for (int t = 0; t < 3; ++t){
            bf8_t a0[4];
            #pragma unroll
            for (int kk = 0; kk < 4; ++kk)
                a0[kk] = *(const bf8_t*)(pr + t*128 + kk*32 + lk*8);
            mfma_bd1_acc(a0, wpmd + t*4096, lr, lk, acc);
        }
    }
    // ---- gelu -> tb -> A-frags ----
    bf8_t ga[4];
    acc_to_tb_gelu(tb[wave], acc, lr, lk);
    tb_frags(tb[wave], lr, lk, ga);
    // ---- Wo GEMM (LDS-staged) ----
    __syncthreads();
    mfma_l1(ga, wl, lr, lk, acc);
    bf8_t hw[4];
    acc_to_tb(tb[wave], acc, lr, lk, bo);
    tb_rows(tb[wave], lr, lk, hw);
    // ---- vectorized row-major epilogue (+ precomputed injv) ----
    const float sig = 1.f/(1.f + expf(-skipp[0]));
    const int cpb = NN / *bszp;
    float4 sca = *(const float4*)&scale[lr*8];
    float4 scb = *(const float4*)&scale[lr*8 + 4];
    #pragma unroll
    for (int c = 0; c < 4; ++c){
        int row = rw + c*4 + lk;
        bf8_t x8 = *(const bf8_t*)(x2b + (size_t)row*128 + lr*8);
        bf8_t i8 = *(const bf8_t*)(injv + (size_t)row*128 + lr*8);
        float x[8], v[8];
        float ssl = 0.f;
        #pragma unroll
        for (int j = 0; j < 8; ++j){
            x[j] = bf2f((u16)x8[j]);
            float h = bf2f((u16)hw[c][j]);
            v[j] = sig*h + (1.f - sig)*x[j];
            ssl += v[j]*v[j];
        }
        ssl += __shfl_xor(ssl, 1); ssl += __shfl_xor(ssl, 2);
        ssl += __shfl_xor(ssl, 4); ssl += __shfl_xor(ssl, 8);
        float rq = rsqrtf(ssl*(1.f/128.f) + 1e-6f);
        const float* gr = gbuf + (row / cpb)*256;
        float4 g0 = *(const float4*)&gr[lr*8];
        float4 g1 = *(const float4*)&gr[lr*8 + 4];
        float4 b0 = *(const float4*)&gr[128 + lr*8];
        float4 b1 = *(const float4*)&gr[128 + lr*8 + 4];
        float4 oA, oB;
        #pragma unroll
        for (int j = 0; j < 8; ++j){
            float scj = (j < 4) ? ((const float*)&sca)[j] : ((const float*)&scb)[j-4];
            float y = lrelu(x[j] + scj*v[j]*rq);
            float hf = y + bf2f((u16)i8[j]);
            float gj = (j < 4) ? ((const float*)&g0)[j] : ((const float*)&g1)[j-4];
            float bj = (j < 4) ? ((const float*)&b0)[j] : ((const float*)&b1)[j-4];
            float ov = (1.f + gj)*hf + bj;
            if (j < 4) ((float*)&oA)[j] = ov; else ((float*)&oB)[j-4] = ov;
        }
        *(float4*)(out + (size_t)row*128 + lr*8)     = oA;
        *(float4*)(out + (size_t)row*128 + lr*8 + 4) = oB;
    }
}

// ============ FiLM small MLP ============
__global__ __launch_bounds__(256) void film_k(const float* __restrict__ z,
    const float* __restrict__ W1, const float* __restrict__ b1,
    const float* __restrict__ W2, const float* __restrict__ b2,
    float* __restrict__ gb)
{
    __shared__ float zr[128];
    __shared__ float g1[256];
    int r = blockIdx.x, tid = threadIdx.x;
    if (tid < 128) zr[tid] = z[r*128 + tid];
    __syncthreads();
    float s = b1[tid];
    for (int k = 0; k < 128; ++k) s += zr[k]*W1[k*256 + tid];
    g1[tid] = gelu_exact(s);
    __syncthreads();
    float s2 = b2[tid];
    for (int k = 0; k < 256; ++k) s2 += g1[k]*W2[k*256 + tid];
    gb[r*256 + tid] = 0.1f*tanhf(s2);
}

// ================= launch =================
extern "C" void kernel_launch(void* const* d_in, const int* in_sizes, int n_in,
                              void* d_out, int out_size, void* d_ws, size_t ws_size,
                              hipStream_t stream)
{
    const float* x_cell = (const float*)d_in[0];
    const float* z_h    = (const float*)d_in[1];
    const float* x_emb  = (const float*)d_in[2];
    const int*   eidx   = (const int*)d_in[3];
    const int*   bszp   = (const int*)d_in[4];
    const float* g1W  = (const float*)d_in[5];
    const float* g1as = (const float*)d_in[6];
    const float* g1ad = (const float*)d_in[7];
    const float* g1b  = (const float*)d_in[8];
    const float* g2W  = (const float*)d_in[9];
    const float* g2as = (const float*)d_in[10];
    const float* g2ad = (const float*)d_in[11];
    const float* g2b  = (const float*)d_in[12];
    const float* n1s  = (const float*)d_in[13];
    const float* n2s  = (const float*)d_in[14];
    const float* n3s  = (const float*)d_in[15];
    const float* Wk   = (const float*)d_in[16];
    const float* bk   = (const float*)d_in[17];
    const float* Wq   = (const float*)d_in[18];
    const float* bq   = (const float*)d_in[19];
    const float* Wv   = (const float*)d_in[20];
    const float* bv   = (const float*)d_in[21];
    const float* arel = (const float*)d_in[22];
    const float* mrel = (const float*)d_in[23];
    const float* prel = (const float*)d_in[24];
    const float* Wo   = (const float*)d_in[25];
    const float* bo   = (const float*)d_in[26];
    const float* skipp= (const float*)d_in[27];
    const float* injW = (const float*)d_in[28];
    const float* injb = (const float*)d_in[29];
    const float* fW1  = (const float*)d_in[30];
    const float* fb1  = (const float*)d_in[31];
    const float* fW2  = (const float*)d_in[32];
    const float* fb2  = (const float*)d_in[33];

    // ---- workspace layout ----
    u16* wp   = (u16*)d_ws;                   // 17*16384 u16
    u16* wpa  = wp + (size_t)17*16384;        // 6*2048 u16
    float4* ab = (float4*)(wpa + 6*2048);     // CSRN float4
    u16* x0b  = (u16*)(ab + CSRN);            // ND u16 (x_cell bf16)
    u16* x1b  = x0b + ND;                     // ND u16
    u16* x2b  = x1b + ND;                     // ND u16
    u8*  kvb  = (u8*)(x2b + ND);              // NN*256 bytes (k|v fp8)
    u16* pb   = (u16*)(kvb + (size_t)NN*256); // 3*ND u16 (interleaved [node][3][128])
    u16* hb   = pb + 3*ND;                    // 3*ND u16 (reused as qtb)
    u16* injv = hb + 3*ND;                    // ND u16 (inject result, bias folded)
    float* alsb = (float*)(injv + ND);        // 3*NN*4 f32
    float* aldb = alsb + (size_t)3*NN*4;      // 3*NN*4 f32
    float* gbuf = aldb + (size_t)3*NN*4;      // 32*256 f32
    int* s0off  = (int*)(gbuf + 32*256);      // NN+1
    int* s1off  = s0off + (NN+1);             // NN
    int* s2off  = s1off + NN;                 // NN
    int* csrc   = s2off + NN;                 // CSRN
    int* posmap = csrc + CSRN;                // 3*EE
    int* tmpc   = posmap + 3*EE;              // 3*NN (cnt)
    int* cur    = tmpc + 3*NN;                // 3*NN
    int* parts  = cur + 3*NN;                 // 256

    u16* qtb = hb;
    float* outp = (float*)d_out;

    const u16* wpg1 = wp;
    const u16* wpg2 = wp + (size_t)3*16384;
    const u16* wpk  = wp + (size_t)6*16384;
    const u16* wpq  = wp + (size_t)7*16384;
    const u16* wpv  = wp + (size_t)8*16384;
    const u16* wpo  = wp + (size_t)9*16384;
    const u16* wpinj= wp + (size_t)10*16384;
    const u16* wpad = wp + (size_t)11*16384;            // packed arel [3][4096]
    const u16* wpmd = wpad + (size_t)3*4096;            // packed mrel [3][4096]

    // ---- weight pre-pack + x_cell cast ----
    wpack_k<<<18, 256, 0, stream>>>(g1W, g2W, Wk, Wq, Wv, Wo, injW, arel, mrel,
                                    g1as, g1ad, g2as, g2ad, wp, wpa);
    xcast_k<<<(int)(ND/2048), 256, 0, stream>>>(x_cell, x0b);

    // ---- type-sorted merged CSR with self slots ----
    hipMemsetAsync(tmpc, 0, 3*NN*sizeof(int), stream);
    hist_k<<<3*EE/256, 256, 0, stream>>>(eidx, tmpc);
    scanA_k<<<64, 256, 0, stream>>>(tmpc, s0off, parts);
    scan2_k<<<1, 64, 0, stream>>>(parts);
    scanB_k<<<64, 256, 0, stream>>>(tmpc, s0off, s1off, s2off, parts);
    selffill_k<<<3*NN/256, 256, 0, stream>>>(s0off, s1off, s2off, csrc);
    hipMemsetAsync(cur, 0, 3*NN*sizeof(int), stream);
    scatter_k<<<3*EE/256, 256, 0, stream>>>(eidx, s0off, s1off, s2off, cur, csrc, posmap);

    // ---- FiLM small MLP ----
    int B = in_sizes[1] / 128;
    film_k<<<B, 256, 0, stream>>>(z_h, fW1, fb1, fW2, fb2, gbuf);

    // ---- GAT layer 1 ----
    gat_gemm3_k<<<dim3(512,3), 256, 0, stream>>>(x0b, wpg1, wpa, hb, alsb, aldb);
    alpha_k<<<3*NTOT/256, 256, 0, stream>>>(alsb, aldb, eidx, posmap, s0off, s1off, s2off, ab);
    gat_aggres_k<<<16384, 256, 0, stream>>>(hb, (const float*)ab, s0off, s1off, s2off, csrc,
                                            g1b, x0b, n1s, x1b);

    // ---- GAT layer 2 ----
    gat_gemm3_k<<<dim3(512,3), 256, 0, stream>>>(x1b, wpg2, wpa + 3*2048, hb, alsb, aldb);
    alpha_k<<<3*NTOT/256, 256, 0, stream>>>(alsb, aldb, eidx, posmap, s0off, s1off, s2off, ab);
    gat_aggres_k<<<16384, 256, 0, stream>>>(hb, (const float*)ab, s0off, s1off, s2off, csrc,
                                            g2b, x1b, n2s, x2b);

    // ---- HGT projections + inject (4 tasks) ----
    hgt_proj_k<<<dim3(512,4), 256, 0, stream>>>(x2b, wpk, wpq, wpv, wpad, wpinj, x_emb,
                                                bk, bq, bv, injb, kvb, qtb, injv);
    hgt_agg_k<<<16384, 256, 0, stream>>>(kvb, qtb, prel, s0off, s1off, s2off, csrc, pb);

    // ---- final ----
    final_k<<<1024, 256, 0, stream>>>(pb, wpmd, wpo, bo, x2b, skipp, n3s,
                                      injv, gbuf, bszp, outp);
}

// Round 21
// 536.062 us; speedup vs baseline: 1.0414x; 1.0095x over previous
//
#include <hip/hip_runtime.h>

#define NN 65536
#define EE 262144
#define ND ((size_t)NN * 128)
#define TBW 132
#define WLP 136   // LDS weight pitch (u16)
#define NTOT (EE + NN)          // edges + selfs per type
#define CSRN (3*EE + 3*NN)      // total CSR slots

typedef unsigned short u16;
typedef unsigned char u8;
typedef short bf8_t __attribute__((ext_vector_type(8)));
typedef float f32x4 __attribute__((ext_vector_type(4)));
typedef float f32x2 __attribute__((ext_vector_type(2)));

__device__ __forceinline__ float lrelu(float x){ return x > 0.f ? x : 0.2f*x; }
__device__ __forceinline__ float gelu_exact(float x){ return 0.5f*x*(1.f+erff(x*0.70710678118654752f)); }
__device__ __forceinline__ float fexp(float x){ return __expf(x); }
__device__ __forceinline__ u16 f2bf(float f){
    union { float f; unsigned u; } v; v.f = f;
    unsigned u = v.u;
    return (u16)((u + 0x7FFFu + ((u >> 16) & 1u)) >> 16);
}
__device__ __forceinline__ float bf2f(u16 b){
    union { unsigned u; float f; } v; v.u = ((unsigned)b) << 16; return v.f;
}
__device__ __forceinline__ float2 bf2x(unsigned p){
    union { unsigned u; float f; } a, b;
    a.u = (p & 0xFFFFu) << 16; b.u = p & 0xFFFF0000u;
    return make_float2(a.f, b.f);
}
__device__ __forceinline__ unsigned cvt2(float a, float b){
    unsigned r; asm("v_cvt_pk_bf16_f32 %0, %1, %2" : "=v"(r) : "v"(a), "v"(b)); return r;
}
// ---- fp8 e4m3 (OCP) HW conversions ----
__device__ __forceinline__ unsigned enc_fp8x4(float a, float b, float c, float d){
    int r = __builtin_amdgcn_cvt_pk_fp8_f32(a, b, 0, false);
    r = __builtin_amdgcn_cvt_pk_fp8_f32(c, d, r, true);
    return (unsigned)r;
}

// ============ A-fragment loads ============
__device__ __forceinline__ void load_af32(const float* __restrict__ X, int row, int lk, bf8_t* af){
    #pragma unroll
    for (int kk = 0; kk < 4; ++kk){
        const float* p = X + (size_t)row*128 + kk*32 + lk*8;
        float4 a = *(const float4*)p;
        float4 b = *(const float4*)(p+4);
        union { bf8_t v; unsigned u[4]; } r;
        r.u[0] = cvt2(a.x, a.y); r.u[1] = cvt2(a.z, a.w);
        r.u[2] = cvt2(b.x, b.y); r.u[3] = cvt2(b.z, b.w);
        af[kk] = r.v;
    }
}
__device__ __forceinline__ void load_af16(const u16* __restrict__ X, int row, int lk, bf8_t* af){
    #pragma unroll
    for (int kk = 0; kk < 4; ++kk)
        af[kk] = *(const bf8_t*)(X + (size_t)row*128 + kk*32 + lk*8);
}

// ============ LDS weight staging ============
__device__ __forceinline__ void stage_w(const u16* __restrict__ src, u16* __restrict__ wl, int tid){
    #pragma unroll
    for (int j = 0; j < 8; ++j){
        int o = (j*256 + tid)*8;
        bf8_t v = *(const bf8_t*)(src + o);
        *(bf8_t*)(wl + ((o>>7)*WLP + (o&127))) = v;
    }
}

// ============ MFMA from LDS-staged weights ============
__device__ __forceinline__ void mfma_l1(const bf8_t* af, const u16* __restrict__ wl,
                                        int lr, int lk, f32x4* acc){
    #pragma unroll
    for (int i = 0; i < 8; ++i) acc[i] = (f32x4){0.f,0.f,0.f,0.f};
    #pragma unroll
    for (int kk = 0; kk < 4; ++kk){
        bf8_t B[8];
        #pragma unroll
        for (int nt = 0; nt < 8; ++nt)
            B[nt] = *(const bf8_t*)&wl[(nt*16+lr)*WLP + kk*32 + lk*8];
        #pragma unroll
        for (int nt = 0; nt < 8; ++nt)
            acc[nt] = __builtin_amdgcn_mfma_f32_16x16x32_bf16(af[kk], B[nt], acc[nt], 0, 0, 0);
    }
}
__device__ __forceinline__ void mfma_l2(const bf8_t* af0, const bf8_t* af1,
                                        const u16* __restrict__ wl,
                                        int lr, int lk, f32x4* acc0, f32x4* acc1){
    #pragma unroll
    for (int i = 0; i < 8; ++i){ acc0[i] = (f32x4){0.f,0.f,0.f,0.f}; acc1[i] = (f32x4){0.f,0.f,0.f,0.f}; }
    #pragma unroll
    for (int kk = 0; kk < 4; ++kk){
        bf8_t B[8];
        #pragma unroll
        for (int nt = 0; nt < 8; ++nt)
            B[nt] = *(const bf8_t*)&wl[(nt*16+lr)*WLP + kk*32 + lk*8];
        #pragma unroll
        for (int nt = 0; nt < 8; ++nt){
            acc0[nt] = __builtin_amdgcn_mfma_f32_16x16x32_bf16(af0[kk], B[nt], acc0[nt], 0, 0, 0);
            acc1[nt] = __builtin_amdgcn_mfma_f32_16x16x32_bf16(af1[kk], B[nt], acc1[nt], 0, 0, 0);
        }
    }
}
// ============ block-diagonal MFMA: packed B [8 nt][16 lr][32 k] from GLOBAL ============
__device__ __forceinline__ void mfma_bd1_acc(const bf8_t* af, const u16* __restrict__ Bp,
                                             int lr, int lk, f32x4* acc){
    bf8_t B[8];
    #pragma unroll
    for (int nt = 0; nt < 8; ++nt)
        B[nt] = *(const bf8_t*)&Bp[nt*512 + lr*32 + lk*8];
    #pragma unroll
    for (int nt = 0; nt < 8; ++nt)
        acc[nt] = __builtin_amdgcn_mfma_f32_16x16x32_bf16(af[nt>>1], B[nt], acc[nt], 0, 0, 0);
}
__device__ __forceinline__ void mfma_bd2(const bf8_t* af0, const bf8_t* af1,
                                         const u16* __restrict__ Bp,
                                         int lr, int lk, f32x4* acc0, f32x4* acc1){
    bf8_t B[8];
    #pragma unroll
    for (int nt = 0; nt < 8; ++nt)
        B[nt] = *(const bf8_t*)&Bp[nt*512 + lr*32 + lk*8];
    #pragma unroll
    for (int nt = 0; nt < 8; ++nt){
        acc0[nt] = __builtin_amdgcn_mfma_f32_16x16x32_bf16(af0[nt>>1], B[nt], (f32x4){0.f,0.f,0.f,0.f}, 0, 0, 0);
        acc1[nt] = __builtin_amdgcn_mfma_f32_16x16x32_bf16(af1[nt>>1], B[nt], (f32x4){0.f,0.f,0.f,0.f}, 0, 0, 0);
    }
}

// ============ per-wave LDS transpose buffer ============
__device__ __forceinline__ void acc_to_tb(u16 (*tbw)[TBW], const f32x4* acc, int lr, int lk, const float* bias){
    asm volatile("s_waitcnt lgkmcnt(0)" ::: "memory");
    #pragma unroll
    for (int nt = 0; nt < 8; ++nt){
        int col = nt*16 + lr;
        float badd = bias ? bias[col] : 0.f;
        #pragma unroll
        for (int i = 0; i < 4; ++i) tbw[lk*4+i][col] = f2bf(acc[nt][i] + badd);
    }
    asm volatile("s_waitcnt lgkmcnt(0)" ::: "memory");
}
__device__ __forceinline__ void acc_to_tb_gelu(u16 (*tbw)[TBW], const f32x4* acc, int lr, int lk){
    asm volatile("s_waitcnt lgkmcnt(0)" ::: "memory");
    #pragma unroll
    for (int nt = 0; nt < 8; ++nt){
        int col = nt*16 + lr;
        #pragma unroll
        for (int i = 0; i < 4; ++i) tbw[lk*4+i][col] = f2bf(gelu_exact(acc[nt][i]));
    }
    asm volatile("s_waitcnt lgkmcnt(0)" ::: "memory");
}
__device__ __forceinline__ void tb_store(const u16 (*tbw)[TBW], u16* __restrict__ O, size_t rowstride, int rowbase, int lr, int lk){
    #pragma unroll
    for (int c = 0; c < 4; ++c){
        bf8_t v = *(const bf8_t*)&tbw[c*4+lk][lr*8];
        *(bf8_t*)(O + (size_t)(rowbase + c*4 + lk)*rowstride + lr*8) = v;
    }
}
// fp8 store: rowstride in BYTES
__device__ __forceinline__ void tb_store_fp8(const u16 (*tbw)[TBW], u8* __restrict__ O, size_t rowstride, int rowbase, int lr, int lk){
    #pragma unroll
    for (int c = 0; c < 4; ++c){
        bf8_t v = *(const bf8_t*)&tbw[c*4+lk][lr*8];
        float f[8];
        #pragma unroll
        for (int j = 0; j < 8; ++j) f[j] = bf2f((u16)v[j]);
        uint2 o2;
        o2.x = enc_fp8x4(f[0], f[1], f[2], f[3]);
        o2.y = enc_fp8x4(f[4], f[5], f[6], f[7]);
        *(uint2*)(O + (size_t)(rowbase + c*4 + lk)*rowstride + lr*8) = o2;
    }
}
__device__ __forceinline__ void tb_frags(const u16 (*tbw)[TBW], int lr, int lk, bf8_t* ha){
    #pragma unroll
    for (int kk = 0; kk < 4; ++kk) ha[kk] = *(const bf8_t*)&tbw[lr][kk*32 + lk*8];
}
__device__ __forceinline__ void tb_rows(const u16 (*tbw)[TBW], int lr, int lk, bf8_t* rw){
    #pragma unroll
    for (int c = 0; c < 4; ++c) rw[c] = *(const bf8_t*)&tbw[c*4+lk][lr*8];
}

// ============ x_cell f32 -> bf16 one-time cast ============
__global__ __launch_bounds__(256) void xcast_k(const float* __restrict__ X, u16* __restrict__ O){
    size_t gid = (size_t)blockIdx.x*256 + threadIdx.x;
    const float* p = X + gid*8;
    float4 a = *(const float4*)p;
    float4 b = *(const float4*)(p+4);
    union { bf8_t v; unsigned u[4]; } r;
    r.u[0] = cvt2(a.x, a.y); r.u[1] = cvt2(a.z, a.w);
    r.u[2] = cvt2(b.x, b.y); r.u[3] = cvt2(b.z, b.w);
    *(bf8_t*)(O + gid*8) = r.v;
}

// ============ weight pre-pack ============
__global__ __launch_bounds__(256) void wpack_k(
    const float* __restrict__ g1W, const float* __restrict__ g2W,
    const float* __restrict__ Wk, const float* __restrict__ Wq, const float* __restrict__ Wv,
    const float* __restrict__ Wo, const float* __restrict__ injW,
    const float* __restrict__ arel, const float* __restrict__ mrel,
    const float* __restrict__ g1as, const float* __restrict__ g1ad,
    const float* __restrict__ g2as, const float* __restrict__ g2ad,
    u16* __restrict__ wp, u16* __restrict__ wpa)
{
    int b = blockIdx.x, tid = threadIdx.x;
    if (b < 11) {
        const float* src;
        if (b < 3) src = g1W + b*16384;
        else if (b < 6) src = g2W + (b-3)*16384;
        else if (b == 6) src = Wk;
        else if (b == 7) src = Wq;
        else if (b == 8) src = Wv;
        else if (b == 9) src = Wo;
        else src = injW;
        u16* dst = wp + (size_t)b*16384;
        for (int idx = tid; idx < 16384; idx += 256) {
            int n = idx >> 7, k = idx & 127;
            dst[idx] = f2bf(src[k*128 + n]);
        }
    } else if (b < 17) {
        int rel2 = (b < 14);
        const float* src = rel2 ? (arel + (b-11)*4096) : (mrel + (b-14)*4096);
        u16* dst = wp + (size_t)11*16384 + (size_t)(b-11)*4096;
        for (int idx = tid; idx < 4096; idx += 256) {
            int nt = idx >> 9, rest = idx & 511;
            int lr = rest >> 5, kp = rest & 31;
            int h = nt >> 1, c = (nt & 1)*16 + lr;
            float v = rel2 ? src[h*1024 + c*32 + kp] : src[h*1024 + kp*32 + c];
            dst[idx] = f2bf(v);
        }
    } else {
        for (int idx = tid; idx < 6*2048; idx += 256) {
            int m = idx >> 11;
            int j = idx & 2047;
            int cg = j >> 7, k = j & 127;
            const float* as = (m < 3) ? g1as : g2as;
            const float* ad = (m < 3) ? g1ad : g2ad;
            int t = (m < 3) ? m : m - 3;
            float v = 0.f;
            if (cg < 4)      { if ((k>>5)==cg)   v = as[t*128 + cg*32 + (k&31)]; }
            else if (cg < 8) { int g = cg-4; if ((k>>5)==g) v = ad[t*128 + g*32 + (k&31)]; }
            wpa[idx] = f2bf(v);
        }
    }
}

// ============ GAT projection: grid (512 rowblocks x 3 types), bf16 input ============
__global__ __launch_bounds__(256, 3) void gat_gemm3_k(const u16* __restrict__ Xb,
    const u16* __restrict__ wpg, const u16* __restrict__ wpa,
    u16* __restrict__ hb, float* __restrict__ alsb, float* __restrict__ aldb)
{
    __shared__ __align__(16) u16 wl[128*WLP];
    __shared__ __align__(16) u16 tb[4][16][TBW];
    const int tid = threadIdx.x, wave = tid>>6, lane = tid&63, lr = lane&15, lk = lane>>4;
    const int t = blockIdx.y;
    const int rw0 = blockIdx.x*128 + wave*32;
    bf8_t af0[4], af1[4];
    load_af16(Xb, rw0 + lr, lk, af0);
    load_af16(Xb, rw0 + 16 + lr, lk, af1);
    stage_w(wpg + t*16384, wl, tid);
    bf8_t Ba[4];
    #pragma unroll
    for (int kk = 0; kk < 4; ++kk)
        Ba[kk] = *(const bf8_t*)&wpa[t*2048 + lr*128 + kk*32 + lk*8];
    __syncthreads();
    f32x4 acc0[8], acc1[8];
    mfma_l2(af0, af1, wl, lr, lk, acc0, acc1);
    u16* h = hb + (size_t)t*ND;
    float* alst = alsb + (size_t)t*NN*4;
    float* aldt = aldb + (size_t)t*NN*4;
    {
        acc_to_tb(tb[wave], acc0, lr, lk, nullptr);
        tb_store(tb[wave], h, 128, rw0, lr, lk);
        bf8_t ha[4]; tb_frags(tb[wave], lr, lk, ha);
        f32x4 a2 = (f32x4){0.f,0.f,0.f,0.f};
        #pragma unroll
        for (int kk = 0; kk < 4; ++kk)
            a2 = __builtin_amdgcn_mfma_f32_16x16x32_bf16(ha[kk], Ba[kk], a2, 0, 0, 0);
        if (lr < 8){
            float* dp = (lr < 4) ? alst : aldt;
            int g = lr & 3;
            #pragma unroll
            for (int i = 0; i < 4; ++i) dp[(size_t)(rw0 + lk*4 + i)*4 + g] = a2[i];
        }
    }
    {
        acc_to_tb(tb[wave], acc1, lr, lk, nullptr);
        tb_store(tb[wave], h, 128, rw0 + 16, lr, lk);
        bf8_t ha[4]; tb_frags(tb[wave], lr, lk, ha);
        f32x4 a2 = (f32x4){0.f,0.f,0.f,0.f};
        #pragma unroll
        for (int kk = 0; kk < 4; ++kk)
            a2 = __builtin_amdgcn_mfma_f32_16x16x32_bf16(ha[kk], Ba[kk], a2, 0, 0, 0);
        if (lr < 8){
            float* dp = (lr < 4) ? alst : aldt;
            int g = lr & 3;
            #pragma unroll
            for (int i = 0; i < 4; ++i) dp[(size_t)(rw0 + 16 + lk*4 + i)*4 + g] = a2[i];
        }
    }
}

// ============ HGT projections + inject: grid (512 rowblocks x 4 tasks) ============
// task 0: k -> kv[:,0:128] fp8 | 1: v -> kv[:,128:256] fp8 | 2: inj -> injv bf16
// task 3: q = x@Wq + bq computed ONCE, then qt_t = q @ A_t^T for t=0..2
__global__ __launch_bounds__(256, 3) void hgt_proj_k(const u16* __restrict__ X,
    const u16* __restrict__ wpk, const u16* __restrict__ wpq, const u16* __restrict__ wpv,
    const u16* __restrict__ wpad, const u16* __restrict__ wpinj, const float* __restrict__ xembf,
    const float* __restrict__ bk, const float* __restrict__ bq, const float* __restrict__ bv,
    const float* __restrict__ injb,
    u8* __restrict__ kvb, u16* __restrict__ qtb, u16* __restrict__ injv)
{
    __shared__ __align__(16) u16 wl[128*WLP];
    __shared__ __align__(16) u16 tb[4][16][TBW];
    const int tid = threadIdx.x, wave = tid>>6, lane = tid&63, lr = lane&15, lk = lane>>4;
    const int task = blockIdx.y;
    const int rw0 = blockIdx.x*128 + wave*32;
    f32x4 acc0[8], acc1[8];
    if (task == 2) {
        bf8_t e0[4], e1[4];
        load_af32(xembf, rw0 + lr, lk, e0);
        load_af32(xembf, rw0 + 16 + lr, lk, e1);
        stage_w(wpinj, wl, tid);
        __syncthreads();
        mfma_l2(e0, e1, wl, lr, lk, acc0, acc1);
        acc_to_tb(tb[wave], acc0, lr, lk, injb); tb_store(tb[wave], injv, 128, rw0, lr, lk);
        acc_to_tb(tb[wave], acc1, lr, lk, injb); tb_store(tb[wave], injv, 128, rw0 + 16, lr, lk);
        return;
    }
    bf8_t af0[4], af1[4];
    load_af16(X, rw0 + lr, lk, af0);
    load_af16(X, rw0 + 16 + lr, lk, af1);
    if (task == 0) {
        stage_w(wpk, wl, tid);
        __syncthreads();
        mfma_l2(af0, af1, wl, lr, lk, acc0, acc1);
        acc_to_tb(tb[wave], acc0, lr, lk, bk); tb_store_fp8(tb[wave], kvb, 256, rw0, lr, lk);
        acc_to_tb(tb[wave], acc1, lr, lk, bk); tb_store_fp8(tb[wave], kvb, 256, rw0 + 16, lr, lk);
    } else if (task == 1) {
        stage_w(wpv, wl, tid);
        __syncthreads();
        mfma_l2(af0, af1, wl, lr, lk, acc0, acc1);
        acc_to_tb(tb[wave], acc0, lr, lk, bv); tb_store_fp8(tb[wave], kvb + 128, 256, rw0, lr, lk);
        acc_to_tb(tb[wave], acc1, lr, lk, bv); tb_store_fp8(tb[wave], kvb + 128, 256, rw0 + 16, lr, lk);
    } else {
        // task 3: q once, then 3 block-diag transforms
        stage_w(wpq, wl, tid);
        __syncthreads();
        mfma_l2(af0, af1, wl, lr, lk, acc0, acc1);
        bf8_t ha0[4], ha1[4];
        acc_to_tb(tb[wave], acc0, lr, lk, bq); tb_frags(tb[wave], lr, lk, ha0);
        acc_to_tb(tb[wave], acc1, lr, lk, bq); tb_frags(tb[wave], lr, lk, ha1);
        #pragma unroll
        for (int t = 0; t < 3; ++t){
            mfma_bd2(ha0, ha1, wpad + t*4096, lr, lk, acc0, acc1);
            u16* o = qtb + (size_t)t*ND;
            acc_to_tb(tb[wave], acc0, lr, lk, nullptr); tb_store(tb[wave], o, 128, rw0, lr, lk);
            acc_to_tb(tb[wave], acc1, lr, lk, nullptr); tb_store(tb[wave], o, 128, rw0 + 16, lr, lk);
        }
    }
}

// ================= type-sorted merged CSR with self-loop slots =================
__global__ __launch_bounds__(256) void hist_k(const int* __restrict__ ei, int* __restrict__ cnt){
    int gid = blockIdx.x*256 + threadIdx.x;
    int t = gid / EE, e = gid - t*EE;
    int d = ei[t*2*EE + EE + e];
    atomicAdd(&cnt[t*NN + d], 1);
}
__global__ __launch_bounds__(256) void scanA_k(const int* __restrict__ cnt, int* __restrict__ s0off, int* __restrict__ parts){
    __shared__ int sums[256];
    int b = blockIdx.x; int base = b * 1024;
    int tid = threadIdx.x;
    int v[4]; int tsum = 0;
    #pragma unroll
    for (int i = 0; i < 4; ++i){
        int n = base + tid*4 + i;
        v[i] = cnt[n] + cnt[NN+n] + cnt[2*NN+n] + 3;
        tsum += v[i];
    }
    sums[tid] = tsum; __syncthreads();
    for (int ofs = 1; ofs < 256; ofs <<= 1) {
        int a = (tid >= ofs) ? sums[tid-ofs] : 0;
        __syncthreads();
        sums[tid] += a;
        __syncthreads();
    }
    int run = sums[tid] - tsum;
    #pragma unroll
    for (int i = 0; i < 4; ++i){ s0off[base + tid*4 + i] = run; run += v[i]; }
    if (tid == 255) parts[b] = sums[255];
}
__global__ void scan2_k(int* parts){
    if (threadIdx.x == 0 && blockIdx.x == 0) {
        int run = 0;
        for (int i = 0; i < 64; ++i) { int v = parts[i]; parts[i] = run; run += v; }
    }
}
__global__ __launch_bounds__(256) void scanB_k(const int* __restrict__ cnt, int* __restrict__ s0off,
                                               int* __restrict__ s1off, int* __restrict__ s2off,
                                               const int* __restrict__ parts){
    int b = blockIdx.x; int base = b * 1024;
    int add = parts[b];
    #pragma unroll
    for (int i = 0; i < 4; ++i){
        int n = base + threadIdx.x*4 + i;
        int m = s0off[n] + add;
        int c0 = cnt[n], c1 = cnt[NN+n];
        s0off[n] = m;
        s1off[n] = m + c0 + 1;
        s2off[n] = m + c0 + c1 + 2;
    }
    if (b == 0 && threadIdx.x == 0) s0off[NN] = CSRN;
}
__global__ __launch_bounds__(256) void selffill_k(const int* __restrict__ s0off, const int* __restrict__ s1off,
                                                  const int* __restrict__ s2off, int* __restrict__ csrc){
    int gid = blockIdx.x*256 + threadIdx.x;
    int t = gid / NN, n = gid - t*NN;
    int pos = (t==0) ? s0off[n] : (t==1 ? s1off[n] : s2off[n]);
    csrc[pos] = n;
}
__global__ __launch_bounds__(256) void scatter_k(const int* __restrict__ ei,
    const int* __restrict__ s0off, const int* __restrict__ s1off, const int* __restrict__ s2off,
    int* __restrict__ cur, int* __restrict__ csrc, int* __restrict__ posmap){
    int gid = blockIdx.x*256 + threadIdx.x;
    int t = gid / EE, e = gid - t*EE;
    int s = ei[t*2*EE + e];
    int d = ei[t*2*EE + EE + e];
    int p = atomicAdd(&cur[t*NN + d], 1);
    int basep = (t==0) ? s0off[d] : (t==1 ? s1off[d] : s2off[d]);
    int pos = basep + 1 + p;
    csrc[pos] = s;
    posmap[t*EE + e] = pos;
}

// ============ per-edge alpha precompute (GAT layer) ============
__global__ __launch_bounds__(256) void alpha_k(const float* __restrict__ alsb, const float* __restrict__ aldb,
    const int* __restrict__ ei, const int* __restrict__ posmap,
    const int* __restrict__ s0off, const int* __restrict__ s1off, const int* __restrict__ s2off,
    float4* __restrict__ ab)
{
    int gid = blockIdx.x*256 + threadIdx.x;
    int t = gid / NTOT, r = gid - t*NTOT;
    int s, d, pos;
    if (r < EE) {
        s = ei[t*2*EE + r];
        d = ei[t*2*EE + EE + r];
        pos = posmap[t*EE + r];
    } else {
        int n = r - EE;
        s = n; d = n;
        pos = (t==0) ? s0off[n] : (t==1 ? s1off[n] : s2off[n]);
    }
    const float* As = alsb + ((size_t)t*NN + s)*4;
    const float* Ad = aldb + ((size_t)t*NN + d)*4;
    float4 o;
    o.x = fexp(lrelu(As[0] + Ad[0]));
    o.y = fexp(lrelu(As[1] + Ad[1]));
    o.z = fexp(lrelu(As[2] + Ad[2]));
    o.w = fexp(lrelu(As[3] + Ad[3]));
    ab[pos] = o;
}

// ============ GAT aggregate: 4ch/lane, 2 edges/wave ============
__global__ __launch_bounds__(256) void gat_aggres_k(const u16* __restrict__ hb,
    const float* __restrict__ abf,
    const int* __restrict__ s0off, const int* __restrict__ s1off, const int* __restrict__ s2off,
    const int* __restrict__ csrc,
    const float* __restrict__ bias3, const u16* __restrict__ xoldb,
    const float* __restrict__ scale, u16* __restrict__ outb)
{
    int gid = blockIdx.x*256 + threadIdx.x;
    int node = gid >> 6, lane = gid & 63;
    int eh = lane >> 5, hh = (lane >> 3) & 3, cp = lane & 7;
    int ch = hh*32 + cp*4;
    int segb[4] = { s0off[node], s1off[node], s2off[node], s0off[node+1] };
    float a[4] = {0.f, 0.f, 0.f, 0.f};
    #pragma unroll
    for (int t = 0; t < 3; ++t) {
        const u16* h = hb + (size_t)t*ND;
        int beg = segb[t], end = segb[t+1];
        float ds = 0.f, s0 = 0.f, s1 = 0.f, s2 = 0.f, s3 = 0.f;
        for (int pos = beg; pos < end; pos += 4) {
            int p0 = pos + eh, p1 = pos + 2 + eh;
            int v0 = (p0 < end), v1 = (p1 < end);
            int q0 = v0 ? p0 : beg, q1 = v1 ? p1 : beg;
            int sA = csrc[q0], sB = csrc[q1];
            float alA = abf[(size_t)q0*4 + hh];
            float alB = abf[(size_t)q1*4 + hh];
            uint2 hA = *(const uint2*)&h[(size_t)sA*128 + ch];
            uint2 hB = *(const uint2*)&h[(size_t)sB*128 + ch];
            alA = v0 ? alA : 0.f;
            alB = v1 ? alB : 0.f;
            float2 wA0 = bf2x(hA.x), wA1 = bf2x(hA.y);
            float2 wB0 = bf2x(hB.x), wB1 = bf2x(hB.y);
            ds += alA + alB;
            s0 += alA*wA0.x + alB*wB0.x;
            s1 += alA*wA0.y + alB*wB0.y;
            s2 += alA*wA1.x + alB*wB1.x;
            s3 += alA*wA1.y + alB*wB1.y;
        }
        ds += __shfl_xor(ds, 32);
        s0 += __shfl_xor(s0, 32);
        s1 += __shfl_xor(s1, 32);
        s2 += __shfl_xor(s2, 32);
        s3 += __shfl_xor(s3, 32);
        float inv = 1.f/(ds + 1e-16f);
        a[0] += s0*inv; a[1] += s1*inv; a[2] += s2*inv; a[3] += s3*inv;
    }
    float4 b0 = *(const float4*)&bias3[ch];
    float4 b1 = *(const float4*)&bias3[128 + ch];
    float4 b2 = *(const float4*)&bias3[256 + ch];
    a[0] += b0.x + b1.x + b2.x;
    a[1] += b0.y + b1.y + b2.y;
    a[2] += b0.z + b1.z + b2.z;
    a[3] += b0.w + b1.w + b2.w;
    float ssum = a[0]*a[0] + a[1]*a[1] + a[2]*a[2] + a[3]*a[3];
    ssum += __shfl_xor(ssum, 1); ssum += __shfl_xor(ssum, 2);
    ssum += __shfl_xor(ssum, 4); ssum += __shfl_xor(ssum, 8);
    ssum += __shfl_xor(ssum, 16);
    float r = rsqrtf(ssum*(1.f/128.f) + 1e-6f);
    float4 sc = *(const float4*)&scale[ch];
    size_t off = (size_t)node*128 + ch;
    uint2 xo = *(const uint2*)&xoldb[off];
    float2 p0 = bf2x(xo.x), p1 = bf2x(xo.y);
    float y0 = lrelu(p0.x + sc.x*a[0]*r);
    float y1 = lrelu(p0.y + sc.y*a[1]*r);
    float y2 = lrelu(p1.x + sc.z*a[2]*r);
    float y3 = lrelu(p1.y + sc.w*a[3]*r);
    uint2 o2; o2.x = cvt2(y0, y1); o2.y = cvt2(y2, y3);
    *(uint2*)&outb[off] = o2;
}

// ============ HGT aggregate: fp8 kv, 4ch/lane, 2 edges/wave; pb interleaved [node][3][128] ============
__global__ __launch_bounds__(256) void hgt_agg_k(const u8* __restrict__ kvb,
    const u16* __restrict__ qtb, const float* __restrict__ prel,
    const int* __restrict__ s0off, const int* __restrict__ s1off, const int* __restrict__ s2off,
    const int* __restrict__ csrc, u16* __restrict__ pb)
{
    int gid = blockIdx.x*256 + threadIdx.x;
    int node = gid >> 6, lane = gid & 63;
    int eh = lane >> 5, hh = (lane >> 3) & 3, cp = lane & 7;
    int ch = hh*32 + cp*4;
    const float S = 0.17677669529663689f; // 1/sqrt(32)
    int segb[4] = { s0off[node], s1off[node], s2off[node], s0off[node+1] };
    float dsum = 0.f;
    float ac[3][4];
    #pragma unroll
    for (int t = 0; t < 3; ++t){ ac[t][0]=0.f; ac[t][1]=0.f; ac[t][2]=0.f; ac[t][3]=0.f; }
    #pragma unroll
    for (int t = 0; t < 3; ++t) {
        float ph = prel[t*4 + hh] * S;
        uint2 qw = *(const uint2*)&qtb[(size_t)t*ND + (size_t)node*128 + ch];
        float2 q0 = bf2x(qw.x), q1 = bf2x(qw.y);
        int self = segb[t];
        int beg = self + 1, end = segb[t+1];
        for (int pos = beg; pos < end; pos += 4) {
            int p0 = pos + eh, p1 = pos + 2 + eh;
            int v0 = (p0 < end), v1 = (p1 < end);
            int qp0 = v0 ? p0 : self, qp1 = v1 ? p1 : self;
            int sA = csrc[qp0], sB = csrc[qp1];
            size_t rA = (size_t)sA*256 + ch, rB = (size_t)sB*256 + ch;
            unsigned kA = *(const unsigned*)&kvb[rA], kB = *(const unsigned*)&kvb[rB];
            unsigned vA = *(const unsigned*)&kvb[rA + 128], vB = *(const unsigned*)&kvb[rB + 128];
            f32x2 kA0 = __builtin_amdgcn_cvt_pk_f32_fp8((int)kA, false);
            f32x2 kA1 = __builtin_amdgcn_cvt_pk_f32_fp8((int)kA, true);
            f32x2 kB0 = __builtin_amdgcn_cvt_pk_f32_fp8((int)kB, false);
            f32x2 kB1 = __builtin_amdgcn_cvt_pk_f32_fp8((int)kB, true);
            float scA = kA0[0]*q0.x + kA0[1]*q0.y + kA1[0]*q1.x + kA1[1]*q1.y;
            float scB = kB0[0]*q0.x + kB0[1]*q0.y + kB1[0]*q1.x + kB1[1]*q1.y;
            scA += __shfl_xor(scA, 1); scB += __shfl_xor(scB, 1);
            scA += __shfl_xor(scA, 2); scB += __shfl_xor(scB, 2);
            scA += __shfl_xor(scA, 4); scB += __shfl_xor(scB, 4);
            float eA = v0 ? fexp(scA*ph) : 0.f;
            float eB = v1 ? fexp(scB*ph) : 0.f;
            f32x2 vA0 = __builtin_amdgcn_cvt_pk_f32_fp8((int)vA, false);
            f32x2 vA1 = __builtin_amdgcn_cvt_pk_f32_fp8((int)vA, true);
            f32x2 vB0 = __builtin_amdgcn_cvt_pk_f32_fp8((int)vB, false);
            f32x2 vB1 = __builtin_amdgcn_cvt_pk_f32_fp8((int)vB, true);
            dsum += eA + eB;
            ac[t][0] += eA*vA0[0] + eB*vB0[0];
            ac[t][1] += eA*vA0[1] + eB*vB0[1];
            ac[t][2] += eA*vA1[0] + eB*vB1[0];
            ac[t][3] += eA*vA1[1] + eB*vB1[1];
        }
    }
    dsum += __shfl_xor(dsum, 32);
    #pragma unroll
    for (int t = 0; t < 3; ++t){
        ac[t][0] += __shfl_xor(ac[t][0], 32);
        ac[t][1] += __shfl_xor(ac[t][1], 32);
        ac[t][2] += __shfl_xor(ac[t][2], 32);
        ac[t][3] += __shfl_xor(ac[t][3], 32);
    }
    float inv = 1.f/(dsum + 1e-16f);
    size_t o = (size_t)node*384 + ch;
    #pragma unroll
    for (int t = 0; t < 3; ++t){
        uint2 o2;
        o2.x = cvt2(ac[t][0]*inv, ac[t][1]*inv);
        o2.y = cvt2(ac[t][2]*inv, ac[t][3]*inv);
        *(uint2*)&pb[o + (size_t)t*128] = o2;
    }
}

// ============ final: M-stage (block-diag) + Wo (LDS) + epilogue w/ precomputed injv ============
__global__ __launch_bounds__(256, 3) void final_k(const u16* __restrict__ pb,
    const u16* __restrict__ wpmd, const u16* __restrict__ wpo, const float* __restrict__ bo,
    const u16* __restrict__ x2b, const float* __restrict__ skipp, const float* __restrict__ scale,
    const u16* __restrict__ injv,
    const float* __restrict__ gbuf, const int* __restrict__ bszp,
    float* __restrict__ out)
{
    __shared__ __align__(16) u16 wl[128*WLP];
    __shared__ __align__(16) u16 tb[4][16][TBW];
    const int tid = threadIdx.x, wave = tid>>6, lane = tid&63, lr = lane&15, lk = lane>>4;
    const int rw = blockIdx.x*64 + wave*16;
    stage_w(wpo, wl, tid);
    // ---- agg_pre = Σ_t partial_t @ M_t (interleaved pb, block-diag packed B) ----
    f32x4 acc[8];
    #pragma unroll
    for (int i = 0; i < 8; ++i) acc[i] = (f32x4){0.f,0.f,0.f,0.f};
    {
        const u16* pr = pb + (size_t)(rw + lr)*384;
        #pragma unroll
        for (int t = 0; t < 3; ++t){
            bf8_t a0[4];
            #pragma unroll
            for (int kk = 0; kk < 4; ++kk)
                a0[kk] = *(const bf8_t*)(pr + t*128 + kk*32 + lk*8);
            mfma_bd1_acc(a0, wpmd + t*4096, lr, lk, acc);
        }
    }
    // ---- gelu -> tb -> A-frags ----
    bf8_t ga[4];
    acc_to_tb_gelu(tb[wave], acc, lr, lk);
    tb_frags(tb[wave], lr, lk, ga);
    // ---- Wo GEMM (LDS-staged) ----
    __syncthreads();
    mfma_l1(ga, wl, lr, lk, acc);
    bf8_t hw[4];
    acc_to_tb(tb[wave], acc, lr, lk, bo);
    tb_rows(tb[wave], lr, lk, hw);
    // ---- vectorized row-major epilogue (+ precomputed injv) ----
    const float sig = 1.f/(1.f + expf(-skipp[0]));
    const int cpb = NN / *bszp;
    float4 sca = *(const float4*)&scale[lr*8];
    float4 scb = *(const float4*)&scale[lr*8 + 4];
    #pragma unroll
    for (int c = 0; c < 4; ++c){
        int row = rw + c*4 + lk;
        bf8_t x8 = *(const bf8_t*)(x2b + (size_t)row*128 + lr*8);
        bf8_t i8 = *(const bf8_t*)(injv + (size_t)row*128 + lr*8);
        float x[8], v[8];
        float ssl = 0.f;
        #pragma unroll
        for (int j = 0; j < 8; ++j){
            x[j] = bf2f((u16)x8[j]);
            float h = bf2f((u16)hw[c][j]);
            v[j] = sig*h + (1.f - sig)*x[j];
            ssl += v[j]*v[j];
        }
        ssl += __shfl_xor(ssl, 1); ssl += __shfl_xor(ssl, 2);
        ssl += __shfl_xor(ssl, 4); ssl += __shfl_xor(ssl, 8);
        float rq = rsqrtf(ssl*(1.f/128.f) + 1e-6f);
        const float* gr = gbuf + (row / cpb)*256;
        float4 g0 = *(const float4*)&gr[lr*8];
        float4 g1 = *(const float4*)&gr[lr*8 + 4];
        float4 b0 = *(const float4*)&gr[128 + lr*8];
        float4 b1 = *(const float4*)&gr[128 + lr*8 + 4];
        float4 oA, oB;
        #pragma unroll
        for (int j = 0; j < 8; ++j){
            float scj = (j < 4) ? ((const float*)&sca)[j] : ((const float*)&scb)[j-4];
            float y = lrelu(x[j] + scj*v[j]*rq);
            float hf = y + bf2f((u16)i8[j]);
            float gj = (j < 4) ? ((const float*)&g0)[j] : ((const float*)&g1)[j-4];
            float bj = (j < 4) ? ((const float*)&b0)[j] : ((const float*)&b1)[j-4];
            float ov = (1.f + gj)*hf + bj;
            if (j < 4) ((float*)&oA)[j] = ov; else ((float*)&oB)[j-4] = ov;
        }
        *(float4*)(out + (size_t)row*128 + lr*8)     = oA;
        *(float4*)(out + (size_t)row*128 + lr*8 + 4) = oB;
    }
}

// ============ FiLM small MLP ============
__global__ __launch_bounds__(256) void film_k(const float* __restrict__ z,
    const float* __restrict__ W1, const float* __restrict__ b1,
    const float* __restrict__ W2, const float* __restrict__ b2,
    float* __restrict__ gb)
{
    __shared__ float zr[128];
    __shared__ float g1[256];
    int r = blockIdx.x, tid = threadIdx.x;
    if (tid < 128) zr[tid] = z[r*128 + tid];
    __syncthreads();
    float s = b1[tid];
    for (int k = 0; k < 128; ++k) s += zr[k]*W1[k*256 + tid];
    g1[tid] = gelu_exact(s);
    __syncthreads();
    float s2 = b2[tid];
    for (int k = 0; k < 256; ++k) s2 += g1[k]*W2[k*256 + tid];
    gb[r*256 + tid] = 0.1f*tanhf(s2);
}

// ================= launch =================
extern "C" void kernel_launch(void* const* d_in, const int* in_sizes, int n_in,
                              void* d_out, int out_size, void* d_ws, size_t ws_size,
                              hipStream_t stream)
{
    const float* x_cell = (const float*)d_in[0];
    const float* z_h    = (const float*)d_in[1];
    const float* x_emb  = (const float*)d_in[2];
    const int*   eidx   = (const int*)d_in[3];
    const int*   bszp   = (const int*)d_in[4];
    const float* g1W  = (const float*)d_in[5];
    const float* g1as = (const float*)d_in[6];
    const float* g1ad = (const float*)d_in[7];
    const float* g1b  = (const float*)d_in[8];
    const float* g2W  = (const float*)d_in[9];
    const float* g2as = (const float*)d_in[10];
    const float* g2ad = (const float*)d_in[11];
    const float* g2b  = (const float*)d_in[12];
    const float* n1s  = (const float*)d_in[13];
    const float* n2s  = (const float*)d_in[14];
    const float* n3s  = (const float*)d_in[15];
    const float* Wk   = (const float*)d_in[16];
    const float* bk   = (const float*)d_in[17];
    const float* Wq   = (const float*)d_in[18];
    const float* bq   = (const float*)d_in[19];
    const float* Wv   = (const float*)d_in[20];
    const float* bv   = (const float*)d_in[21];
    const float* arel = (const float*)d_in[22];
    const float* mrel = (const float*)d_in[23];
    const float* prel = (const float*)d_in[24];
    const float* Wo   = (const float*)d_in[25];
    const float* bo   = (const float*)d_in[26];
    const float* skipp= (const float*)d_in[27];
    const float* injW = (const float*)d_in[28];
    const float* injb = (const float*)d_in[29];
    const float* fW1  = (const float*)d_in[30];
    const float* fb1  = (const float*)d_in[31];
    const float* fW2  = (const float*)d_in[32];
    const float* fb2  = (const float*)d_in[33];

    // ---- workspace layout ----
    u16* wp   = (u16*)d_ws;                   // 17*16384 u16
    u16* wpa  = wp + (size_t)17*16384;        // 6*2048 u16
    float4* ab = (float4*)(wpa + 6*2048);     // CSRN float4
    u16* x0b  = (u16*)(ab + CSRN);            // ND u16 (x_cell bf16)
    u16* x1b  = x0b + ND;                     // ND u16
    u16* x2b  = x1b + ND;                     // ND u16
    u8*  kvb  = (u8*)(x2b + ND);              // NN*256 bytes (k|v fp8)
    u16* pb   = (u16*)(kvb + (size_t)NN*256); // 3*ND u16 (interleaved [node][3][128])
    u16* hb   = pb + 3*ND;                    // 3*ND u16 (reused as qtb)
    u16* injv = hb + 3*ND;                    // ND u16 (inject result, bias folded)
    float* alsb = (float*)(injv + ND);        // 3*NN*4 f32
    float* aldb = alsb + (size_t)3*NN*4;      // 3*NN*4 f32
    float* gbuf = aldb + (size_t)3*NN*4;      // 32*256 f32
    int* s0off  = (int*)(gbuf + 32*256);      // NN+1
    int* s1off  = s0off + (NN+1);             // NN
    int* s2off  = s1off + NN;                 // NN
    int* csrc   = s2off + NN;                 // CSRN
    int* posmap = csrc + CSRN;                // 3*EE
    int* tmpc   = posmap + 3*EE;              // 3*NN (cnt)
    int* cur    = tmpc + 3*NN;                // 3*NN
    int* parts  = cur + 3*NN;                 // 256

    u16* qtb = hb;
    float* outp = (float*)d_out;

    const u16* wpg1 = wp;
    const u16* wpg2 = wp + (size_t)3*16384;
    const u16* wpk  = wp + (size_t)6*16384;
    const u16* wpq  = wp + (size_t)7*16384;
    const u16* wpv  = wp + (size_t)8*16384;
    const u16* wpo  = wp + (size_t)9*16384;
    const u16* wpinj= wp + (size_t)10*16384;
    const u16* wpad = wp + (size_t)11*16384;            // packed arel [3][4096]
    const u16* wpmd = wpad + (size_t)3*4096;            // packed mrel [3][4096]

    // ---- weight pre-pack + x_cell cast ----
    wpack_k<<<18, 256, 0, stream>>>(g1W, g2W, Wk, Wq, Wv, Wo, injW, arel, mrel,
                                    g1as, g1ad, g2as, g2ad, wp, wpa);
    xcast_k<<<(int)(ND/2048), 256, 0, stream>>>(x_cell, x0b);

    // ---- type-sorted merged CSR with self slots ----
    hipMemsetAsync(tmpc, 0, 3*NN*sizeof(int), stream);
    hist_k<<<3*EE/256, 256, 0, stream>>>(eidx, tmpc);
    scanA_k<<<64, 256, 0, stream>>>(tmpc, s0off, parts);
    scan2_k<<<1, 64, 0, stream>>>(parts);
    scanB_k<<<64, 256, 0, stream>>>(tmpc, s0off, s1off, s2off, parts);
    selffill_k<<<3*NN/256, 256, 0, stream>>>(s0off, s1off, s2off, csrc);
    hipMemsetAsync(cur, 0, 3*NN*sizeof(int), stream);
    scatter_k<<<3*EE/256, 256, 0, stream>>>(eidx, s0off, s1off, s2off, cur, csrc, posmap);

    // ---- FiLM small MLP ----
    int B = in_sizes[1] / 128;
    film_k<<<B, 256, 0, stream>>>(z_h, fW1, fb1, fW2, fb2, gbuf);

    // ---- GAT layer 1 ----
    gat_gemm3_k<<<dim3(512,3), 256, 0, stream>>>(x0b, wpg1, wpa, hb, alsb, aldb);
    alpha_k<<<3*NTOT/256, 256, 0, stream>>>(alsb, aldb, eidx, posmap, s0off, s1off, s2off, ab);
    gat_aggres_k<<<16384, 256, 0, stream>>>(hb, (const float*)ab, s0off, s1off, s2off, csrc,
                                            g1b, x0b, n1s, x1b);

    // ---- GAT layer 2 ----
    gat_gemm3_k<<<dim3(512,3), 256, 0, stream>>>(x1b, wpg2, wpa + 3*2048, hb, alsb, aldb);
    alpha_k<<<3*NTOT/256, 256, 0, stream>>>(alsb, aldb, eidx, posmap, s0off, s1off, s2off, ab);
    gat_aggres_k<<<16384, 256, 0, stream>>>(hb, (const float*)ab, s0off, s1off, s2off, csrc,
                                            g2b, x1b, n2s, x2b);

    // ---- HGT projections + inject (4 tasks) ----
    hgt_proj_k<<<dim3(512,4), 256, 0, stream>>>(x2b, wpk, wpq, wpv, wpad, wpinj, x_emb,
                                                bk, bq, bv, injb, kvb, qtb, injv);
    hgt_agg_k<<<16384, 256, 0, stream>>>(kvb, qtb, prel, s0off, s1off, s2off, csrc, pb);

    // ---- final ----
    final_k<<<1024, 256, 0, stream>>>(pb, wpmd, wpo, bo, x2b, skipp, n3s,
                                      injv, gbuf, bszp, outp);
}

// Round 23
// 533.766 us; speedup vs baseline: 1.0459x; 1.0043x over previous
//
#include <hip/hip_runtime.h>

#define NN 65536
#define EE 262144
#define ND ((size_t)NN * 128)
#define TBW 132
#define WLP 136   // LDS weight pitch (u16)
#define NTOT (EE + NN)          // edges + selfs per type
#define CSRN (3*EE + 3*NN)      // total CSR slots

typedef unsigned short u16;
typedef unsigned char u8;
typedef short bf8_t __attribute__((ext_vector_type(8)));
typedef float f32x4 __attribute__((ext_vector_type(4)));
typedef float f32x2 __attribute__((ext_vector_type(2)));

__device__ __forceinline__ float lrelu(float x){ return x > 0.f ? x : 0.2f*x; }
__device__ __forceinline__ float gelu_exact(float x){ return 0.5f*x*(1.f+erff(x*0.70710678118654752f)); }
__device__ __forceinline__ float fexp(float x){ return __expf(x); }
__device__ __forceinline__ u16 f2bf(float f){
    union { float f; unsigned u; } v; v.f = f;
    unsigned u = v.u;
    return (u16)((u + 0x7FFFu + ((u >> 16) & 1u)) >> 16);
}
__device__ __forceinline__ float bf2f(u16 b){
    union { unsigned u; float f; } v; v.u = ((unsigned)b) << 16; return v.f;
}
__device__ __forceinline__ float2 bf2x(unsigned p){
    union { unsigned u; float f; } a, b;
    a.u = (p & 0xFFFFu) << 16; b.u = p & 0xFFFF0000u;
    return make_float2(a.f, b.f);
}
__device__ __forceinline__ unsigned cvt2(float a, float b){
    unsigned r; asm("v_cvt_pk_bf16_f32 %0, %1, %2" : "=v"(r) : "v"(a), "v"(b)); return r;
}
// ---- fp8 e4m3 (OCP) HW conversions ----
__device__ __forceinline__ unsigned enc_fp8x4(float a, float b, float c, float d){
    int r = __builtin_amdgcn_cvt_pk_fp8_f32(a, b, 0, false);
    r = __builtin_amdgcn_cvt_pk_fp8_f32(c, d, r, true);
    return (unsigned)r;
}

// ============ A-fragment loads ============
__device__ __forceinline__ void load_af32(const float* __restrict__ X, int row, int lk, bf8_t* af){
    #pragma unroll
    for (int kk = 0; kk < 4; ++kk){
        const float* p = X + (size_t)row*128 + kk*32 + lk*8;
        float4 a = *(const float4*)p;
        float4 b = *(const float4*)(p+4);
        union { bf8_t v; unsigned u[4]; } r;
        r.u[0] = cvt2(a.x, a.y); r.u[1] = cvt2(a.z, a.w);
        r.u[2] = cvt2(b.x, b.y); r.u[3] = cvt2(b.z, b.w);
        af[kk] = r.v;
    }
}
__device__ __forceinline__ void load_af16(const u16* __restrict__ X, int row, int lk, bf8_t* af){
    #pragma unroll
    for (int kk = 0; kk < 4; ++kk)
        af[kk] = *(const bf8_t*)(X + (size_t)row*128 + kk*32 + lk*8);
}

// ============ LDS weight staging ============
__device__ __forceinline__ void stage_w(const u16* __restrict__ src, u16* __restrict__ wl, int tid){
    #pragma unroll
    for (int j = 0; j < 8; ++j){
        int o = (j*256 + tid)*8;
        bf8_t v = *(const bf8_t*)(src + o);
        *(bf8_t*)(wl + ((o>>7)*WLP + (o&127))) = v;
    }
}

// ============ MFMA from LDS-staged weights ============
__device__ __forceinline__ void mfma_l1(const bf8_t* af, const u16* __restrict__ wl,
                                        int lr, int lk, f32x4* acc){
    #pragma unroll
    for (int i = 0; i < 8; ++i) acc[i] = (f32x4){0.f,0.f,0.f,0.f};
    #pragma unroll
    for (int kk = 0; kk < 4; ++kk){
        bf8_t B[8];
        #pragma unroll
        for (int nt = 0; nt < 8; ++nt)
            B[nt] = *(const bf8_t*)&wl[(nt*16+lr)*WLP + kk*32 + lk*8];
        #pragma unroll
        for (int nt = 0; nt < 8; ++nt)
            acc[nt] = __builtin_amdgcn_mfma_f32_16x16x32_bf16(af[kk], B[nt], acc[nt], 0, 0, 0);
    }
}
__device__ __forceinline__ void mfma_l2(const bf8_t* af0, const bf8_t* af1,
                                        const u16* __restrict__ wl,
                                        int lr, int lk, f32x4* acc0, f32x4* acc1){
    #pragma unroll
    for (int i = 0; i < 8; ++i){ acc0[i] = (f32x4){0.f,0.f,0.f,0.f}; acc1[i] = (f32x4){0.f,0.f,0.f,0.f}; }
    #pragma unroll
    for (int kk = 0; kk < 4; ++kk){
        bf8_t B[8];
        #pragma unroll
        for (int nt = 0; nt < 8; ++nt)
            B[nt] = *(const bf8_t*)&wl[(nt*16+lr)*WLP + kk*32 + lk*8];
        #pragma unroll
        for (int nt = 0; nt < 8; ++nt){
            acc0[nt] = __builtin_amdgcn_mfma_f32_16x16x32_bf16(af0[kk], B[nt], acc0[nt], 0, 0, 0);
            acc1[nt] = __builtin_amdgcn_mfma_f32_16x16x32_bf16(af1[kk], B[nt], acc1[nt], 0, 0, 0);
        }
    }
}
// ============ block-diagonal MFMA: packed B [8 nt][16 lr][32 k] from GLOBAL ============
__device__ __forceinline__ void mfma_bd1_acc(const bf8_t* af, const u16* __restrict__ Bp,
                                             int lr, int lk, f32x4* acc){
    bf8_t B[8];
    #pragma unroll
    for (int nt = 0; nt < 8; ++nt)
        B[nt] = *(const bf8_t*)&Bp[nt*512 + lr*32 + lk*8];
    #pragma unroll
    for (int nt = 0; nt < 8; ++nt)
        acc[nt] = __builtin_amdgcn_mfma_f32_16x16x32_bf16(af[nt>>1], B[nt], acc[nt], 0, 0, 0);
}
__device__ __forceinline__ void mfma_bd2(const bf8_t* af0, const bf8_t* af1,
                                         const u16* __restrict__ Bp,
                                         int lr, int lk, f32x4* acc0, f32x4* acc1){
    bf8_t B[8];
    #pragma unroll
    for (int nt = 0; nt < 8; ++nt)
        B[nt] = *(const bf8_t*)&Bp[nt*512 + lr*32 + lk*8];
    #pragma unroll
    for (int nt = 0; nt < 8; ++nt){
        acc0[nt] = __builtin_amdgcn_mfma_f32_16x16x32_bf16(af0[nt>>1], B[nt], (f32x4){0.f,0.f,0.f,0.f}, 0, 0, 0);
        acc1[nt] = __builtin_amdgcn_mfma_f32_16x16x32_bf16(af1[nt>>1], B[nt], (f32x4){0.f,0.f,0.f,0.f}, 0, 0, 0);
    }
}

// ============ per-wave LDS transpose buffer ============
__device__ __forceinline__ void acc_to_tb(u16 (*tbw)[TBW], const f32x4* acc, int lr, int lk, const float* bias){
    asm volatile("s_waitcnt lgkmcnt(0)" ::: "memory");
    #pragma unroll
    for (int nt = 0; nt < 8; ++nt){
        int col = nt*16 + lr;
        float badd = bias ? bias[col] : 0.f;
        #pragma unroll
        for (int i = 0; i < 4; ++i) tbw[lk*4+i][col] = f2bf(acc[nt][i] + badd);
    }
    asm volatile("s_waitcnt lgkmcnt(0)" ::: "memory");
}
__device__ __forceinline__ void acc_to_tb_gelu(u16 (*tbw)[TBW], const f32x4* acc, int lr, int lk){
    asm volatile("s_waitcnt lgkmcnt(0)" ::: "memory");
    #pragma unroll
    for (int nt = 0; nt < 8; ++nt){
        int col = nt*16 + lr;
        #pragma unroll
        for (int i = 0; i < 4; ++i) tbw[lk*4+i][col] = f2bf(gelu_exact(acc[nt][i]));
    }
    asm volatile("s_waitcnt lgkmcnt(0)" ::: "memory");
}
__device__ __forceinline__ void tb_store(const u16 (*tbw)[TBW], u16* __restrict__ O, size_t rowstride, int rowbase, int lr, int lk){
    #pragma unroll
    for (int c = 0; c < 4; ++c){
        bf8_t v = *(const bf8_t*)&tbw[c*4+lk][lr*8];
        *(bf8_t*)(O + (size_t)(rowbase + c*4 + lk)*rowstride + lr*8) = v;
    }
}
// fp8 store: rowstride in BYTES
__device__ __forceinline__ void tb_store_fp8(const u16 (*tbw)[TBW], u8* __restrict__ O, size_t rowstride, int rowbase, int lr, int lk){
    #pragma unroll
    for (int c = 0; c < 4; ++c){
        bf8_t v = *(const bf8_t*)&tbw[c*4+lk][lr*8];
        float f[8];
        #pragma unroll
        for (int j = 0; j < 8; ++j) f[j] = bf2f((u16)v[j]);
        uint2 o2;
        o2.x = enc_fp8x4(f[0], f[1], f[2], f[3]);
        o2.y = enc_fp8x4(f[4], f[5], f[6], f[7]);
        *(uint2*)(O + (size_t)(rowbase + c*4 + lk)*rowstride + lr*8) = o2;
    }
}
__device__ __forceinline__ void tb_frags(const u16 (*tbw)[TBW], int lr, int lk, bf8_t* ha){
    #pragma unroll
    for (int kk = 0; kk < 4; ++kk) ha[kk] = *(const bf8_t*)&tbw[lr][kk*32 + lk*8];
}
__device__ __forceinline__ void tb_rows(const u16 (*tbw)[TBW], int lr, int lk, bf8_t* rw){
    #pragma unroll
    for (int c = 0; c < 4; ++c) rw[c] = *(const bf8_t*)&tbw[c*4+lk][lr*8];
}

// ============ x_cell f32 -> bf16 one-time cast ============
__global__ __launch_bounds__(256) void xcast_k(const float* __restrict__ X, u16* __restrict__ O){
    size_t gid = (size_t)blockIdx.x*256 + threadIdx.x;
    const float* p = X + gid*8;
    float4 a = *(const float4*)p;
    float4 b = *(const float4*)(p+4);
    union { bf8_t v; unsigned u[4]; } r;
    r.u[0] = cvt2(a.x, a.y); r.u[1] = cvt2(a.z, a.w);
    r.u[2] = cvt2(b.x, b.y); r.u[3] = cvt2(b.z, b.w);
    *(bf8_t*)(O + gid*8) = r.v;
}

// ============ weight pre-pack ============
__global__ __launch_bounds__(256) void wpack_k(
    const float* __restrict__ g1W, const float* __restrict__ g2W,
    const float* __restrict__ Wk, const float* __restrict__ Wq, const float* __restrict__ Wv,
    const float* __restrict__ Wo, const float* __restrict__ injW,
    const float* __restrict__ arel, const float* __restrict__ mrel,
    const float* __restrict__ g1as, const float* __restrict__ g1ad,
    const float* __restrict__ g2as, const float* __restrict__ g2ad,
    u16* __restrict__ wp, u16* __restrict__ wpa)
{
    int b = blockIdx.x, tid = threadIdx.x;
    if (b < 11) {
        const float* src;
        if (b < 3) src = g1W + b*16384;
        else if (b < 6) src = g2W + (b-3)*16384;
        else if (b == 6) src = Wk;
        else if (b == 7) src = Wq;
        else if (b == 8) src = Wv;
        else if (b == 9) src = Wo;
        else src = injW;
        u16* dst = wp + (size_t)b*16384;
        for (int idx = tid; idx < 16384; idx += 256) {
            int n = idx >> 7, k = idx & 127;
            dst[idx] = f2bf(src[k*128 + n]);
        }
    } else if (b < 17) {
        int rel2 = (b < 14);
        const float* src = rel2 ? (arel + (b-11)*4096) : (mrel + (b-14)*4096);
        u16* dst = wp + (size_t)11*16384 + (size_t)(b-11)*4096;
        for (int idx = tid; idx < 4096; idx += 256) {
            int nt = idx >> 9, rest = idx & 511;
            int lr = rest >> 5, kp = rest & 31;
            int h = nt >> 1, c = (nt & 1)*16 + lr;
            float v = rel2 ? src[h*1024 + c*32 + kp] : src[h*1024 + kp*32 + c];
            dst[idx] = f2bf(v);
        }
    } else {
        for (int idx = tid; idx < 6*2048; idx += 256) {
            int m = idx >> 11;
            int j = idx & 2047;
            int cg = j >> 7, k = j & 127;
            const float* as = (m < 3) ? g1as : g2as;
            const float* ad = (m < 3) ? g1ad : g2ad;
            int t = (m < 3) ? m : m - 3;
            float v = 0.f;
            if (cg < 4)      { if ((k>>5)==cg)   v = as[t*128 + cg*32 + (k&31)]; }
            else if (cg < 8) { int g = cg-4; if ((k>>5)==g) v = ad[t*128 + g*32 + (k&31)]; }
            wpa[idx] = f2bf(v);
        }
    }
}

// ============ GAT projection: grid (512 rowblocks x 3 types), bf16 input ============
__global__ __launch_bounds__(256, 3) void gat_gemm3_k(const u16* __restrict__ Xb,
    const u16* __restrict__ wpg, const u16* __restrict__ wpa,
    u16* __restrict__ hb, float* __restrict__ alsb, float* __restrict__ aldb)
{
    __shared__ __align__(16) u16 wl[128*WLP];
    __shared__ __align__(16) u16 tb[4][16][TBW];
    const int tid = threadIdx.x, wave = tid>>6, lane = tid&63, lr = lane&15, lk = lane>>4;
    const int t = blockIdx.y;
    const int rw0 = blockIdx.x*128 + wave*32;
    bf8_t af0[4], af1[4];
    load_af16(Xb, rw0 + lr, lk, af0);
    load_af16(Xb, rw0 + 16 + lr, lk, af1);
    stage_w(wpg + t*16384, wl, tid);
    bf8_t Ba[4];
    #pragma unroll
    for (int kk = 0; kk < 4; ++kk)
        Ba[kk] = *(const bf8_t*)&wpa[t*2048 + lr*128 + kk*32 + lk*8];
    __syncthreads();
    f32x4 acc0[8], acc1[8];
    mfma_l2(af0, af1, wl, lr, lk, acc0, acc1);
    u16* h = hb + (size_t)t*ND;
    float* alst = alsb + (size_t)t*NN*4;
    float* aldt = aldb + (size_t)t*NN*4;
    {
        acc_to_tb(tb[wave], acc0, lr, lk, nullptr);
        tb_store(tb[wave], h, 128, rw0, lr, lk);
        bf8_t ha[4]; tb_frags(tb[wave], lr, lk, ha);
        f32x4 a2 = (f32x4){0.f,0.f,0.f,0.f};
        #pragma unroll
        for (int kk = 0; kk < 4; ++kk)
            a2 = __builtin_amdgcn_mfma_f32_16x16x32_bf16(ha[kk], Ba[kk], a2, 0, 0, 0);
        if (lr < 8){
            float* dp = (lr < 4) ? alst : aldt;
            int g = lr & 3;
            #pragma unroll
            for (int i = 0; i < 4; ++i) dp[(size_t)(rw0 + lk*4 + i)*4 + g] = a2[i];
        }
    }
    {
        acc_to_tb(tb[wave], acc1, lr, lk, nullptr);
        tb_store(tb[wave], h, 128, rw0 + 16, lr, lk);
        bf8_t ha[4]; tb_frags(tb[wave], lr, lk, ha);
        f32x4 a2 = (f32x4){0.f,0.f,0.f,0.f};
        #pragma unroll
        for (int kk = 0; kk < 4; ++kk)
            a2 = __builtin_amdgcn_mfma_f32_16x16x32_bf16(ha[kk], Ba[kk], a2, 0, 0, 0);
        if (lr < 8){
            float* dp = (lr < 4) ? alst : aldt;
            int g = lr & 3;
            #pragma unroll
            for (int i = 0; i < 4; ++i) dp[(size_t)(rw0 + 16 + lk*4 + i)*4 + g] = a2[i];
        }
    }
}

// ============ HGT projections + inject: grid (512 rowblocks x 4 tasks) ============
// task 0: k -> kv[:,0:128] fp8 | 1: v -> kv[:,128:256] fp8 | 2: inj -> injv bf16
// task 3: q = x@Wq + bq computed ONCE, then qt_t = q @ A_t^T for t=0..2 (bf16)
__global__ __launch_bounds__(256, 3) void hgt_proj_k(const u16* __restrict__ X,
    const u16* __restrict__ wpk, const u16* __restrict__ wpq, const u16* __restrict__ wpv,
    const u16* __restrict__ wpad, const u16* __restrict__ wpinj, const float* __restrict__ xembf,
    const float* __restrict__ bk, const float* __restrict__ bq, const float* __restrict__ bv,
    const float* __restrict__ injb,
    u8* __restrict__ kvb, u16* __restrict__ qtb, u16* __restrict__ injv)
{
    __shared__ __align__(16) u16 wl[128*WLP];
    __shared__ __align__(16) u16 tb[4][16][TBW];
    const int tid = threadIdx.x, wave = tid>>6, lane = tid&63, lr = lane&15, lk = lane>>4;
    const int task = blockIdx.y;
    const int rw0 = blockIdx.x*128 + wave*32;
    f32x4 acc0[8], acc1[8];
    if (task == 2) {
        bf8_t e0[4], e1[4];
        load_af32(xembf, rw0 + lr, lk, e0);
        load_af32(xembf, rw0 + 16 + lr, lk, e1);
        stage_w(wpinj, wl, tid);
        __syncthreads();
        mfma_l2(e0, e1, wl, lr, lk, acc0, acc1);
        acc_to_tb(tb[wave], acc0, lr, lk, injb); tb_store(tb[wave], injv, 128, rw0, lr, lk);
        acc_to_tb(tb[wave], acc1, lr, lk, injb); tb_store(tb[wave], injv, 128, rw0 + 16, lr, lk);
        return;
    }
    bf8_t af0[4], af1[4];
    load_af16(X, rw0 + lr, lk, af0);
    load_af16(X, rw0 + 16 + lr, lk, af1);
    if (task == 0) {
        stage_w(wpk, wl, tid);
        __syncthreads();
        mfma_l2(af0, af1, wl, lr, lk, acc0, acc1);
        acc_to_tb(tb[wave], acc0, lr, lk, bk); tb_store_fp8(tb[wave], kvb, 256, rw0, lr, lk);
        acc_to_tb(tb[wave], acc1, lr, lk, bk); tb_store_fp8(tb[wave], kvb, 256, rw0 + 16, lr, lk);
    } else if (task == 1) {
        stage_w(wpv, wl, tid);
        __syncthreads();
        mfma_l2(af0, af1, wl, lr, lk, acc0, acc1);
        acc_to_tb(tb[wave], acc0, lr, lk, bv); tb_store_fp8(tb[wave], kvb + 128, 256, rw0, lr, lk);
        acc_to_tb(tb[wave], acc1, lr, lk, bv); tb_store_fp8(tb[wave], kvb + 128, 256, rw0 + 16, lr, lk);
    } else {
        // task 3: q once, then 3 block-diag transforms (bf16 out)
        stage_w(wpq, wl, tid);
        __syncthreads();
        mfma_l2(af0, af1, wl, lr, lk, acc0, acc1);
        bf8_t ha0[4], ha1[4];
        acc_to_tb(tb[wave], acc0, lr, lk, bq); tb_frags(tb[wave], lr, lk, ha0);
        acc_to_tb(tb[wave], acc1, lr, lk, bq); tb_frags(tb[wave], lr, lk, ha1);
        #pragma unroll
        for (int t = 0; t < 3; ++t){
            mfma_bd2(ha0, ha1, wpad + t*4096, lr, lk, acc0, acc1);
            u16* o = qtb + (size_t)t*ND;
            acc_to_tb(tb[wave], acc0, lr, lk, nullptr); tb_store(tb[wave], o, 128, rw0, lr, lk);
            acc_to_tb(tb[wave], acc1, lr, lk, nullptr); tb_store(tb[wave], o, 128, rw0 + 16, lr, lk);
        }
    }
}

// ================= type-sorted merged CSR with self-loop slots =================
__global__ __launch_bounds__(256) void hist_k(const int* __restrict__ ei, int* __restrict__ cnt){
    int gid = blockIdx.x*256 + threadIdx.x;
    int t = gid / EE, e = gid - t*EE;
    int d = ei[t*2*EE + EE + e];
    atomicAdd(&cnt[t*NN + d], 1);
}
__global__ __launch_bounds__(256) void scanA_k(const int* __restrict__ cnt, int* __restrict__ s0off, int* __restrict__ parts){
    __shared__ int sums[256];
    int b = blockIdx.x; int base = b * 1024;
    int tid = threadIdx.x;
    int v[4]; int tsum = 0;
    #pragma unroll
    for (int i = 0; i < 4; ++i){
        int n = base + tid*4 + i;
        v[i] = cnt[n] + cnt[NN+n] + cnt[2*NN+n] + 3;
        tsum += v[i];
    }
    sums[tid] = tsum; __syncthreads();
    for (int ofs = 1; ofs < 256; ofs <<= 1) {
        int a = (tid >= ofs) ? sums[tid-ofs] : 0;
        __syncthreads();
        sums[tid] += a;
        __syncthreads();
    }
    int run = sums[tid] - tsum;
    #pragma unroll
    for (int i = 0; i < 4; ++i){ s0off[base + tid*4 + i] = run; run += v[i]; }
    if (tid == 255) parts[b] = sums[255];
}
__global__ void scan2_k(int* parts){
    if (threadIdx.x == 0 && blockIdx.x == 0) {
        int run = 0;
        for (int i = 0; i < 64; ++i) { int v = parts[i]; parts[i] = run; run += v; }
    }
}
__global__ __launch_bounds__(256) void scanB_k(const int* __restrict__ cnt, int* __restrict__ s0off,
                                               int* __restrict__ s1off, int* __restrict__ s2off,
                                               const int* __restrict__ parts){
    int b = blockIdx.x; int base = b * 1024;
    int add = parts[b];
    #pragma unroll
    for (int i = 0; i < 4; ++i){
        int n = base + threadIdx.x*4 + i;
        int m = s0off[n] + add;
        int c0 = cnt[n], c1 = cnt[NN+n];
        s0off[n] = m;
        s1off[n] = m + c0 + 1;
        s2off[n] = m + c0 + c1 + 2;
    }
    if (b == 0 && threadIdx.x == 0) s0off[NN] = CSRN;
}
__global__ __launch_bounds__(256) void selffill_k(const int* __restrict__ s0off, const int* __restrict__ s1off,
                                                  const int* __restrict__ s2off, int* __restrict__ csrc){
    int gid = blockIdx.x*256 + threadIdx.x;
    int t = gid / NN, n = gid - t*NN;
    int pos = (t==0) ? s0off[n] : (t==1 ? s1off[n] : s2off[n]);
    csrc[pos] = n;
}
__global__ __launch_bounds__(256) void scatter_k(const int* __restrict__ ei,
    const int* __restrict__ s0off, const int* __restrict__ s1off, const int* __restrict__ s2off,
    int* __restrict__ cur, int* __restrict__ csrc, int* __restrict__ posmap){
    int gid = blockIdx.x*256 + threadIdx.x;
    int t = gid / EE, e = gid - t*EE;
    int s = ei[t*2*EE + e];
    int d = ei[t*2*EE + EE + e];
    int p = atomicAdd(&cur[t*NN + d], 1);
    int basep = (t==0) ? s0off[d] : (t==1 ? s1off[d] : s2off[d]);
    int pos = basep + 1 + p;
    csrc[pos] = s;
    posmap[t*EE + e] = pos;
}

// ============ per-edge alpha precompute (GAT layer) ============
__global__ __launch_bounds__(256) void alpha_k(const float* __restrict__ alsb, const float* __restrict__ aldb,
    const int* __restrict__ ei, const int* __restrict__ posmap,
    const int* __restrict__ s0off, const int* __restrict__ s1off, const int* __restrict__ s2off,
    float4* __restrict__ ab)
{
    int gid = blockIdx.x*256 + threadIdx.x;
    int t = gid / NTOT, r = gid - t*NTOT;
    int s, d, pos;
    if (r < EE) {
        s = ei[t*2*EE + r];
        d = ei[t*2*EE + EE + r];
        pos = posmap[t*EE + r];
    } else {
        int n = r - EE;
        s = n; d = n;
        pos = (t==0) ? s0off[n] : (t==1 ? s1off[n] : s2off[n]);
    }
    const float* As = alsb + ((size_t)t*NN + s)*4;
    const float* Ad = aldb + ((size_t)t*NN + d)*4;
    float4 o;
    o.x = fexp(lrelu(As[0] + Ad[0]));
    o.y = fexp(lrelu(As[1] + Ad[1]));
    o.z = fexp(lrelu(As[2] + Ad[2]));
    o.w = fexp(lrelu(As[3] + Ad[3]));
    ab[pos] = o;
}

// ============ GAT aggregate: 4ch/lane, 2 edges/wave ============
__global__ __launch_bounds__(256) void gat_aggres_k(const u16* __restrict__ hb,
    const float* __restrict__ abf,
    const int* __restrict__ s0off, const int* __restrict__ s1off, const int* __restrict__ s2off,
    const int* __restrict__ csrc,
    const float* __restrict__ bias3, const u16* __restrict__ xoldb,
    const float* __restrict__ scale, u16* __restrict__ outb)
{
    int gid = blockIdx.x*256 + threadIdx.x;
    int node = gid >> 6, lane = gid & 63;
    int eh = lane >> 5, hh = (lane >> 3) & 3, cp = lane & 7;
    int ch = hh*32 + cp*4;
    int segb[4] = { s0off[node], s1off[node], s2off[node], s0off[node+1] };
    float a[4] = {0.f, 0.f, 0.f, 0.f};
    #pragma unroll
    for (int t = 0; t < 3; ++t) {
        const u16* h = hb + (size_t)t*ND;
        int beg = segb[t], end = segb[t+1];
        float ds = 0.f, s0 = 0.f, s1 = 0.f, s2 = 0.f, s3 = 0.f;
        for (int pos = beg; pos < end; pos += 4) {
            int p0 = pos + eh, p1 = pos + 2 + eh;
            int v0 = (p0 < end), v1 = (p1 < end);
            int q0 = v0 ? p0 : beg, q1 = v1 ? p1 : beg;
            int sA = csrc[q0], sB = csrc[q1];
            float alA = abf[(size_t)q0*4 + hh];
            float alB = abf[(size_t)q1*4 + hh];
            uint2 hA = *(const uint2*)&h[(size_t)sA*128 + ch];
            uint2 hB = *(const uint2*)&h[(size_t)sB*128 + ch];
            alA = v0 ? alA : 0.f;
            alB = v1 ? alB : 0.f;
            float2 wA0 = bf2x(hA.x), wA1 = bf2x(hA.y);
            float2 wB0 = bf2x(hB.x), wB1 = bf2x(hB.y);
            ds += alA + alB;
            s0 += alA*wA0.x + alB*wB0.x;
            s1 += alA*wA0.y + alB*wB0.y;
            s2 += alA*wA1.x + alB*wB1.x;
            s3 += alA*wA1.y + alB*wB1.y;
        }
        ds += __shfl_xor(ds, 32);
        s0 += __shfl_xor(s0, 32);
        s1 += __shfl_xor(s1, 32);
        s2 += __shfl_xor(s2, 32);
        s3 += __shfl_xor(s3, 32);
        float inv = 1.f/(ds + 1e-16f);
        a[0] += s0*inv; a[1] += s1*inv; a[2] += s2*inv; a[3] += s3*inv;
    }
    float4 b0 = *(const float4*)&bias3[ch];
    float4 b1 = *(const float4*)&bias3[128 + ch];
    float4 b2 = *(const float4*)&bias3[256 + ch];
    a[0] += b0.x + b1.x + b2.x;
    a[1] += b0.y + b1.y + b2.y;
    a[2] += b0.z + b1.z + b2.z;
    a[3] += b0.w + b1.w + b2.w;
    float ssum = a[0]*a[0] + a[1]*a[1] + a[2]*a[2] + a[3]*a[3];
    ssum += __shfl_xor(ssum, 1); ssum += __shfl_xor(ssum, 2);
    ssum += __shfl_xor(ssum, 4); ssum += __shfl_xor(ssum, 8);
    ssum += __shfl_xor(ssum, 16);
    float r = rsqrtf(ssum*(1.f/128.f) + 1e-6f);
    float4 sc = *(const float4*)&scale[ch];
    size_t off = (size_t)node*128 + ch;
    uint2 xo = *(const uint2*)&xoldb[off];
    float2 p0 = bf2x(xo.x), p1 = bf2x(xo.y);
    float y0 = lrelu(p0.x + sc.x*a[0]*r);
    float y1 = lrelu(p0.y + sc.y*a[1]*r);
    float y2 = lrelu(p1.x + sc.z*a[2]*r);
    float y3 = lrelu(p1.y + sc.w*a[3]*r);
    uint2 o2; o2.x = cvt2(y0, y1); o2.y = cvt2(y2, y3);
    *(uint2*)&outb[off] = o2;
}

// ============ HGT aggregate: fp8 kv + bf16 qt, 4ch/lane, 2 edges/wave; pb interleaved ============
__global__ __launch_bounds__(256) void hgt_agg_k(const u8* __restrict__ kvb,
    const u16* __restrict__ qtb, const float* __restrict__ prel,
    const int* __restrict__ s0off, const int* __restrict__ s1off, const int* __restrict__ s2off,
    const int* __restrict__ csrc, u16* __restrict__ pb)
{
    int gid = blockIdx.x*256 + threadIdx.x;
    int node = gid >> 6, lane = gid & 63;
    int eh = lane >> 5, hh = (lane >> 3) & 3, cp = lane & 7;
    int ch = hh*32 + cp*4;
    const float S = 0.17677669529663689f; // 1/sqrt(32)
    int segb[4] = { s0off[node], s1off[node], s2off[node], s0off[node+1] };
    float dsum = 0.f;
    float ac[3][4];
    #pragma unroll
    for (int t = 0; t < 3; ++t){ ac[t][0]=0.f; ac[t][1]=0.f; ac[t][2]=0.f; ac[t][3]=0.f; }
    #pragma unroll
    for (int t = 0; t < 3; ++t) {
        float ph = prel[t*4 + hh] * S;
        uint2 qw = *(const uint2*)&qtb[(size_t)t*ND + (size_t)node*128 + ch];
        float2 q0 = bf2x(qw.x), q1 = bf2x(qw.y);
        int self = segb[t];
        int beg = self + 1, end = segb[t+1];
        for (int pos = beg; pos < end; pos += 4) {
            int p0 = pos + eh, p1 = pos + 2 + eh;
            int v0 = (p0 < end), v1 = (p1 < end);
            int qp0 = v0 ? p0 : self, qp1 = v1 ? p1 : self;
            int sA = csrc[qp0], sB = csrc[qp1];
            size_t rA = (size_t)sA*256 + ch, rB = (size_t)sB*256 + ch;
            unsigned kA = *(const unsigned*)&kvb[rA], kB = *(const unsigned*)&kvb[rB];
            unsigned vA = *(const unsigned*)&kvb[rA + 128], vB = *(const unsigned*)&kvb[rB + 128];
            f32x2 kA0 = __builtin_amdgcn_cvt_pk_f32_fp8((int)kA, false);
            f32x2 kA1 = __builtin_amdgcn_cvt_pk_f32_fp8((int)kA, true);
            f32x2 kB0 = __builtin_amdgcn_cvt_pk_f32_fp8((int)kB, false);
            f32x2 kB1 = __builtin_amdgcn_cvt_pk_f32_fp8((int)kB, true);
            float scA = kA0[0]*q0.x + kA0[1]*q0.y + kA1[0]*q1.x + kA1[1]*q1.y;
            float scB = kB0[0]*q0.x + kB0[1]*q0.y + kB1[0]*q1.x + kB1[1]*q1.y;
            scA += __shfl_xor(scA, 1); scB += __shfl_xor(scB, 1);
            scA += __shfl_xor(scA, 2); scB += __shfl_xor(scB, 2);
            scA += __shfl_xor(scA, 4); scB += __shfl_xor(scB, 4);
            float eA = v0 ? fexp(scA*ph) : 0.f;
            float eB = v1 ? fexp(scB*ph) : 0.f;
            f32x2 vA0 = __builtin_amdgcn_cvt_pk_f32_fp8((int)vA, false);
            f32x2 vA1 = __builtin_amdgcn_cvt_pk_f32_fp8((int)vA, true);
            f32x2 vB0 = __builtin_amdgcn_cvt_pk_f32_fp8((int)vB, false);
            f32x2 vB1 = __builtin_amdgcn_cvt_pk_f32_fp8((int)vB, true);
            dsum += eA + eB;
            ac[t][0] += eA*vA0[0] + eB*vB0[0];
            ac[t][1] += eA*vA0[1] + eB*vB0[1];
            ac[t][2] += eA*vA1[0] + eB*vB1[0];
            ac[t][3] += eA*vA1[1] + eB*vB1[1];
        }
    }
    dsum += __shfl_xor(dsum, 32);
    #pragma unroll
    for (int t = 0; t < 3; ++t){
        ac[t][0] += __shfl_xor(ac[t][0], 32);
        ac[t][1] += __shfl_xor(ac[t][1], 32);
        ac[t][2] += __shfl_xor(ac[t][2], 32);
        ac[t][3] += __shfl_xor(ac[t][3], 32);
    }
    float inv = 1.f/(dsum + 1e-16f);
    size_t o = (size_t)node*384 + ch;
    #pragma unroll
    for (int t = 0; t < 3; ++t){
        uint2 o2;
        o2.x = cvt2(ac[t][0]*inv, ac[t][1]*inv);
        o2.y = cvt2(ac[t][2]*inv, ac[t][3]*inv);
        *(uint2*)&pb[o + (size_t)t*128] = o2;
    }
}

// ============ final: M-stage (block-diag) + Wo (LDS) + epilogue w/ precomputed injv ============
__global__ __launch_bounds__(256, 3) void final_k(const u16* __restrict__ pb,
    const u16* __restrict__ wpmd, const u16* __restrict__ wpo, const float* __restrict__ bo,
    const u16* __restrict__ x2b, const float* __restrict__ skipp, const float* __restrict__ scale,
    const u16* __restrict__ injv,
    const float* __restrict__ gbuf, const int* __restrict__ bszp,
    float* __restrict__ out)
{
    __shared__ __align__(16) u16 wl[128*WLP];
    __shared__ __align__(16) u16 tb[4][16][TBW];
    const int tid = threadIdx.x, wave = tid>>6, lane = tid&63, lr = lane&15, lk = lane>>4;
    const int rw = blockIdx.x*64 + wave*16;
    stage_w(wpo, wl, tid);
    f32x4 acc[8];
    #pragma unroll
    for (int i = 0; i < 8; ++i) acc[i] = (f32x4){0.f,0.f,0.f,0.f};
    {
        const u16* pr = pb + (size_t)(rw + lr)*384;
        #pragma unroll
        for (int t = 0; t < 3; ++t){
            bf8_t a0[4];
            #pragma unroll
            for (int kk = 0; kk < 4; ++kk)
                a0[kk] = *(const bf8_t*)(pr + t*128 + kk*32 + lk*8);
            mfma_bd1_acc(a0, wpmd + t*4096, lr, lk, acc);
        }
    }
    bf8_t ga[4];
    acc_to_tb_gelu(tb[wave], acc, lr, lk);
    tb_frags(tb[wave], lr, lk, ga);
    __syncthreads();
    mfma_l1(ga, wl, lr, lk, acc);
    bf8_t hw[4];
    acc_to_tb(tb[wave], acc, lr, lk, bo);
    tb_rows(tb[wave], lr, lk, hw);
    const float sig = 1.f/(1.f + expf(-skipp[0]));
    const int cpb = NN / *bszp;
    float4 sca = *(const float4*)&scale[lr*8];
    float4 scb = *(const float4*)&scale[lr*8 + 4];
    #pragma unroll
    for (int c = 0; c < 4; ++c){
        int row = rw + c*4 + lk;
        bf8_t x8 = *(const bf8_t*)(x2b + (size_t)row*128 + lr*8);
        bf8_t i8 = *(const bf8_t*)(injv + (size_t)row*128 + lr*8);
        float x[8], v[8];
        float ssl = 0.f;
        #pragma unroll
        for (int j = 0; j < 8; ++j){
            x[j] = bf2f((u16)x8[j]);
            float h = bf2f((u16)hw[c][j]);
            v[j] = sig*h + (1.f - sig)*x[j];
            ssl += v[j]*v[j];
        }
        ssl += __shfl_xor(ssl, 1); ssl += __shfl_xor(ssl, 2);
        ssl += __shfl_xor(ssl, 4); ssl += __shfl_xor(ssl, 8);
        float rq = rsqrtf(ssl*(1.f/128.f) + 1e-6f);
        const float* gr = gbuf + (row / cpb)*256;
        float4 g0 = *(const float4*)&gr[lr*8];
        float4 g1 = *(const float4*)&gr[lr*8 + 4];
        float4 b0 = *(const float4*)&gr[128 + lr*8];
        float4 b1 = *(const float4*)&gr[128 + lr*8 + 4];
        float4 oA, oB;
        #pragma unroll
        for (int j = 0; j < 8; ++j){
            float scj = (j < 4) ? ((const float*)&sca)[j] : ((const float*)&scb)[j-4];
            float y = lrelu(x[j] + scj*v[j]*rq);
            float hf = y + bf2f((u16)i8[j]);
            float gj = (j < 4) ? ((const float*)&g0)[j] : ((const float*)&g1)[j-4];
            float bj = (j < 4) ? ((const float*)&b0)[j] : ((const float*)&b1)[j-4];
            float ov = (1.f + gj)*hf + bj;
            if (j < 4) ((float*)&oA)[j] = ov; else ((float*)&oB)[j-4] = ov;
        }
        *(float4*)(out + (size_t)row*128 + lr*8)     = oA;
        *(float4*)(out + (size_t)row*128 + lr*8 + 4) = oB;
    }
}

// ============ FiLM small MLP ============
__global__ __launch_bounds__(256) void film_k(const float* __restrict__ z,
    const float* __restrict__ W1, const float* __restrict__ b1,
    const float* __restrict__ W2, const float* __restrict__ b2,
    float* __restrict__ gb)
{
    __shared__ float zr[128];
    __shared__ float g1[256];
    int r = blockIdx.x, tid = threadIdx.x;
    if (tid < 128) zr[tid] = z[r*128 + tid];
    __syncthreads();
    float s = b1[tid];
    for (int k = 0; k < 128; ++k) s += zr[k]*W1[k*256 + tid];
    g1[tid] = gelu_exact(s);
    __syncthreads();
    float s2 = b2[tid];
    for (int k = 0; k < 256; ++k) s2 += g1[k]*W2[k*256 + tid];
    gb[r*256 + tid] = 0.1f*tanhf(s2);
}

// ================= launch =================
extern "C" void kernel_launch(void* const* d_in, const int* in_sizes, int n_in,
                              void* d_out, int out_size, void* d_ws, size_t ws_size,
                              hipStream_t stream)
{
    const float* x_cell = (const float*)d_in[0];
    const float* z_h    = (const float*)d_in[1];
    const float* x_emb  = (const float*)d_in[2];
    const int*   eidx   = (const int*)d_in[3];
    const int*   bszp   = (const int*)d_in[4];
    const float* g1W  = (const float*)d_in[5];
    const float* g1as = (const float*)d_in[6];
    const float* g1ad = (const float*)d_in[7];
    const float* g1b  = (const float*)d_in[8];
    const float* g2W  = (const float*)d_in[9];
    const float* g2as = (const float*)d_in[10];
    const float* g2ad = (const float*)d_in[11];
    const float* g2b  = (const float*)d_in[12];
    const float* n1s  = (const float*)d_in[13];
    const float* n2s  = (const float*)d_in[14];
    const float* n3s  = (const float*)d_in[15];
    const float* Wk   = (const float*)d_in[16];
    const float* bk   = (const float*)d_in[17];
    const float* Wq   = (const float*)d_in[18];
    const float* bq   = (const float*)d_in[19];
    const float* Wv   = (const float*)d_in[20];
    const float* bv   = (const float*)d_in[21];
    const float* arel = (const float*)d_in[22];
    const float* mrel = (const float*)d_in[23];
    const float* prel = (const float*)d_in[24];
    const float* Wo   = (const float*)d_in[25];
    const float* bo   = (const float*)d_in[26];
    const float* skipp= (const float*)d_in[27];
    const float* injW = (const float*)d_in[28];
    const float* injb = (const float*)d_in[29];
    const float* fW1  = (const float*)d_in[30];
    const float* fb1  = (const float*)d_in[31];
    const float* fW2  = (const float*)d_in[32];
    const float* fb2  = (const float*)d_in[33];

    // ---- workspace layout ----
    u16* wp   = (u16*)d_ws;                   // 17*16384 u16
    u16* wpa  = wp + (size_t)17*16384;        // 6*2048 u16
    float4* ab = (float4*)(wpa + 6*2048);     // CSRN float4
    u16* x0b  = (u16*)(ab + CSRN);            // ND u16 (x_cell bf16)
    u16* x1b  = x0b + ND;                     // ND u16
    u16* x2b  = x1b + ND;                     // ND u16
    u8*  kvb  = (u8*)(x2b + ND);              // NN*256 bytes (k|v fp8)
    u16* pb   = (u16*)(kvb + (size_t)NN*256); // 3*ND u16 (interleaved [node][3][128])
    u16* hb   = pb + 3*ND;                    // 3*ND u16 (GAT h; reused as qtb)
    u16* injv = hb + 3*ND;                    // ND u16 (inject result, bias folded)
    float* alsb = (float*)(injv + ND);        // 3*NN*4 f32
    float* aldb = alsb + (size_t)3*NN*4;      // 3*NN*4 f32
    float* gbuf = aldb + (size_t)3*NN*4;      // 32*256 f32
    int* s0off  = (int*)(gbuf + 32*256);      // NN+1
    int* s1off  = s0off + (NN+1);             // NN
    int* s2off  = s1off + NN;                 // NN
    int* csrc   = s2off + NN;                 // CSRN
    int* posmap = csrc + CSRN;                // 3*EE
    int* tmpc   = posmap + 3*EE;              // 3*NN (cnt)
    int* cur    = tmpc + 3*NN;                // 3*NN
    int* parts  = cur + 3*NN;                 // 256

    u16* qtb = hb;
    float* outp = (float*)d_out;

    const u16* wpg1 = wp;
    const u16* wpg2 = wp + (size_t)3*16384;
    const u16* wpk  = wp + (size_t)6*16384;
    const u16* wpq  = wp + (size_t)7*16384;
    const u16* wpv  = wp + (size_t)8*16384;
    const u16* wpo  = wp + (size_t)9*16384;
    const u16* wpinj= wp + (size_t)10*16384;
    const u16* wpad = wp + (size_t)11*16384;            // packed arel [3][4096]
    const u16* wpmd = wpad + (size_t)3*4096;            // packed mrel [3][4096]

    // ---- weight pre-pack + x_cell cast ----
    wpack_k<<<18, 256, 0, stream>>>(g1W, g2W, Wk, Wq, Wv, Wo, injW, arel, mrel,
                                    g1as, g1ad, g2as, g2ad, wp, wpa);
    xcast_k<<<(int)(ND/2048), 256, 0, stream>>>(x_cell, x0b);

    // ---- type-sorted merged CSR with self slots ----
    hipMemsetAsync(tmpc, 0, 3*NN*sizeof(int), stream);
    hist_k<<<3*EE/256, 256, 0, stream>>>(eidx, tmpc);
    scanA_k<<<64, 256, 0, stream>>>(tmpc, s0off, parts);
    scan2_k<<<1, 64, 0, stream>>>(parts);
    scanB_k<<<64, 256, 0, stream>>>(tmpc, s0off, s1off, s2off, parts);
    selffill_k<<<3*NN/256, 256, 0, stream>>>(s0off, s1off, s2off, csrc);
    hipMemsetAsync(cur, 0, 3*NN*sizeof(int), stream);
    scatter_k<<<3*EE/256, 256, 0, stream>>>(eidx, s0off, s1off, s2off, cur, csrc, posmap);

    // ---- FiLM small MLP ----
    int B = in_sizes[1] / 128;
    film_k<<<B, 256, 0, stream>>>(z_h, fW1, fb1, fW2, fb2, gbuf);

    // ---- GAT layer 1 ----
    gat_gemm3_k<<<dim3(512,3), 256, 0, stream>>>(x0b, wpg1, wpa, hb, alsb, aldb);
    alpha_k<<<3*NTOT/256, 256, 0, stream>>>(alsb, aldb, eidx, posmap, s0off, s1off, s2off, ab);
    gat_aggres_k<<<16384, 256, 0, stream>>>(hb, (const float*)ab, s0off, s1off, s2off, csrc,
                                            g1b, x0b, n1s, x1b);

    // ---- GAT layer 2 ----
    gat_gemm3_k<<<dim3(512,3), 256, 0, stream>>>(x1b, wpg2, wpa + 3*2048, hb, alsb, aldb);
    alpha_k<<<3*NTOT/256, 256, 0, stream>>>(alsb, aldb, eidx, posmap, s0off, s1off, s2off, ab);
    gat_aggres_k<<<16384, 256, 0, stream>>>(hb, (const float*)ab, s0off, s1off, s2off, csrc,
                                            g2b, x1b, n2s, x2b);

    // ---- HGT projections + inject (4 tasks) ----
    hgt_proj_k<<<dim3(512,4), 256, 0, stream>>>(x2b, wpk, wpq, wpv, wpad, wpinj, x_emb,
                                                bk, bq, bv, injb, kvb, qtb, injv);
    hgt_agg_k<<<16384, 256, 0, stream>>>(kvb, qtb, prel, s0off, s1off, s2off, csrc, pb);

    // ---- final ----
    final_k<<<1024, 256, 0, stream>>>(pb, wpmd, wpo, bo, x2b, skipp, n3s,
                                      injv, gbuf, bszp, outp);
}